// Round 2
// baseline (615.798 us; speedup 1.0000x reference)
//
#include <hip/hip_runtime.h>
#include <math.h>

// B=1, C=64, H=W=64, N=4096, heads=8, dh=8, inner=64, hid_lc=32, hid_f=256.
// Single persistent fused kernel: 5 stages separated by device-scope grid
// barriers. Grid 512 blocks x 256 threads, co-resident by construction:
// __launch_bounds__(256,3) caps VGPR ~168 (3 waves/SIMD = 3 blocks/CU) and
// the LDS union is 49.9 KB -> 3 blocks/CU capacity >= 2 needed. Barrier
// counters live in ws and are zeroed by init_kernel each iteration (ws is
// re-poisoned between iterations, so counters must be re-inited in-stream).
#define NPIX 4096
#define IMG 64
#define NBLK 512

typedef __attribute__((ext_vector_type(8))) short bf16x8;
typedef __attribute__((ext_vector_type(4))) float floatx4;
typedef __attribute__((ext_vector_type(4))) unsigned int uintx4;

// fp32 -> (hi bf16 in low16) | (lo bf16 in high16), lo = x - f32(hi)
__device__ __forceinline__ unsigned int split_pack(float x) {
  unsigned int u = __float_as_uint(x);
  unsigned int hif = u & 0xffff0000u;
  float lof = x - __uint_as_float(hif);
  return (u >> 16) | (__float_as_uint(lof) & 0xffff0000u);
}

// pack hi16 of two floats in ONE v_perm_b32: low16 = hi16(a), high16 = hi16(b)
__device__ __forceinline__ unsigned int pack_hi2(float a, float b) {
  return __builtin_amdgcn_perm(__float_as_uint(b), __float_as_uint(a),
                               0x07060302u);
}

// Device-scope grid barrier: release-fence + arrive, spin on counter, then
// acquire-fence so post-barrier loads see pre-barrier stores across XCDs.
__device__ __forceinline__ void gbar(unsigned int* ctr) {
  __syncthreads();
  __threadfence();  // release: push this thread's stores device-visible
  if (threadIdx.x == 0) {
    atomicAdd(ctr, 1u);
    while (__hip_atomic_load(ctr, __ATOMIC_RELAXED,
                             __HIP_MEMORY_SCOPE_AGENT) < (unsigned)NBLK)
      __builtin_amdgcn_s_sleep(2);
  }
  __syncthreads();
  __threadfence();  // acquire: don't serve stale cache lines after barrier
}

// LDS stage overlays (union keeps the fused kernel at 49.9 KB).
struct S1 {  // lc12
  float lum[400];
  float sw1[288];
  float tin[32][324];
  float swt[4][32][9];
  float red[256];
};
struct S2 {  // ln_qkv
  float xs[64][32];
  float wsh[64][64];
  float h2s[32][32];
  float wgs[32][64];
  float wbs[32][64];
  float mu[32];
  float rs[32];
};
struct S4 {  // proj_ffn1 (single reused weight buffer)
  float at[64][34];
  float wsh[64][64];
  float xsl[64][34];
  float ps[16][32];
  float pq[16][32];
  float mus[32];
  float rss[32];
};
struct S5 {  // ffn2_dw
  float xs2[16][260];
  float wshT[32][260];
};
union SU {
  S1 s1;
  S2 s2;
  S4 s4;
  S5 s5;
};

__global__ void init_kernel(unsigned int* __restrict__ ctr,
                            unsigned short* __restrict__ cbuf) {
  int t = threadIdx.x;
  if (t < 8) ctr[t] = 0u;
  if (t >= 32 && t < 48) cbuf[t - 32] = (t - 32 < 8) ? 0x3F80 : 0;
}

__global__ __launch_bounds__(256, 3) void fused_kernel(
    const float* __restrict__ x, const float* __restrict__ luma,
    const float* __restrict__ lc1w, const float* __restrict__ lc1b,
    const float* __restrict__ lc2w, const float* __restrict__ lc2b,
    const float* __restrict__ ln1w, const float* __restrict__ ln1b,
    const float* __restrict__ qkvW, const float* __restrict__ qkvB,
    const float* __restrict__ gamW, const float* __restrict__ gamB,
    const float* __restrict__ betW, const float* __restrict__ betB,
    const float* __restrict__ alpha, const float* __restrict__ projW,
    const float* __restrict__ projB, const float* __restrict__ ln2w,
    const float* __restrict__ ln2b, const float* __restrict__ ffn1W,
    const float* __restrict__ ffn1B, const float* __restrict__ dww,
    const float* __restrict__ dwb, const float* __restrict__ ffn2W,
    const float* __restrict__ ffn2B, float* __restrict__ out,
    float* __restrict__ pooled, float* __restrict__ bsums,
    unsigned short* __restrict__ cbuf, float* __restrict__ mu1,
    float* __restrict__ rs1, unsigned short* __restrict__ qhl,
    unsigned short* __restrict__ khl, unsigned short* __restrict__ vthx,
    unsigned short* __restrict__ vtlx, float* __restrict__ pacc,
    float* __restrict__ pl, float* __restrict__ x1, float* __restrict__ f1,
    float* __restrict__ h2, unsigned int* __restrict__ ctr) {
  __shared__ SU u;
  int bid = blockIdx.x;
  int tid = threadIdx.x;

  // ---------------- Stage 1: lc12 (128 units) ----------------
  if (bid < 128) {
    int tile = bid >> 3, ocg = bid & 7;
    int ty0 = (tile >> 2) * 16, tx0 = (tile & 3) * 16;
    float(&lum)[400] = u.s1.lum;
    float(&sw1)[288] = u.s1.sw1;
    float(&tin)[32][324] = u.s1.tin;
    float(&swt)[4][32][9] = u.s1.swt;
    float(&red)[256] = u.s1.red;
    for (int idx = tid; idx < 400; idx += 256) {
      int py = idx / 20, px = idx - py * 20;
      int gy = ty0 + py - 2, gx = tx0 + px - 2;
      lum[idx] = (gy >= 0 && gy < IMG && gx >= 0 && gx < IMG)
                     ? luma[gy * IMG + gx]
                     : 0.f;
    }
    for (int idx = tid; idx < 288; idx += 256) sw1[idx] = lc1w[idx];
    for (int idx = tid; idx < 1152; idx += 256) {
      int o = idx / 288, r = idx - o * 288;
      swt[o][r / 9][r % 9] = lc2w[(ocg * 4 + o) * 288 + r];
    }
    __syncthreads();
    for (int idx = tid; idx < 32 * 324; idx += 256) {
      int ic = idx / 324, pos = idx - ic * 324;
      int py = pos / 18, px = pos - py * 18;
      int gy = ty0 + py - 1, gx = tx0 + px - 1;
      float v = 0.f;
      if (gy >= 0 && gy < IMG && gx >= 0 && gx < IMG) {
        float s = lc1b[ic];
        const float* wp = &sw1[ic * 9];
#pragma unroll
        for (int dy = 0; dy < 3; dy++)
#pragma unroll
          for (int dx = 0; dx < 3; dx++)
            s = fmaf(wp[dy * 3 + dx], lum[(py + dy) * 20 + px + dx], s);
        v = fmaxf(s, 0.f);
      }
      tin[ic][pos] = v;
    }
    __syncthreads();
    int ly = tid >> 4, lx = tid & 15;
    int p = (ty0 + ly) * IMG + tx0 + lx;
    float acc[4];
#pragma unroll
    for (int o = 0; o < 4; o++) acc[o] = lc2b[ocg * 4 + o];
    for (int ic = 0; ic < 32; ic++) {
      float v[9];
#pragma unroll
      for (int dy = 0; dy < 3; dy++)
#pragma unroll
        for (int dx = 0; dx < 3; dx++)
          v[dy * 3 + dx] = tin[ic][(ly + dy) * 18 + lx + dx];
#pragma unroll
      for (int o = 0; o < 4; o++)
#pragma unroll
        for (int t = 0; t < 9; t++) acc[o] = fmaf(swt[o][ic][t], v[t], acc[o]);
    }
#pragma unroll
    for (int o = 0; o < 4; o++)
      h2[(ocg * 4 + o) * NPIX + p] = fmaxf(acc[o], 0.f);
    if (ocg == 0) {
      int gy = ty0 + ly, gx = tx0 + lx;
      float sv = 0.f;
#pragma unroll
      for (int dy = 0; dy < 3; dy++)
#pragma unroll
        for (int dx = 0; dx < 3; dx++)
          sv += lum[(ly + dy + 1) * 20 + lx + dx + 1];
      float cy = 3.f - (gy == 0 ? 1.f : 0.f) - (gy == 63 ? 1.f : 0.f);
      float cx = 3.f - (gx == 0 ? 1.f : 0.f) - (gx == 63 ? 1.f : 0.f);
      float pv = (cy * cx - sv) * (1.f / 9.f);
      pooled[p] = pv;
      red[tid] = pv;
      __syncthreads();
      for (int st = 128; st > 0; st >>= 1) {
        if (tid < st) red[tid] += red[tid + st];
        __syncthreads();
      }
      if (tid == 0) bsums[tile] = red[0];
      float s = 0.f, q = 0.f;
#pragma unroll 8
      for (int cc = 0; cc < 64; cc++) {
        float xv = x[cc * NPIX + p];
        s += xv;
        q = fmaf(xv, xv, q);
      }
      float mu = s * (1.f / 64.f);
      mu1[p] = mu;
      rs1[p] = rsqrtf(q * (1.f / 64.f) - mu * mu + 1e-5f);
    }
  }
  gbar(&ctr[0]);

  // ---------------- Stage 2: ln_qkv (384 units) ----------------
  if (bid < 384) {
    const float QSCALE = 0.35355339059327376f * 1.4426950408889634f;
    float(&xs)[64][32] = u.s2.xs;
    float(&wsh)[64][64] = u.s2.wsh;
    float(&h2s)[32][32] = u.s2.h2s;
    float(&wgs)[32][64] = u.s2.wgs;
    float(&wbs)[32][64] = u.s2.wbs;
    float(&mu)[32] = u.s2.mu;
    float(&rs)[32] = u.s2.rs;
    int n0 = (bid & 127) * 32, part = bid >> 7, m0 = part * 64;
    if (tid < 32) {
      mu[tid] = mu1[n0 + tid];
      rs[tid] = rs1[n0 + tid];
    }
    {
      int e = tid * 2;
      int c = e >> 3, off = (e & 7) * 4;
      *(float4*)&xs[c][off] = *(const float4*)&x[c * NPIX + n0 + off];
      int e1 = e + 1;
      int c1 = e1 >> 3, off1 = (e1 & 7) * 4;
      *(float4*)&xs[c1][off1] = *(const float4*)&x[c1 * NPIX + n0 + off1];
    }
    {
      int m = tid >> 2, kg = (tid & 3) * 16;
      const float4* wr = (const float4*)&qkvW[(m0 + m) * 64 + kg];
      float4 w0 = wr[0], w1 = wr[1], w2 = wr[2], w3 = wr[3];
      float wv[16] = {w0.x, w0.y, w0.z, w0.w, w1.x, w1.y, w1.z, w1.w,
                      w2.x, w2.y, w2.z, w2.w, w3.x, w3.y, w3.z, w3.w};
#pragma unroll
      for (int j = 0; j < 16; j++) wsh[kg + j][m] = wv[j];
    }
    {
      int k = tid >> 3, nf = (tid & 7) * 4;
      *(float4*)&h2s[k][nf] = *(const float4*)&h2[k * NPIX + n0 + nf];
    }
    {
      int m = tid >> 2, kg = (tid & 3) * 8;
      const float4* g0 = (const float4*)&gamW[m * 32 + kg];
      float4 a = g0[0], b4 = g0[1];
      float gv[8] = {a.x, a.y, a.z, a.w, b4.x, b4.y, b4.z, b4.w};
#pragma unroll
      for (int j = 0; j < 8; j++) wgs[kg + j][m] = gv[j];
      const float4* bb0 = (const float4*)&betW[m * 32 + kg];
      float4 c4 = bb0[0], d4 = bb0[1];
      float bv[8] = {c4.x, c4.y, c4.z, c4.w, d4.x, d4.y, d4.z, d4.w};
#pragma unroll
      for (int j = 0; j < 8; j++) wbs[kg + j][m] = bv[j];
    }
    __syncthreads();
    {
      int c = tid >> 2, pg = (tid & 3) * 8;
      float wc = ln1w[c], bc = ln1b[c];
#pragma unroll
      for (int j = 0; j < 8; j++) {
        int p = pg + j;
        xs[c][p] = (xs[c][p] - mu[p]) * rs[p] * wc + bc;
      }
    }
    __syncthreads();
    int tx = tid & 15, ty = tid >> 4;
    float ga[4][2] = {}, ba[4][2] = {};
#pragma unroll 8
    for (int kk = 0; kk < 32; kk++) {
      float4 wg4 = *(const float4*)&wgs[kk][ty * 4];
      float4 wb4 = *(const float4*)&wbs[kk][ty * 4];
      float2 h22 = *(const float2*)&h2s[kk][tx * 2];
      float gv[4] = {wg4.x, wg4.y, wg4.z, wg4.w};
      float bv[4] = {wb4.x, wb4.y, wb4.z, wb4.w};
      float hv[2] = {h22.x, h22.y};
#pragma unroll
      for (int im = 0; im < 4; im++)
#pragma unroll
        for (int in = 0; in < 2; in++) {
          ga[im][in] = fmaf(gv[im], hv[in], ga[im][in]);
          ba[im][in] = fmaf(bv[im], hv[in], ba[im][in]);
        }
    }
#pragma unroll
    for (int im = 0; im < 4; im++) {
      int cc = ty * 4 + im;
      float gb = gamB[cc], bb2 = betB[cc];
#pragma unroll
      for (int in = 0; in < 2; in++) {
        ga[im][in] += gb;
        ba[im][in] += bb2;
      }
    }
    float acc[4][2] = {};
#pragma unroll 8
    for (int kk = 0; kk < 64; kk++) {
      float4 a = *(const float4*)&wsh[kk][ty * 4];
      float2 b2 = *(const float2*)&xs[kk][tx * 2];
      float av[4] = {a.x, a.y, a.z, a.w};
      float bv[2] = {b2.x, b2.y};
#pragma unroll
      for (int im = 0; im < 4; im++)
#pragma unroll
        for (int in = 0; in < 2; in++)
          acc[im][in] = fmaf(av[im], bv[in], acc[im][in]);
    }
    float val[4][2];
#pragma unroll
    for (int im = 0; im < 4; im++) {
      int cc = ty * 4 + im;
      float bv = qkvB[m0 + cc];
#pragma unroll
      for (int in = 0; in < 2; in++)
        val[im][in] = fmaf(ga[im][in], acc[im][in] + bv, ba[im][in]);
    }
    if (part == 0) {
      float msum = 0.f;
#pragma unroll
      for (int t = 0; t < 16; t++) msum += bsums[t];
      float mean = msum * (1.f / 4096.f);
      float a0 = alpha[0];
      const float2 pv = *(const float2*)&pooled[n0 + tx * 2];
      float iv[2] = {a0 * (pv.x - mean), a0 * (pv.y - mean)};
#pragma unroll
      for (int im = 0; im < 4; im++)
#pragma unroll
        for (int in = 0; in < 2; in++)
          val[im][in] = (val[im][in] + iv[in]) * QSCALE;
    }
    if (part < 2) {
      unsigned short* dst = (part == 0) ? qhl : khl;
      int hh = ty >> 1, d0 = (ty & 1) * 4;
#pragma unroll
      for (int in = 0; in < 2; in++) {
        int n = n0 + tx * 2 + in;
        unsigned int pk[4];
#pragma unroll
        for (int im = 0; im < 4; im++) pk[im] = split_pack(val[im][in]);
        short4 hi, lo;
        hi.x = (short)(pk[0] & 0xffffu); hi.y = (short)(pk[1] & 0xffffu);
        hi.z = (short)(pk[2] & 0xffffu); hi.w = (short)(pk[3] & 0xffffu);
        lo.x = (short)(pk[0] >> 16); lo.y = (short)(pk[1] >> 16);
        lo.z = (short)(pk[2] >> 16); lo.w = (short)(pk[3] >> 16);
        unsigned short* base = dst + ((size_t)(hh * NPIX + n) << 4) + d0;
        *(short4*)base = hi;
        *(short4*)(base + 8) = lo;
      }
    } else {
      int nq = n0 + tx * 2;
      int off0 = (nq >> 5) * 32 + ((nq >> 4) & 1) * 4 + ((nq >> 2) & 3) * 8 +
                 (nq & 3);
#pragma unroll
      for (int im = 0; im < 4; im++) {
        int cc = ty * 4 + im;
        unsigned int pk0 = split_pack(val[im][0]);
        unsigned int pk1 = split_pack(val[im][1]);
        short2 hi, lo;
        hi.x = (short)(pk0 & 0xffffu);
        hi.y = (short)(pk1 & 0xffffu);
        lo.x = (short)(pk0 >> 16);
        lo.y = (short)(pk1 >> 16);
        *(short2*)(vthx + (size_t)cc * NPIX + off0) = hi;
        *(short2*)(vtlx + (size_t)cc * NPIX + off0) = lo;
      }
    }
  }
  gbar(&ctr[1]);

  // ---------------- Stage 3: attn (1024 units, 2 per block) ----------------
  {
    int wave = tid >> 6, lane = tid & 63;
    int g = lane >> 4, c = lane & 15;
#pragma unroll 1
    for (int rep = 0; rep < 2; rep++) {
      int unit = bid * 2 + rep;
      int h = (unit >> 4) & 7, jp = unit >> 7;
      int i0 = (unit & 15) * 256 + wave * 64;
      int jbase = jp * 512;
      bf16x8 qB[4];
#pragma unroll
      for (int t = 0; t < 4; t++)
        qB[t] = *(const bf16x8*)(qhl +
                                 ((size_t)(h * NPIX + i0 + t * 16 + c) << 4) +
                                 ((g & 1) << 3));
      const unsigned short* kp =
          khl + ((size_t)(h * NPIX + jbase + c) << 4) + ((g >> 1) << 3);
      const unsigned short* vhp;
      const unsigned short* vlp;
      int vstep;
      if (c < 8) {
        vhp = vthx + (size_t)(h * 8 + c) * NPIX + jbase + (g << 3);
        vlp = vtlx + (size_t)(h * 8 + c) * NPIX + jbase + (g << 3);
        vstep = 32;
      } else {
        vhp = (c == 8) ? cbuf : (cbuf + 8);  // ones row / zero rows
        vlp = cbuf + 8;
        vstep = 0;
      }
      floatx4 zero4 = {0.f, 0.f, 0.f, 0.f};
      floatx4 aH[4], aM[4];
#pragma unroll
      for (int t = 0; t < 4; t++) {
        aH[t] = zero4;
        aM[t] = zero4;
      }
#pragma unroll 4
      for (int jt = 0; jt < 16; ++jt) {
        bf16x8 ka0 = *(const bf16x8*)kp;
        bf16x8 ka1 = *(const bf16x8*)(kp + 256);
        bf16x8 avh = *(const bf16x8*)vhp;
        bf16x8 avl = *(const bf16x8*)vlp;
        kp += 512;
        vhp += vstep;
        vlp += vstep;
#pragma unroll
        for (int t = 0; t < 4; t++) {
          floatx4 s0 = __builtin_amdgcn_mfma_f32_16x16x32_bf16(ka0, qB[t],
                                                               zero4, 0, 0, 0);
          floatx4 s1 = __builtin_amdgcn_mfma_f32_16x16x32_bf16(ka1, qB[t],
                                                               zero4, 0, 0, 0);
          float p0 = __builtin_amdgcn_exp2f(fminf(s0[0], 80.f));
          float p1 = __builtin_amdgcn_exp2f(fminf(s0[1], 80.f));
          float p2 = __builtin_amdgcn_exp2f(fminf(s0[2], 80.f));
          float p3 = __builtin_amdgcn_exp2f(fminf(s0[3], 80.f));
          float p4 = __builtin_amdgcn_exp2f(fminf(s1[0], 80.f));
          float p5 = __builtin_amdgcn_exp2f(fminf(s1[1], 80.f));
          float p6 = __builtin_amdgcn_exp2f(fminf(s1[2], 80.f));
          float p7 = __builtin_amdgcn_exp2f(fminf(s1[3], 80.f));
          uintx4 bh;
          bh.x = pack_hi2(p0, p1);
          bh.y = pack_hi2(p2, p3);
          bh.z = pack_hi2(p4, p5);
          bh.w = pack_hi2(p6, p7);
          bf16x8 pbh = __builtin_bit_cast(bf16x8, bh);
          aH[t] =
              __builtin_amdgcn_mfma_f32_16x16x32_bf16(avh, pbh, aH[t], 0, 0, 0);
          aM[t] =
              __builtin_amdgcn_mfma_f32_16x16x32_bf16(avl, pbh, aM[t], 0, 0, 0);
        }
      }
#pragma unroll
      for (int t = 0; t < 4; t++) {
        floatx4 o = aH[t] + aM[t];
        if (g < 2) {
          size_t b0 = (size_t)((jp * 8 + h) * NPIX + i0 + t * 16 + c);
          *(float4*)&pacc[b0 * 8 + g * 4] = make_float4(o[0], o[1], o[2], o[3]);
        } else if (g == 2) {
          pl[(size_t)((jp * 8 + h) * NPIX + i0 + t * 16 + c)] = o[0];
        }
      }
    }
  }
  gbar(&ctr[2]);

  // ---------------- Stage 4: proj_ffn1 (512 units) ----------------
  {
    float(&at)[64][34] = u.s4.at;
    float(&wsh)[64][64] = u.s4.wsh;
    float(&xsl)[64][34] = u.s4.xsl;
    float(&ps)[16][32] = u.s4.ps;
    float(&pq)[16][32] = u.s4.pq;
    float(&mus)[32] = u.s4.mus;
    float(&rss)[32] = u.s4.rss;
    int n0 = (bid & 127) * 32;
    int ch = bid >> 7;
    int mm = tid >> 2, kg = (tid & 3) * 16;
    {
      const float4* wr = (const float4*)&projW[mm * 64 + kg];
      float4 w0 = wr[0], w1 = wr[1], w2 = wr[2], w3 = wr[3];
      float wv[16] = {w0.x, w0.y, w0.z, w0.w, w1.x, w1.y, w1.z, w1.w,
                      w2.x, w2.y, w2.z, w2.w, w3.x, w3.y, w3.z, w3.w};
#pragma unroll
      for (int j = 0; j < 16; j++) wsh[kg + j][mm] = wv[j];
    }
    {
      int hh = tid >> 5, nn = tid & 31;
      int i = n0 + nn;
      float L = 0.f, o[8] = {};
#pragma unroll
      for (int p = 0; p < 8; p++) {
        size_t base = (size_t)((p * 8 + hh) * NPIX + i);
        L += pl[base];
        const float4 a0 = *(const float4*)&pacc[base * 8];
        const float4 a1 = *(const float4*)&pacc[base * 8 + 4];
        o[0] += a0.x; o[1] += a0.y; o[2] += a0.z; o[3] += a0.w;
        o[4] += a1.x; o[5] += a1.y; o[6] += a1.z; o[7] += a1.w;
      }
      float inv = 1.f / L;
#pragma unroll
      for (int d = 0; d < 8; d++) at[hh * 8 + d][nn] = o[d] * inv;
    }
    __syncthreads();
    int mq = tid >> 4, pp = (tid & 15) * 2;
    float acc[4][2] = {};
#pragma unroll 8
    for (int k = 0; k < 64; k++) {
      float4 w4 = *(const float4*)&wsh[k][mq * 4];
      float2 b2 = *(const float2*)&at[k][pp];
      acc[0][0] = fmaf(w4.x, b2.x, acc[0][0]);
      acc[0][1] = fmaf(w4.x, b2.y, acc[0][1]);
      acc[1][0] = fmaf(w4.y, b2.x, acc[1][0]);
      acc[1][1] = fmaf(w4.y, b2.y, acc[1][1]);
      acc[2][0] = fmaf(w4.z, b2.x, acc[2][0]);
      acc[2][1] = fmaf(w4.z, b2.y, acc[2][1]);
      acc[3][0] = fmaf(w4.w, b2.x, acc[3][0]);
      acc[3][1] = fmaf(w4.w, b2.y, acc[3][1]);
    }
    float v[4][2], sn0 = 0.f, sn1 = 0.f, qn0 = 0.f, qn1 = 0.f;
#pragma unroll
    for (int im = 0; im < 4; im++) {
      int row = mq * 4 + im;
      float bpv = projB[row];
      const float2 xr = *(const float2*)&x[row * NPIX + n0 + pp];
      float v0 = acc[im][0] + bpv + xr.x;
      float v1 = acc[im][1] + bpv + xr.y;
      v[im][0] = v0;
      v[im][1] = v1;
      sn0 += v0;
      qn0 = fmaf(v0, v0, qn0);
      sn1 += v1;
      qn1 = fmaf(v1, v1, qn1);
    }
    if (ch == 0) {
#pragma unroll
      for (int im = 0; im < 4; im++)
        *(float2*)&x1[(mq * 4 + im) * NPIX + n0 + pp] =
            make_float2(v[im][0], v[im][1]);
    }
    ps[mq][pp] = sn0;
    ps[mq][pp + 1] = sn1;
    pq[mq][pp] = qn0;
    pq[mq][pp + 1] = qn1;
    __syncthreads();
    // Stage W1 slice into the (now free) weight buffer; tid<32 does LN stats.
    {
      const float4* w1r = (const float4*)&ffn1W[(ch * 64 + mm) * 64 + kg];
      float4 u0 = w1r[0], u1 = w1r[1], u2 = w1r[2], u3 = w1r[3];
      float uv[16] = {u0.x, u0.y, u0.z, u0.w, u1.x, u1.y, u1.z, u1.w,
                      u2.x, u2.y, u2.z, u2.w, u3.x, u3.y, u3.z, u3.w};
#pragma unroll
      for (int j = 0; j < 16; j++) wsh[kg + j][mm] = uv[j];
    }
    if (tid < 32) {
      float s = 0.f, q = 0.f;
#pragma unroll
      for (int t = 0; t < 16; t++) {
        s += ps[t][tid];
        q += pq[t][tid];
      }
      float mu = s * (1.f / 64.f);
      mus[tid] = mu;
      rss[tid] = rsqrtf(q * (1.f / 64.f) - mu * mu + 1e-5f);
    }
    __syncthreads();
    {
      float mu0 = mus[pp], mu1v = mus[pp + 1];
      float rs0 = rss[pp], rs1v = rss[pp + 1];
#pragma unroll
      for (int im = 0; im < 4; im++) {
        int row = mq * 4 + im;
        float w2v = ln2w[row], b2v = ln2b[row];
        *(float2*)&xsl[row][pp] =
            make_float2((v[im][0] - mu0) * rs0 * w2v + b2v,
                        (v[im][1] - mu1v) * rs1v * w2v + b2v);
      }
    }
    __syncthreads();
    float a2[4][2] = {};
#pragma unroll 8
    for (int k = 0; k < 64; k++) {
      float4 w4 = *(const float4*)&wsh[k][mq * 4];
      float2 b2 = *(const float2*)&xsl[k][pp];
      a2[0][0] = fmaf(w4.x, b2.x, a2[0][0]);
      a2[0][1] = fmaf(w4.x, b2.y, a2[0][1]);
      a2[1][0] = fmaf(w4.y, b2.x, a2[1][0]);
      a2[1][1] = fmaf(w4.y, b2.y, a2[1][1]);
      a2[2][0] = fmaf(w4.z, b2.x, a2[2][0]);
      a2[2][1] = fmaf(w4.z, b2.y, a2[2][1]);
      a2[3][0] = fmaf(w4.w, b2.x, a2[3][0]);
      a2[3][1] = fmaf(w4.w, b2.y, a2[3][1]);
    }
#pragma unroll
    for (int im = 0; im < 4; im++) {
      int row = ch * 64 + mq * 4 + im;
      float bb = ffn1B[row];
      *(float2*)&f1[row * NPIX + n0 + pp] =
          make_float2(a2[im][0] + bb, a2[im][1] + bb);
    }
  }
  gbar(&ctr[3]);

  // ---------------- Stage 5: ffn2_dw (512 units) ----------------
  {
    float(&xs2)[16][260] = u.s5.xs2;
    float(&wshT)[32][260] = u.s5.wshT;
    int n0 = (bid & 255) * 16, m0 = (bid >> 8) * 32;
    int y = n0 >> 6, x0 = n0 & 63;
    {
      int mm = tid >> 3, kg = (tid & 7) * 32;
      const float4* src = (const float4*)&ffn2W[(m0 + mm) * 256 + kg];
      float4* dst = (float4*)&wshT[mm][kg];
#pragma unroll
      for (int i = 0; i < 8; i++) dst[i] = src[i];
    }
    {
      int px4 = (tid & 3) * 4;
      int xabs = x0 + px4;
#pragma unroll
      for (int k = 0; k < 4; k++) {
        int c = (tid >> 2) + 64 * k;
        const float* base = f1 + c * NPIX;
        float wv[9];
#pragma unroll
        for (int i = 0; i < 9; i++) wv[i] = dww[c * 9 + i];
        float bc = dwb[c];
        float a[4] = {bc, bc, bc, bc};
#pragma unroll
        for (int dy = 0; dy < 3; dy++) {
          int yy = y + dy - 1;
          if (yy < 0 || yy > 63) continue;
          const float* row = base + yy * IMG + xabs;
          float4 mid = *(const float4*)row;
          float left = (xabs > 0) ? row[-1] : 0.f;
          float right = (xabs + 4 < IMG) ? row[4] : 0.f;
          float win[6] = {left, mid.x, mid.y, mid.z, mid.w, right};
#pragma unroll
          for (int o = 0; o < 4; o++)
#pragma unroll
            for (int dx = 0; dx < 3; dx++)
              a[o] = fmaf(wv[dy * 3 + dx], win[o + dx], a[o]);
        }
#pragma unroll
        for (int o = 0; o < 4; o++)
          xs2[px4 + o][c] =
              0.5f * a[o] * (1.f + erff(a[o] * 0.70710678118654752f));
      }
    }
    __syncthreads();
    int m = tid >> 3, np = (tid & 7) * 2;
    float a0 = 0.f, a1 = 0.f;
#pragma unroll 4
    for (int k4 = 0; k4 < 64; k4++) {
      float4 w4 = *(const float4*)&wshT[m][k4 * 4];
      float4 xa = *(const float4*)&xs2[np][k4 * 4];
      float4 xb = *(const float4*)&xs2[np + 1][k4 * 4];
      a0 = fmaf(w4.x, xa.x, a0);
      a1 = fmaf(w4.x, xb.x, a1);
      a0 = fmaf(w4.y, xa.y, a0);
      a1 = fmaf(w4.y, xb.y, a1);
      a0 = fmaf(w4.z, xa.z, a0);
      a1 = fmaf(w4.z, xb.z, a1);
      a0 = fmaf(w4.w, xa.w, a0);
      a1 = fmaf(w4.w, xb.w, a1);
    }
    int row = m0 + m;
    float bv = ffn2B[row];
    const float2 rr = *(const float2*)&x1[row * NPIX + n0 + np];
    *(float2*)&out[row * NPIX + n0 + np] =
        make_float2(a0 + bv + rr.x, a1 + bv + rr.y);
  }
}

// ---------------------------------------------------------------------------
extern "C" void kernel_launch(void* const* d_in, const int* in_sizes, int n_in,
                              void* d_out, int out_size, void* d_ws,
                              size_t ws_size, hipStream_t stream) {
  const float* x      = (const float*)d_in[0];
  const float* luma   = (const float*)d_in[1];
  const float* ln1_w  = (const float*)d_in[2];
  const float* ln1_b  = (const float*)d_in[3];
  const float* qkv_w  = (const float*)d_in[4];
  const float* qkv_b  = (const float*)d_in[5];
  const float* proj_w = (const float*)d_in[6];
  const float* proj_b = (const float*)d_in[7];
  const float* lc1_w  = (const float*)d_in[8];
  const float* lc1_b  = (const float*)d_in[9];
  const float* lc2_w  = (const float*)d_in[10];
  const float* lc2_b  = (const float*)d_in[11];
  const float* gam_w  = (const float*)d_in[12];
  const float* gam_b  = (const float*)d_in[13];
  const float* bet_w  = (const float*)d_in[14];
  const float* bet_b  = (const float*)d_in[15];
  const float* alpha  = (const float*)d_in[16];
  const float* ln2_w  = (const float*)d_in[17];
  const float* ln2_b  = (const float*)d_in[18];
  const float* ffn1_w = (const float*)d_in[19];
  const float* ffn1_b = (const float*)d_in[20];
  const float* dw_w   = (const float*)d_in[21];
  const float* dw_b   = (const float*)d_in[22];
  const float* ffn2_w = (const float*)d_in[23];
  const float* ffn2_b = (const float*)d_in[24];
  float* out = (float*)d_out;

  float* w = (float*)d_ws;
  float* pooled = w + 0;        // 4096
  float* bsums  = w + 4096;     // 64 (16 used)
  unsigned short* cbuf = (unsigned short*)(w + 4160);     // 64 f (16 us used)
  float* mu1 = w + 4224;        // 4096
  float* rs1 = w + 8320;        // 4096
  unsigned short* qhl  = (unsigned short*)(w + 12416);    // 262144 f
  unsigned short* khl  = (unsigned short*)(w + 274560);   // 262144 f
  unsigned short* vthx = (unsigned short*)(w + 536704);   // 131072 f
  unsigned short* vtlx = (unsigned short*)(w + 667776);   // 131072 f
  float* pacc = w + 798848;    // 2097152 (JP=8)
  float* pl   = w + 2896000;   // 262144
  float* x1   = w + 3158144;   // 262144
  float* f1   = w + 3420288;   // 1048576
  float* h2   = w + 4468864;   // 131072
  unsigned int* ctr = (unsigned int*)(w + 4599936);  // 8 uints

  init_kernel<<<1, 64, 0, stream>>>(ctr, cbuf);
  fused_kernel<<<dim3(NBLK), 256, 0, stream>>>(
      x, luma, lc1_w, lc1_b, lc2_w, lc2_b, ln1_w, ln1_b, qkv_w, qkv_b, gam_w,
      gam_b, bet_w, bet_b, alpha, proj_w, proj_b, ln2_w, ln2_b, ffn1_w, ffn1_b,
      dw_w, dw_b, ffn2_w, ffn2_b, out, pooled, bsums, cbuf, mu1, rs1, qhl, khl,
      vthx, vtlx, pacc, pl, x1, f1, h2, ctr);
}

// Round 3
// 337.856 us; speedup vs baseline: 1.8227x; 1.8227x over previous
//
#include <hip/hip_runtime.h>
#include <math.h>

// B=1, C=64, H=W=64, N=4096, heads=8, dh=8, inner=64, hid_lc=32, hid_f=256.
// Single persistent fused kernel: 5 stages separated by device-scope grid
// barriers. Grid 512 blocks x 256 threads, co-resident by construction
// (LDS union 49.9 KB -> 3 blocks/CU capacity >= 2 needed; occupancy 24%
// confirmed by rocprof in r2).
//
// r3 barrier fix: r2 used __threadfence() in every wave on BOTH sides of the
// arrival counter. That is a seq_cst device fence = buffer_wbl2 + buffer_inv
// per wave; early blocks invalidated the XCD L2 while late blocks were still
// computing -> rolling-invalidate storm, ~125 us/barrier (535 us total vs
// ~40 us of work). Now: tid0-only asymmetric fences -- RELEASE (wbl2, no inv)
// before arrival, ACQUIRE (inv, no wbl2) after spin-exit, so no cache
// invalidation ever overlaps stage execution.
#define NPIX 4096
#define IMG 64
#define NBLK 512

typedef __attribute__((ext_vector_type(8))) short bf16x8;
typedef __attribute__((ext_vector_type(4))) float floatx4;
typedef __attribute__((ext_vector_type(4))) unsigned int uintx4;

// fp32 -> (hi bf16 in low16) | (lo bf16 in high16), lo = x - f32(hi)
__device__ __forceinline__ unsigned int split_pack(float x) {
  unsigned int u = __float_as_uint(x);
  unsigned int hif = u & 0xffff0000u;
  float lof = x - __uint_as_float(hif);
  return (u >> 16) | (__float_as_uint(lof) & 0xffff0000u);
}

// pack hi16 of two floats in ONE v_perm_b32: low16 = hi16(a), high16 = hi16(b)
__device__ __forceinline__ unsigned int pack_hi2(float a, float b) {
  return __builtin_amdgcn_perm(__float_as_uint(b), __float_as_uint(a),
                               0x07060302u);
}

// Device-scope grid barrier, storm-free version.
// Pre-barrier __syncthreads drains each wave's stores to L2 (compiler emits
// s_waitcnt vmcnt(0) before s_barrier). tid0 then writes back this XCD's L2
// (RELEASE fence: buffer_wbl2 only), arrives, spins on the LLC-resident
// counter, and only after ALL blocks arrived invalidates L1+L2 (ACQUIRE
// fence: buffer_inv only). Post-barrier reads start after the closing
// __syncthreads, i.e. after the inv completed.
__device__ __forceinline__ void gbar(unsigned int* ctr) {
  __syncthreads();
  if (threadIdx.x == 0) {
    __builtin_amdgcn_fence(__ATOMIC_RELEASE, "agent");  // wbl2, no inv
    __hip_atomic_fetch_add(ctr, 1u, __ATOMIC_RELAXED,
                           __HIP_MEMORY_SCOPE_AGENT);
    while (__hip_atomic_load(ctr, __ATOMIC_RELAXED,
                             __HIP_MEMORY_SCOPE_AGENT) < (unsigned)NBLK)
      __builtin_amdgcn_s_sleep(8);
    __builtin_amdgcn_fence(__ATOMIC_ACQUIRE, "agent");  // inv, no wbl2
  }
  __syncthreads();
}

// LDS stage overlays (union keeps the fused kernel at 49.9 KB).
struct S1 {  // lc12
  float lum[400];
  float sw1[288];
  float tin[32][324];
  float swt[4][32][9];
  float red[256];
};
struct S2 {  // ln_qkv
  float xs[64][32];
  float wsh[64][64];
  float h2s[32][32];
  float wgs[32][64];
  float wbs[32][64];
  float mu[32];
  float rs[32];
};
struct S4 {  // proj_ffn1 (single reused weight buffer)
  float at[64][34];
  float wsh[64][64];
  float xsl[64][34];
  float ps[16][32];
  float pq[16][32];
  float mus[32];
  float rss[32];
};
struct S5 {  // ffn2_dw
  float xs2[16][260];
  float wshT[32][260];
};
union SU {
  S1 s1;
  S2 s2;
  S4 s4;
  S5 s5;
};

__global__ void init_kernel(unsigned int* __restrict__ ctr,
                            unsigned short* __restrict__ cbuf) {
  int t = threadIdx.x;
  if (t < 8) ctr[t] = 0u;
  if (t >= 32 && t < 48) cbuf[t - 32] = (t - 32 < 8) ? 0x3F80 : 0;
}

__global__ __launch_bounds__(256, 3) void fused_kernel(
    const float* __restrict__ x, const float* __restrict__ luma,
    const float* __restrict__ lc1w, const float* __restrict__ lc1b,
    const float* __restrict__ lc2w, const float* __restrict__ lc2b,
    const float* __restrict__ ln1w, const float* __restrict__ ln1b,
    const float* __restrict__ qkvW, const float* __restrict__ qkvB,
    const float* __restrict__ gamW, const float* __restrict__ gamB,
    const float* __restrict__ betW, const float* __restrict__ betB,
    const float* __restrict__ alpha, const float* __restrict__ projW,
    const float* __restrict__ projB, const float* __restrict__ ln2w,
    const float* __restrict__ ln2b, const float* __restrict__ ffn1W,
    const float* __restrict__ ffn1B, const float* __restrict__ dww,
    const float* __restrict__ dwb, const float* __restrict__ ffn2W,
    const float* __restrict__ ffn2B, float* __restrict__ out,
    float* __restrict__ pooled, float* __restrict__ bsums,
    unsigned short* __restrict__ cbuf, float* __restrict__ mu1,
    float* __restrict__ rs1, unsigned short* __restrict__ qhl,
    unsigned short* __restrict__ khl, unsigned short* __restrict__ vthx,
    unsigned short* __restrict__ vtlx, float* __restrict__ pacc,
    float* __restrict__ pl, float* __restrict__ x1, float* __restrict__ f1,
    float* __restrict__ h2, unsigned int* __restrict__ ctr) {
  __shared__ SU u;
  int bid = blockIdx.x;
  int tid = threadIdx.x;

  // ---------------- Stage 1: lc12 (128 units) ----------------
  if (bid < 128) {
    int tile = bid >> 3, ocg = bid & 7;
    int ty0 = (tile >> 2) * 16, tx0 = (tile & 3) * 16;
    float(&lum)[400] = u.s1.lum;
    float(&sw1)[288] = u.s1.sw1;
    float(&tin)[32][324] = u.s1.tin;
    float(&swt)[4][32][9] = u.s1.swt;
    float(&red)[256] = u.s1.red;
    for (int idx = tid; idx < 400; idx += 256) {
      int py = idx / 20, px = idx - py * 20;
      int gy = ty0 + py - 2, gx = tx0 + px - 2;
      lum[idx] = (gy >= 0 && gy < IMG && gx >= 0 && gx < IMG)
                     ? luma[gy * IMG + gx]
                     : 0.f;
    }
    for (int idx = tid; idx < 288; idx += 256) sw1[idx] = lc1w[idx];
    for (int idx = tid; idx < 1152; idx += 256) {
      int o = idx / 288, r = idx - o * 288;
      swt[o][r / 9][r % 9] = lc2w[(ocg * 4 + o) * 288 + r];
    }
    __syncthreads();
    for (int idx = tid; idx < 32 * 324; idx += 256) {
      int ic = idx / 324, pos = idx - ic * 324;
      int py = pos / 18, px = pos - py * 18;
      int gy = ty0 + py - 1, gx = tx0 + px - 1;
      float v = 0.f;
      if (gy >= 0 && gy < IMG && gx >= 0 && gx < IMG) {
        float s = lc1b[ic];
        const float* wp = &sw1[ic * 9];
#pragma unroll
        for (int dy = 0; dy < 3; dy++)
#pragma unroll
          for (int dx = 0; dx < 3; dx++)
            s = fmaf(wp[dy * 3 + dx], lum[(py + dy) * 20 + px + dx], s);
        v = fmaxf(s, 0.f);
      }
      tin[ic][pos] = v;
    }
    __syncthreads();
    int ly = tid >> 4, lx = tid & 15;
    int p = (ty0 + ly) * IMG + tx0 + lx;
    float acc[4];
#pragma unroll
    for (int o = 0; o < 4; o++) acc[o] = lc2b[ocg * 4 + o];
    for (int ic = 0; ic < 32; ic++) {
      float v[9];
#pragma unroll
      for (int dy = 0; dy < 3; dy++)
#pragma unroll
        for (int dx = 0; dx < 3; dx++)
          v[dy * 3 + dx] = tin[ic][(ly + dy) * 18 + lx + dx];
#pragma unroll
      for (int o = 0; o < 4; o++)
#pragma unroll
        for (int t = 0; t < 9; t++) acc[o] = fmaf(swt[o][ic][t], v[t], acc[o]);
    }
#pragma unroll
    for (int o = 0; o < 4; o++)
      h2[(ocg * 4 + o) * NPIX + p] = fmaxf(acc[o], 0.f);
    if (ocg == 0) {
      int gy = ty0 + ly, gx = tx0 + lx;
      float sv = 0.f;
#pragma unroll
      for (int dy = 0; dy < 3; dy++)
#pragma unroll
        for (int dx = 0; dx < 3; dx++)
          sv += lum[(ly + dy + 1) * 20 + lx + dx + 1];
      float cy = 3.f - (gy == 0 ? 1.f : 0.f) - (gy == 63 ? 1.f : 0.f);
      float cx = 3.f - (gx == 0 ? 1.f : 0.f) - (gx == 63 ? 1.f : 0.f);
      float pv = (cy * cx - sv) * (1.f / 9.f);
      pooled[p] = pv;
      red[tid] = pv;
      __syncthreads();
      for (int st = 128; st > 0; st >>= 1) {
        if (tid < st) red[tid] += red[tid + st];
        __syncthreads();
      }
      if (tid == 0) bsums[tile] = red[0];
      float s = 0.f, q = 0.f;
#pragma unroll 8
      for (int cc = 0; cc < 64; cc++) {
        float xv = x[cc * NPIX + p];
        s += xv;
        q = fmaf(xv, xv, q);
      }
      float mu = s * (1.f / 64.f);
      mu1[p] = mu;
      rs1[p] = rsqrtf(q * (1.f / 64.f) - mu * mu + 1e-5f);
    }
  }
  gbar(&ctr[0]);

  // ---------------- Stage 2: ln_qkv (384 units) ----------------
  if (bid < 384) {
    const float QSCALE = 0.35355339059327376f * 1.4426950408889634f;
    float(&xs)[64][32] = u.s2.xs;
    float(&wsh)[64][64] = u.s2.wsh;
    float(&h2s)[32][32] = u.s2.h2s;
    float(&wgs)[32][64] = u.s2.wgs;
    float(&wbs)[32][64] = u.s2.wbs;
    float(&mu)[32] = u.s2.mu;
    float(&rs)[32] = u.s2.rs;
    int n0 = (bid & 127) * 32, part = bid >> 7, m0 = part * 64;
    if (tid < 32) {
      mu[tid] = mu1[n0 + tid];
      rs[tid] = rs1[n0 + tid];
    }
    {
      int e = tid * 2;
      int c = e >> 3, off = (e & 7) * 4;
      *(float4*)&xs[c][off] = *(const float4*)&x[c * NPIX + n0 + off];
      int e1 = e + 1;
      int c1 = e1 >> 3, off1 = (e1 & 7) * 4;
      *(float4*)&xs[c1][off1] = *(const float4*)&x[c1 * NPIX + n0 + off1];
    }
    {
      int m = tid >> 2, kg = (tid & 3) * 16;
      const float4* wr = (const float4*)&qkvW[(m0 + m) * 64 + kg];
      float4 w0 = wr[0], w1 = wr[1], w2 = wr[2], w3 = wr[3];
      float wv[16] = {w0.x, w0.y, w0.z, w0.w, w1.x, w1.y, w1.z, w1.w,
                      w2.x, w2.y, w2.z, w2.w, w3.x, w3.y, w3.z, w3.w};
#pragma unroll
      for (int j = 0; j < 16; j++) wsh[kg + j][m] = wv[j];
    }
    {
      int k = tid >> 3, nf = (tid & 7) * 4;
      *(float4*)&h2s[k][nf] = *(const float4*)&h2[k * NPIX + n0 + nf];
    }
    {
      int m = tid >> 2, kg = (tid & 3) * 8;
      const float4* g0 = (const float4*)&gamW[m * 32 + kg];
      float4 a = g0[0], b4 = g0[1];
      float gv[8] = {a.x, a.y, a.z, a.w, b4.x, b4.y, b4.z, b4.w};
#pragma unroll
      for (int j = 0; j < 8; j++) wgs[kg + j][m] = gv[j];
      const float4* bb0 = (const float4*)&betW[m * 32 + kg];
      float4 c4 = bb0[0], d4 = bb0[1];
      float bv[8] = {c4.x, c4.y, c4.z, c4.w, d4.x, d4.y, d4.z, d4.w};
#pragma unroll
      for (int j = 0; j < 8; j++) wbs[kg + j][m] = bv[j];
    }
    __syncthreads();
    {
      int c = tid >> 2, pg = (tid & 3) * 8;
      float wc = ln1w[c], bc = ln1b[c];
#pragma unroll
      for (int j = 0; j < 8; j++) {
        int p = pg + j;
        xs[c][p] = (xs[c][p] - mu[p]) * rs[p] * wc + bc;
      }
    }
    __syncthreads();
    int tx = tid & 15, ty = tid >> 4;
    float ga[4][2] = {}, ba[4][2] = {};
#pragma unroll 8
    for (int kk = 0; kk < 32; kk++) {
      float4 wg4 = *(const float4*)&wgs[kk][ty * 4];
      float4 wb4 = *(const float4*)&wbs[kk][ty * 4];
      float2 h22 = *(const float2*)&h2s[kk][tx * 2];
      float gv[4] = {wg4.x, wg4.y, wg4.z, wg4.w};
      float bv[4] = {wb4.x, wb4.y, wb4.z, wb4.w};
      float hv[2] = {h22.x, h22.y};
#pragma unroll
      for (int im = 0; im < 4; im++)
#pragma unroll
        for (int in = 0; in < 2; in++) {
          ga[im][in] = fmaf(gv[im], hv[in], ga[im][in]);
          ba[im][in] = fmaf(bv[im], hv[in], ba[im][in]);
        }
    }
#pragma unroll
    for (int im = 0; im < 4; im++) {
      int cc = ty * 4 + im;
      float gb = gamB[cc], bb2 = betB[cc];
#pragma unroll
      for (int in = 0; in < 2; in++) {
        ga[im][in] += gb;
        ba[im][in] += bb2;
      }
    }
    float acc[4][2] = {};
#pragma unroll 8
    for (int kk = 0; kk < 64; kk++) {
      float4 a = *(const float4*)&wsh[kk][ty * 4];
      float2 b2 = *(const float2*)&xs[kk][tx * 2];
      float av[4] = {a.x, a.y, a.z, a.w};
      float bv[2] = {b2.x, b2.y};
#pragma unroll
      for (int im = 0; im < 4; im++)
#pragma unroll
        for (int in = 0; in < 2; in++)
          acc[im][in] = fmaf(av[im], bv[in], acc[im][in]);
    }
    float val[4][2];
#pragma unroll
    for (int im = 0; im < 4; im++) {
      int cc = ty * 4 + im;
      float bv = qkvB[m0 + cc];
#pragma unroll
      for (int in = 0; in < 2; in++)
        val[im][in] = fmaf(ga[im][in], acc[im][in] + bv, ba[im][in]);
    }
    if (part == 0) {
      float msum = 0.f;
#pragma unroll
      for (int t = 0; t < 16; t++) msum += bsums[t];
      float mean = msum * (1.f / 4096.f);
      float a0 = alpha[0];
      const float2 pv = *(const float2*)&pooled[n0 + tx * 2];
      float iv[2] = {a0 * (pv.x - mean), a0 * (pv.y - mean)};
#pragma unroll
      for (int im = 0; im < 4; im++)
#pragma unroll
        for (int in = 0; in < 2; in++)
          val[im][in] = (val[im][in] + iv[in]) * QSCALE;
    }
    if (part < 2) {
      unsigned short* dst = (part == 0) ? qhl : khl;
      int hh = ty >> 1, d0 = (ty & 1) * 4;
#pragma unroll
      for (int in = 0; in < 2; in++) {
        int n = n0 + tx * 2 + in;
        unsigned int pk[4];
#pragma unroll
        for (int im = 0; im < 4; im++) pk[im] = split_pack(val[im][in]);
        short4 hi, lo;
        hi.x = (short)(pk[0] & 0xffffu); hi.y = (short)(pk[1] & 0xffffu);
        hi.z = (short)(pk[2] & 0xffffu); hi.w = (short)(pk[3] & 0xffffu);
        lo.x = (short)(pk[0] >> 16); lo.y = (short)(pk[1] >> 16);
        lo.z = (short)(pk[2] >> 16); lo.w = (short)(pk[3] >> 16);
        unsigned short* base = dst + ((size_t)(hh * NPIX + n) << 4) + d0;
        *(short4*)base = hi;
        *(short4*)(base + 8) = lo;
      }
    } else {
      int nq = n0 + tx * 2;
      int off0 = (nq >> 5) * 32 + ((nq >> 4) & 1) * 4 + ((nq >> 2) & 3) * 8 +
                 (nq & 3);
#pragma unroll
      for (int im = 0; im < 4; im++) {
        int cc = ty * 4 + im;
        unsigned int pk0 = split_pack(val[im][0]);
        unsigned int pk1 = split_pack(val[im][1]);
        short2 hi, lo;
        hi.x = (short)(pk0 & 0xffffu);
        hi.y = (short)(pk1 & 0xffffu);
        lo.x = (short)(pk0 >> 16);
        lo.y = (short)(pk1 >> 16);
        *(short2*)(vthx + (size_t)cc * NPIX + off0) = hi;
        *(short2*)(vtlx + (size_t)cc * NPIX + off0) = lo;
      }
    }
  }
  gbar(&ctr[1]);

  // ---------------- Stage 3: attn (1024 units, 2 per block) ----------------
  {
    int wave = tid >> 6, lane = tid & 63;
    int g = lane >> 4, c = lane & 15;
#pragma unroll 1
    for (int rep = 0; rep < 2; rep++) {
      int unit = bid * 2 + rep;
      int h = (unit >> 4) & 7, jp = unit >> 7;
      int i0 = (unit & 15) * 256 + wave * 64;
      int jbase = jp * 512;
      bf16x8 qB[4];
#pragma unroll
      for (int t = 0; t < 4; t++)
        qB[t] = *(const bf16x8*)(qhl +
                                 ((size_t)(h * NPIX + i0 + t * 16 + c) << 4) +
                                 ((g & 1) << 3));
      const unsigned short* kp =
          khl + ((size_t)(h * NPIX + jbase + c) << 4) + ((g >> 1) << 3);
      const unsigned short* vhp;
      const unsigned short* vlp;
      int vstep;
      if (c < 8) {
        vhp = vthx + (size_t)(h * 8 + c) * NPIX + jbase + (g << 3);
        vlp = vtlx + (size_t)(h * 8 + c) * NPIX + jbase + (g << 3);
        vstep = 32;
      } else {
        vhp = (c == 8) ? cbuf : (cbuf + 8);  // ones row / zero rows
        vlp = cbuf + 8;
        vstep = 0;
      }
      floatx4 zero4 = {0.f, 0.f, 0.f, 0.f};
      floatx4 aH[4], aM[4];
#pragma unroll
      for (int t = 0; t < 4; t++) {
        aH[t] = zero4;
        aM[t] = zero4;
      }
#pragma unroll 4
      for (int jt = 0; jt < 16; ++jt) {
        bf16x8 ka0 = *(const bf16x8*)kp;
        bf16x8 ka1 = *(const bf16x8*)(kp + 256);
        bf16x8 avh = *(const bf16x8*)vhp;
        bf16x8 avl = *(const bf16x8*)vlp;
        kp += 512;
        vhp += vstep;
        vlp += vstep;
#pragma unroll
        for (int t = 0; t < 4; t++) {
          floatx4 s0 = __builtin_amdgcn_mfma_f32_16x16x32_bf16(ka0, qB[t],
                                                               zero4, 0, 0, 0);
          floatx4 s1 = __builtin_amdgcn_mfma_f32_16x16x32_bf16(ka1, qB[t],
                                                               zero4, 0, 0, 0);
          float p0 = __builtin_amdgcn_exp2f(fminf(s0[0], 80.f));
          float p1 = __builtin_amdgcn_exp2f(fminf(s0[1], 80.f));
          float p2 = __builtin_amdgcn_exp2f(fminf(s0[2], 80.f));
          float p3 = __builtin_amdgcn_exp2f(fminf(s0[3], 80.f));
          float p4 = __builtin_amdgcn_exp2f(fminf(s1[0], 80.f));
          float p5 = __builtin_amdgcn_exp2f(fminf(s1[1], 80.f));
          float p6 = __builtin_amdgcn_exp2f(fminf(s1[2], 80.f));
          float p7 = __builtin_amdgcn_exp2f(fminf(s1[3], 80.f));
          uintx4 bh;
          bh.x = pack_hi2(p0, p1);
          bh.y = pack_hi2(p2, p3);
          bh.z = pack_hi2(p4, p5);
          bh.w = pack_hi2(p6, p7);
          bf16x8 pbh = __builtin_bit_cast(bf16x8, bh);
          aH[t] =
              __builtin_amdgcn_mfma_f32_16x16x32_bf16(avh, pbh, aH[t], 0, 0, 0);
          aM[t] =
              __builtin_amdgcn_mfma_f32_16x16x32_bf16(avl, pbh, aM[t], 0, 0, 0);
        }
      }
#pragma unroll
      for (int t = 0; t < 4; t++) {
        floatx4 o = aH[t] + aM[t];
        if (g < 2) {
          size_t b0 = (size_t)((jp * 8 + h) * NPIX + i0 + t * 16 + c);
          *(float4*)&pacc[b0 * 8 + g * 4] = make_float4(o[0], o[1], o[2], o[3]);
        } else if (g == 2) {
          pl[(size_t)((jp * 8 + h) * NPIX + i0 + t * 16 + c)] = o[0];
        }
      }
    }
  }
  gbar(&ctr[2]);

  // ---------------- Stage 4: proj_ffn1 (512 units) ----------------
  {
    float(&at)[64][34] = u.s4.at;
    float(&wsh)[64][64] = u.s4.wsh;
    float(&xsl)[64][34] = u.s4.xsl;
    float(&ps)[16][32] = u.s4.ps;
    float(&pq)[16][32] = u.s4.pq;
    float(&mus)[32] = u.s4.mus;
    float(&rss)[32] = u.s4.rss;
    int n0 = (bid & 127) * 32;
    int ch = bid >> 7;
    int mm = tid >> 2, kg = (tid & 3) * 16;
    {
      const float4* wr = (const float4*)&projW[mm * 64 + kg];
      float4 w0 = wr[0], w1 = wr[1], w2 = wr[2], w3 = wr[3];
      float wv[16] = {w0.x, w0.y, w0.z, w0.w, w1.x, w1.y, w1.z, w1.w,
                      w2.x, w2.y, w2.z, w2.w, w3.x, w3.y, w3.z, w3.w};
#pragma unroll
      for (int j = 0; j < 16; j++) wsh[kg + j][mm] = wv[j];
    }
    {
      int hh = tid >> 5, nn = tid & 31;
      int i = n0 + nn;
      float L = 0.f, o[8] = {};
#pragma unroll
      for (int p = 0; p < 8; p++) {
        size_t base = (size_t)((p * 8 + hh) * NPIX + i);
        L += pl[base];
        const float4 a0 = *(const float4*)&pacc[base * 8];
        const float4 a1 = *(const float4*)&pacc[base * 8 + 4];
        o[0] += a0.x; o[1] += a0.y; o[2] += a0.z; o[3] += a0.w;
        o[4] += a1.x; o[5] += a1.y; o[6] += a1.z; o[7] += a1.w;
      }
      float inv = 1.f / L;
#pragma unroll
      for (int d = 0; d < 8; d++) at[hh * 8 + d][nn] = o[d] * inv;
    }
    __syncthreads();
    int mq = tid >> 4, pp = (tid & 15) * 2;
    float acc[4][2] = {};
#pragma unroll 8
    for (int k = 0; k < 64; k++) {
      float4 w4 = *(const float4*)&wsh[k][mq * 4];
      float2 b2 = *(const float2*)&at[k][pp];
      acc[0][0] = fmaf(w4.x, b2.x, acc[0][0]);
      acc[0][1] = fmaf(w4.x, b2.y, acc[0][1]);
      acc[1][0] = fmaf(w4.y, b2.x, acc[1][0]);
      acc[1][1] = fmaf(w4.y, b2.y, acc[1][1]);
      acc[2][0] = fmaf(w4.z, b2.x, acc[2][0]);
      acc[2][1] = fmaf(w4.z, b2.y, acc[2][1]);
      acc[3][0] = fmaf(w4.w, b2.x, acc[3][0]);
      acc[3][1] = fmaf(w4.w, b2.y, acc[3][1]);
    }
    float v[4][2], sn0 = 0.f, sn1 = 0.f, qn0 = 0.f, qn1 = 0.f;
#pragma unroll
    for (int im = 0; im < 4; im++) {
      int row = mq * 4 + im;
      float bpv = projB[row];
      const float2 xr = *(const float2*)&x[row * NPIX + n0 + pp];
      float v0 = acc[im][0] + bpv + xr.x;
      float v1 = acc[im][1] + bpv + xr.y;
      v[im][0] = v0;
      v[im][1] = v1;
      sn0 += v0;
      qn0 = fmaf(v0, v0, qn0);
      sn1 += v1;
      qn1 = fmaf(v1, v1, qn1);
    }
    if (ch == 0) {
#pragma unroll
      for (int im = 0; im < 4; im++)
        *(float2*)&x1[(mq * 4 + im) * NPIX + n0 + pp] =
            make_float2(v[im][0], v[im][1]);
    }
    ps[mq][pp] = sn0;
    ps[mq][pp + 1] = sn1;
    pq[mq][pp] = qn0;
    pq[mq][pp + 1] = qn1;
    __syncthreads();
    // Stage W1 slice into the (now free) weight buffer; tid<32 does LN stats.
    {
      const float4* w1r = (const float4*)&ffn1W[(ch * 64 + mm) * 64 + kg];
      float4 u0 = w1r[0], u1 = w1r[1], u2 = w1r[2], u3 = w1r[3];
      float uv[16] = {u0.x, u0.y, u0.z, u0.w, u1.x, u1.y, u1.z, u1.w,
                      u2.x, u2.y, u2.z, u2.w, u3.x, u3.y, u3.z, u3.w};
#pragma unroll
      for (int j = 0; j < 16; j++) wsh[kg + j][mm] = uv[j];
    }
    if (tid < 32) {
      float s = 0.f, q = 0.f;
#pragma unroll
      for (int t = 0; t < 16; t++) {
        s += ps[t][tid];
        q += pq[t][tid];
      }
      float mu = s * (1.f / 64.f);
      mus[tid] = mu;
      rss[tid] = rsqrtf(q * (1.f / 64.f) - mu * mu + 1e-5f);
    }
    __syncthreads();
    {
      float mu0 = mus[pp], mu1v = mus[pp + 1];
      float rs0 = rss[pp], rs1v = rss[pp + 1];
#pragma unroll
      for (int im = 0; im < 4; im++) {
        int row = mq * 4 + im;
        float w2v = ln2w[row], b2v = ln2b[row];
        *(float2*)&xsl[row][pp] =
            make_float2((v[im][0] - mu0) * rs0 * w2v + b2v,
                        (v[im][1] - mu1v) * rs1v * w2v + b2v);
      }
    }
    __syncthreads();
    float a2[4][2] = {};
#pragma unroll 8
    for (int k = 0; k < 64; k++) {
      float4 w4 = *(const float4*)&wsh[k][mq * 4];
      float2 b2 = *(const float2*)&xsl[k][pp];
      a2[0][0] = fmaf(w4.x, b2.x, a2[0][0]);
      a2[0][1] = fmaf(w4.x, b2.y, a2[0][1]);
      a2[1][0] = fmaf(w4.y, b2.x, a2[1][0]);
      a2[1][1] = fmaf(w4.y, b2.y, a2[1][1]);
      a2[2][0] = fmaf(w4.z, b2.x, a2[2][0]);
      a2[2][1] = fmaf(w4.z, b2.y, a2[2][1]);
      a2[3][0] = fmaf(w4.w, b2.x, a2[3][0]);
      a2[3][1] = fmaf(w4.w, b2.y, a2[3][1]);
    }
#pragma unroll
    for (int im = 0; im < 4; im++) {
      int row = ch * 64 + mq * 4 + im;
      float bb = ffn1B[row];
      *(float2*)&f1[row * NPIX + n0 + pp] =
          make_float2(a2[im][0] + bb, a2[im][1] + bb);
    }
  }
  gbar(&ctr[3]);

  // ---------------- Stage 5: ffn2_dw (512 units) ----------------
  {
    float(&xs2)[16][260] = u.s5.xs2;
    float(&wshT)[32][260] = u.s5.wshT;
    int n0 = (bid & 255) * 16, m0 = (bid >> 8) * 32;
    int y = n0 >> 6, x0 = n0 & 63;
    {
      int mm = tid >> 3, kg = (tid & 7) * 32;
      const float4* src = (const float4*)&ffn2W[(m0 + mm) * 256 + kg];
      float4* dst = (float4*)&wshT[mm][kg];
#pragma unroll
      for (int i = 0; i < 8; i++) dst[i] = src[i];
    }
    {
      int px4 = (tid & 3) * 4;
      int xabs = x0 + px4;
#pragma unroll
      for (int k = 0; k < 4; k++) {
        int c = (tid >> 2) + 64 * k;
        const float* base = f1 + c * NPIX;
        float wv[9];
#pragma unroll
        for (int i = 0; i < 9; i++) wv[i] = dww[c * 9 + i];
        float bc = dwb[c];
        float a[4] = {bc, bc, bc, bc};
#pragma unroll
        for (int dy = 0; dy < 3; dy++) {
          int yy = y + dy - 1;
          if (yy < 0 || yy > 63) continue;
          const float* row = base + yy * IMG + xabs;
          float4 mid = *(const float4*)row;
          float left = (xabs > 0) ? row[-1] : 0.f;
          float right = (xabs + 4 < IMG) ? row[4] : 0.f;
          float win[6] = {left, mid.x, mid.y, mid.z, mid.w, right};
#pragma unroll
          for (int o = 0; o < 4; o++)
#pragma unroll
            for (int dx = 0; dx < 3; dx++)
              a[o] = fmaf(wv[dy * 3 + dx], win[o + dx], a[o]);
        }
#pragma unroll
        for (int o = 0; o < 4; o++)
          xs2[px4 + o][c] =
              0.5f * a[o] * (1.f + erff(a[o] * 0.70710678118654752f));
      }
    }
    __syncthreads();
    int m = tid >> 3, np = (tid & 7) * 2;
    float a0 = 0.f, a1 = 0.f;
#pragma unroll 4
    for (int k4 = 0; k4 < 64; k4++) {
      float4 w4 = *(const float4*)&wshT[m][k4 * 4];
      float4 xa = *(const float4*)&xs2[np][k4 * 4];
      float4 xb = *(const float4*)&xs2[np + 1][k4 * 4];
      a0 = fmaf(w4.x, xa.x, a0);
      a1 = fmaf(w4.x, xb.x, a1);
      a0 = fmaf(w4.y, xa.y, a0);
      a1 = fmaf(w4.y, xb.y, a1);
      a0 = fmaf(w4.z, xa.z, a0);
      a1 = fmaf(w4.z, xb.z, a1);
      a0 = fmaf(w4.w, xa.w, a0);
      a1 = fmaf(w4.w, xb.w, a1);
    }
    int row = m0 + m;
    float bv = ffn2B[row];
    const float2 rr = *(const float2*)&x1[row * NPIX + n0 + np];
    *(float2*)&out[row * NPIX + n0 + np] =
        make_float2(a0 + bv + rr.x, a1 + bv + rr.y);
  }
}

// ---------------------------------------------------------------------------
extern "C" void kernel_launch(void* const* d_in, const int* in_sizes, int n_in,
                              void* d_out, int out_size, void* d_ws,
                              size_t ws_size, hipStream_t stream) {
  const float* x      = (const float*)d_in[0];
  const float* luma   = (const float*)d_in[1];
  const float* ln1_w  = (const float*)d_in[2];
  const float* ln1_b  = (const float*)d_in[3];
  const float* qkv_w  = (const float*)d_in[4];
  const float* qkv_b  = (const float*)d_in[5];
  const float* proj_w = (const float*)d_in[6];
  const float* proj_b = (const float*)d_in[7];
  const float* lc1_w  = (const float*)d_in[8];
  const float* lc1_b  = (const float*)d_in[9];
  const float* lc2_w  = (const float*)d_in[10];
  const float* lc2_b  = (const float*)d_in[11];
  const float* gam_w  = (const float*)d_in[12];
  const float* gam_b  = (const float*)d_in[13];
  const float* bet_w  = (const float*)d_in[14];
  const float* bet_b  = (const float*)d_in[15];
  const float* alpha  = (const float*)d_in[16];
  const float* ln2_w  = (const float*)d_in[17];
  const float* ln2_b  = (const float*)d_in[18];
  const float* ffn1_w = (const float*)d_in[19];
  const float* ffn1_b = (const float*)d_in[20];
  const float* dw_w   = (const float*)d_in[21];
  const float* dw_b   = (const float*)d_in[22];
  const float* ffn2_w = (const float*)d_in[23];
  const float* ffn2_b = (const float*)d_in[24];
  float* out = (float*)d_out;

  float* w = (float*)d_ws;
  float* pooled = w + 0;        // 4096
  float* bsums  = w + 4096;     // 64 (16 used)
  unsigned short* cbuf = (unsigned short*)(w + 4160);     // 64 f (16 us used)
  float* mu1 = w + 4224;        // 4096
  float* rs1 = w + 8320;        // 4096
  unsigned short* qhl  = (unsigned short*)(w + 12416);    // 262144 f
  unsigned short* khl  = (unsigned short*)(w + 274560);   // 262144 f
  unsigned short* vthx = (unsigned short*)(w + 536704);   // 131072 f
  unsigned short* vtlx = (unsigned short*)(w + 667776);   // 131072 f
  float* pacc = w + 798848;    // 2097152 (JP=8)
  float* pl   = w + 2896000;   // 262144
  float* x1   = w + 3158144;   // 262144
  float* f1   = w + 3420288;   // 1048576
  float* h2   = w + 4468864;   // 131072
  unsigned int* ctr = (unsigned int*)(w + 4599936);  // 8 uints

  init_kernel<<<1, 64, 0, stream>>>(ctr, cbuf);
  fused_kernel<<<dim3(NBLK), 256, 0, stream>>>(
      x, luma, lc1_w, lc1_b, lc2_w, lc2_b, ln1_w, ln1_b, qkv_w, qkv_b, gam_w,
      gam_b, bet_w, bet_b, alpha, proj_w, proj_b, ln2_w, ln2_b, ffn1_w, ffn1_b,
      dw_w, dw_b, ffn2_w, ffn2_b, out, pooled, bsums, cbuf, mu1, rs1, qhl, khl,
      vthx, vtlx, pacc, pl, x1, f1, h2, ctr);
}

// Round 4
// 289.678 us; speedup vs baseline: 2.1258x; 1.1663x over previous
//
#include <hip/hip_runtime.h>
#include <math.h>

// B=1, C=64, H=W=64, N=4096, heads=8, dh=8, inner=64, hid_lc=32, hid_f=256.
// Single persistent fused kernel: 5 stages separated by device-scope grid
// barriers. Grid 512 blocks x 256 threads, co-resident by construction
// (LDS union 49.9 KB; occupancy ~24% confirmed by rocprof r2/r3).
//
// r4 barrier fix: r3 still ran buffer_wbl2+buffer_inv once per BLOCK (512
// each per barrier = 64 serialized L2 tag-walks per XCD, ~40 us/barrier).
// Cache maintenance is per-XCD state: now a two-phase barrier where (1) all
// blocks arrive relaxed + spin (arrival is ordered after the block's
// vmcnt(0) drain in __syncthreads, so stores are in own-XCD L2), then (2)
// ONE elected block per physical XCD (s_getreg HW_REG_XCC_ID) does
// wbl2 sc1 + inv sc1 and bumps done; all spin until done==8. 8 walks
// instead of 512. Per-block acquire dropped: no inter-stage buffer is read
// before the barrier publishing it, and CDNA L1 is write-through/no-alloc,
// so the elected per-XCD L2 inv is the only invalidation needed.
#define NPIX 4096
#define IMG 64
#define NBLK 512

typedef __attribute__((ext_vector_type(8))) short bf16x8;
typedef __attribute__((ext_vector_type(4))) float floatx4;
typedef __attribute__((ext_vector_type(4))) unsigned int uintx4;

// fp32 -> (hi bf16 in low16) | (lo bf16 in high16), lo = x - f32(hi)
__device__ __forceinline__ unsigned int split_pack(float x) {
  unsigned int u = __float_as_uint(x);
  unsigned int hif = u & 0xffff0000u;
  float lof = x - __uint_as_float(hif);
  return (u >> 16) | (__float_as_uint(lof) & 0xffff0000u);
}

// pack hi16 of two floats in ONE v_perm_b32: low16 = hi16(a), high16 = hi16(b)
__device__ __forceinline__ unsigned int pack_hi2(float a, float b) {
  return __builtin_amdgcn_perm(__float_as_uint(b), __float_as_uint(a),
                               0x07060302u);
}

// Two-phase elected grid barrier. base layout (16 uints per barrier):
// [0]=arrive, [1..8]=per-XCD election, [9]=done.
__device__ __forceinline__ void gbar(unsigned int* base) {
  __syncthreads();  // emits s_waitcnt vmcnt(0) lgkmcnt(0): stores are in L2
  if (threadIdx.x == 0) {
    __hip_atomic_fetch_add(base, 1u, __ATOMIC_RELAXED,
                           __HIP_MEMORY_SCOPE_AGENT);
    while (__hip_atomic_load(base, __ATOMIC_RELAXED,
                             __HIP_MEMORY_SCOPE_AGENT) < (unsigned)NBLK)
      __builtin_amdgcn_s_sleep(4);
    // All blocks' stores now resident in their XCD L2. Elect one block per
    // physical XCD to write back + invalidate that L2.
    unsigned int xcc;
    asm volatile("s_getreg_b32 %0, hwreg(HW_REG_XCC_ID)" : "=s"(xcc));
    xcc &= 7u;
    if (__hip_atomic_fetch_add(base + 1 + xcc, 1u, __ATOMIC_RELAXED,
                               __HIP_MEMORY_SCOPE_AGENT) == 0u) {
      asm volatile(
          "buffer_wbl2 sc1\n\t"
          "s_waitcnt vmcnt(0)\n\t"
          "buffer_inv sc1\n\t"
          "s_waitcnt vmcnt(0)" ::: "memory");
      __hip_atomic_fetch_add(base + 9, 1u, __ATOMIC_RELAXED,
                             __HIP_MEMORY_SCOPE_AGENT);
    }
    while (__hip_atomic_load(base + 9, __ATOMIC_RELAXED,
                             __HIP_MEMORY_SCOPE_AGENT) < 8u)
      __builtin_amdgcn_s_sleep(2);
    asm volatile("" ::: "memory");
  }
  __syncthreads();
}

// LDS stage overlays (union keeps the fused kernel at 49.9 KB).
struct S1 {  // lc12
  float lum[400];
  float sw1[288];
  float tin[32][324];
  float swt[4][32][9];
  float red[256];
};
struct S2 {  // ln_qkv
  float xs[64][32];
  float wsh[64][64];
  float h2s[32][32];
  float wgs[32][64];
  float wbs[32][64];
  float mu[32];
  float rs[32];
};
struct S4 {  // proj_ffn1 (single reused weight buffer)
  float at[64][34];
  float wsh[64][64];
  float xsl[64][34];
  float ps[16][32];
  float pq[16][32];
  float mus[32];
  float rss[32];
};
struct S5 {  // ffn2_dw
  float xs2[16][260];
  float wshT[32][260];
};
union SU {
  S1 s1;
  S2 s2;
  S4 s4;
  S5 s5;
};

__global__ void init_kernel(unsigned int* __restrict__ ctr,
                            unsigned short* __restrict__ cbuf) {
  int t = threadIdx.x;
  if (t < 64) ctr[t] = 0u;
  if (t >= 64 && t < 80) cbuf[t - 64] = (t - 64 < 8) ? 0x3F80 : 0;
}

__global__ __launch_bounds__(256, 3) void fused_kernel(
    const float* __restrict__ x, const float* __restrict__ luma,
    const float* __restrict__ lc1w, const float* __restrict__ lc1b,
    const float* __restrict__ lc2w, const float* __restrict__ lc2b,
    const float* __restrict__ ln1w, const float* __restrict__ ln1b,
    const float* __restrict__ qkvW, const float* __restrict__ qkvB,
    const float* __restrict__ gamW, const float* __restrict__ gamB,
    const float* __restrict__ betW, const float* __restrict__ betB,
    const float* __restrict__ alpha, const float* __restrict__ projW,
    const float* __restrict__ projB, const float* __restrict__ ln2w,
    const float* __restrict__ ln2b, const float* __restrict__ ffn1W,
    const float* __restrict__ ffn1B, const float* __restrict__ dww,
    const float* __restrict__ dwb, const float* __restrict__ ffn2W,
    const float* __restrict__ ffn2B, float* __restrict__ out,
    float* __restrict__ pooled, float* __restrict__ bsums,
    unsigned short* __restrict__ cbuf, float* __restrict__ mu1,
    float* __restrict__ rs1, unsigned short* __restrict__ qhl,
    unsigned short* __restrict__ khl, unsigned short* __restrict__ vthx,
    unsigned short* __restrict__ vtlx, float* __restrict__ pacc,
    float* __restrict__ pl, float* __restrict__ x1, float* __restrict__ f1,
    float* __restrict__ h2, unsigned int* __restrict__ ctr) {
  __shared__ SU u;
  int bid = blockIdx.x;
  int tid = threadIdx.x;

  // ---------------- Stage 1: lc12 (128 units) ----------------
  if (bid < 128) {
    int tile = bid >> 3, ocg = bid & 7;
    int ty0 = (tile >> 2) * 16, tx0 = (tile & 3) * 16;
    float(&lum)[400] = u.s1.lum;
    float(&sw1)[288] = u.s1.sw1;
    float(&tin)[32][324] = u.s1.tin;
    float(&swt)[4][32][9] = u.s1.swt;
    float(&red)[256] = u.s1.red;
    for (int idx = tid; idx < 400; idx += 256) {
      int py = idx / 20, px = idx - py * 20;
      int gy = ty0 + py - 2, gx = tx0 + px - 2;
      lum[idx] = (gy >= 0 && gy < IMG && gx >= 0 && gx < IMG)
                     ? luma[gy * IMG + gx]
                     : 0.f;
    }
    for (int idx = tid; idx < 288; idx += 256) sw1[idx] = lc1w[idx];
    for (int idx = tid; idx < 1152; idx += 256) {
      int o = idx / 288, r = idx - o * 288;
      swt[o][r / 9][r % 9] = lc2w[(ocg * 4 + o) * 288 + r];
    }
    __syncthreads();
    for (int idx = tid; idx < 32 * 324; idx += 256) {
      int ic = idx / 324, pos = idx - ic * 324;
      int py = pos / 18, px = pos - py * 18;
      int gy = ty0 + py - 1, gx = tx0 + px - 1;
      float v = 0.f;
      if (gy >= 0 && gy < IMG && gx >= 0 && gx < IMG) {
        float s = lc1b[ic];
        const float* wp = &sw1[ic * 9];
#pragma unroll
        for (int dy = 0; dy < 3; dy++)
#pragma unroll
          for (int dx = 0; dx < 3; dx++)
            s = fmaf(wp[dy * 3 + dx], lum[(py + dy) * 20 + px + dx], s);
        v = fmaxf(s, 0.f);
      }
      tin[ic][pos] = v;
    }
    __syncthreads();
    int ly = tid >> 4, lx = tid & 15;
    int p = (ty0 + ly) * IMG + tx0 + lx;
    float acc[4];
#pragma unroll
    for (int o = 0; o < 4; o++) acc[o] = lc2b[ocg * 4 + o];
    for (int ic = 0; ic < 32; ic++) {
      float v[9];
#pragma unroll
      for (int dy = 0; dy < 3; dy++)
#pragma unroll
        for (int dx = 0; dx < 3; dx++)
          v[dy * 3 + dx] = tin[ic][(ly + dy) * 18 + lx + dx];
#pragma unroll
      for (int o = 0; o < 4; o++)
#pragma unroll
        for (int t = 0; t < 9; t++) acc[o] = fmaf(swt[o][ic][t], v[t], acc[o]);
    }
#pragma unroll
    for (int o = 0; o < 4; o++)
      h2[(ocg * 4 + o) * NPIX + p] = fmaxf(acc[o], 0.f);
    if (ocg == 0) {
      int gy = ty0 + ly, gx = tx0 + lx;
      float sv = 0.f;
#pragma unroll
      for (int dy = 0; dy < 3; dy++)
#pragma unroll
        for (int dx = 0; dx < 3; dx++)
          sv += lum[(ly + dy + 1) * 20 + lx + dx + 1];
      float cy = 3.f - (gy == 0 ? 1.f : 0.f) - (gy == 63 ? 1.f : 0.f);
      float cx = 3.f - (gx == 0 ? 1.f : 0.f) - (gx == 63 ? 1.f : 0.f);
      float pv = (cy * cx - sv) * (1.f / 9.f);
      pooled[p] = pv;
      red[tid] = pv;
      __syncthreads();
      for (int st = 128; st > 0; st >>= 1) {
        if (tid < st) red[tid] += red[tid + st];
        __syncthreads();
      }
      if (tid == 0) bsums[tile] = red[0];
      float s = 0.f, q = 0.f;
#pragma unroll 8
      for (int cc = 0; cc < 64; cc++) {
        float xv = x[cc * NPIX + p];
        s += xv;
        q = fmaf(xv, xv, q);
      }
      float mu = s * (1.f / 64.f);
      mu1[p] = mu;
      rs1[p] = rsqrtf(q * (1.f / 64.f) - mu * mu + 1e-5f);
    }
  }
  gbar(ctr + 0);

  // ---------------- Stage 2: ln_qkv (384 units) ----------------
  if (bid < 384) {
    const float QSCALE = 0.35355339059327376f * 1.4426950408889634f;
    float(&xs)[64][32] = u.s2.xs;
    float(&wsh)[64][64] = u.s2.wsh;
    float(&h2s)[32][32] = u.s2.h2s;
    float(&wgs)[32][64] = u.s2.wgs;
    float(&wbs)[32][64] = u.s2.wbs;
    float(&mu)[32] = u.s2.mu;
    float(&rs)[32] = u.s2.rs;
    int n0 = (bid & 127) * 32, part = bid >> 7, m0 = part * 64;
    if (tid < 32) {
      mu[tid] = mu1[n0 + tid];
      rs[tid] = rs1[n0 + tid];
    }
    {
      int e = tid * 2;
      int c = e >> 3, off = (e & 7) * 4;
      *(float4*)&xs[c][off] = *(const float4*)&x[c * NPIX + n0 + off];
      int e1 = e + 1;
      int c1 = e1 >> 3, off1 = (e1 & 7) * 4;
      *(float4*)&xs[c1][off1] = *(const float4*)&x[c1 * NPIX + n0 + off1];
    }
    {
      int m = tid >> 2, kg = (tid & 3) * 16;
      const float4* wr = (const float4*)&qkvW[(m0 + m) * 64 + kg];
      float4 w0 = wr[0], w1 = wr[1], w2 = wr[2], w3 = wr[3];
      float wv[16] = {w0.x, w0.y, w0.z, w0.w, w1.x, w1.y, w1.z, w1.w,
                      w2.x, w2.y, w2.z, w2.w, w3.x, w3.y, w3.z, w3.w};
#pragma unroll
      for (int j = 0; j < 16; j++) wsh[kg + j][m] = wv[j];
    }
    {
      int k = tid >> 3, nf = (tid & 7) * 4;
      *(float4*)&h2s[k][nf] = *(const float4*)&h2[k * NPIX + n0 + nf];
    }
    {
      int m = tid >> 2, kg = (tid & 3) * 8;
      const float4* g0 = (const float4*)&gamW[m * 32 + kg];
      float4 a = g0[0], b4 = g0[1];
      float gv[8] = {a.x, a.y, a.z, a.w, b4.x, b4.y, b4.z, b4.w};
#pragma unroll
      for (int j = 0; j < 8; j++) wgs[kg + j][m] = gv[j];
      const float4* bb0 = (const float4*)&betW[m * 32 + kg];
      float4 c4 = bb0[0], d4 = bb0[1];
      float bv[8] = {c4.x, c4.y, c4.z, c4.w, d4.x, d4.y, d4.z, d4.w};
#pragma unroll
      for (int j = 0; j < 8; j++) wbs[kg + j][m] = bv[j];
    }
    __syncthreads();
    {
      int c = tid >> 2, pg = (tid & 3) * 8;
      float wc = ln1w[c], bc = ln1b[c];
#pragma unroll
      for (int j = 0; j < 8; j++) {
        int p = pg + j;
        xs[c][p] = (xs[c][p] - mu[p]) * rs[p] * wc + bc;
      }
    }
    __syncthreads();
    int tx = tid & 15, ty = tid >> 4;
    float ga[4][2] = {}, ba[4][2] = {};
#pragma unroll 8
    for (int kk = 0; kk < 32; kk++) {
      float4 wg4 = *(const float4*)&wgs[kk][ty * 4];
      float4 wb4 = *(const float4*)&wbs[kk][ty * 4];
      float2 h22 = *(const float2*)&h2s[kk][tx * 2];
      float gv[4] = {wg4.x, wg4.y, wg4.z, wg4.w};
      float bv[4] = {wb4.x, wb4.y, wb4.z, wb4.w};
      float hv[2] = {h22.x, h22.y};
#pragma unroll
      for (int im = 0; im < 4; im++)
#pragma unroll
        for (int in = 0; in < 2; in++) {
          ga[im][in] = fmaf(gv[im], hv[in], ga[im][in]);
          ba[im][in] = fmaf(bv[im], hv[in], ba[im][in]);
        }
    }
#pragma unroll
    for (int im = 0; im < 4; im++) {
      int cc = ty * 4 + im;
      float gb = gamB[cc], bb2 = betB[cc];
#pragma unroll
      for (int in = 0; in < 2; in++) {
        ga[im][in] += gb;
        ba[im][in] += bb2;
      }
    }
    float acc[4][2] = {};
#pragma unroll 8
    for (int kk = 0; kk < 64; kk++) {
      float4 a = *(const float4*)&wsh[kk][ty * 4];
      float2 b2 = *(const float2*)&xs[kk][tx * 2];
      float av[4] = {a.x, a.y, a.z, a.w};
      float bv[2] = {b2.x, b2.y};
#pragma unroll
      for (int im = 0; im < 4; im++)
#pragma unroll
        for (int in = 0; in < 2; in++)
          acc[im][in] = fmaf(av[im], bv[in], acc[im][in]);
    }
    float val[4][2];
#pragma unroll
    for (int im = 0; im < 4; im++) {
      int cc = ty * 4 + im;
      float bv = qkvB[m0 + cc];
#pragma unroll
      for (int in = 0; in < 2; in++)
        val[im][in] = fmaf(ga[im][in], acc[im][in] + bv, ba[im][in]);
    }
    if (part == 0) {
      float msum = 0.f;
#pragma unroll
      for (int t = 0; t < 16; t++) msum += bsums[t];
      float mean = msum * (1.f / 4096.f);
      float a0 = alpha[0];
      const float2 pv = *(const float2*)&pooled[n0 + tx * 2];
      float iv[2] = {a0 * (pv.x - mean), a0 * (pv.y - mean)};
#pragma unroll
      for (int im = 0; im < 4; im++)
#pragma unroll
        for (int in = 0; in < 2; in++)
          val[im][in] = (val[im][in] + iv[in]) * QSCALE;
    }
    if (part < 2) {
      unsigned short* dst = (part == 0) ? qhl : khl;
      int hh = ty >> 1, d0 = (ty & 1) * 4;
#pragma unroll
      for (int in = 0; in < 2; in++) {
        int n = n0 + tx * 2 + in;
        unsigned int pk[4];
#pragma unroll
        for (int im = 0; im < 4; im++) pk[im] = split_pack(val[im][in]);
        short4 hi, lo;
        hi.x = (short)(pk[0] & 0xffffu); hi.y = (short)(pk[1] & 0xffffu);
        hi.z = (short)(pk[2] & 0xffffu); hi.w = (short)(pk[3] & 0xffffu);
        lo.x = (short)(pk[0] >> 16); lo.y = (short)(pk[1] >> 16);
        lo.z = (short)(pk[2] >> 16); lo.w = (short)(pk[3] >> 16);
        unsigned short* base = dst + ((size_t)(hh * NPIX + n) << 4) + d0;
        *(short4*)base = hi;
        *(short4*)(base + 8) = lo;
      }
    } else {
      int nq = n0 + tx * 2;
      int off0 = (nq >> 5) * 32 + ((nq >> 4) & 1) * 4 + ((nq >> 2) & 3) * 8 +
                 (nq & 3);
#pragma unroll
      for (int im = 0; im < 4; im++) {
        int cc = ty * 4 + im;
        unsigned int pk0 = split_pack(val[im][0]);
        unsigned int pk1 = split_pack(val[im][1]);
        short2 hi, lo;
        hi.x = (short)(pk0 & 0xffffu);
        hi.y = (short)(pk1 & 0xffffu);
        lo.x = (short)(pk0 >> 16);
        lo.y = (short)(pk1 >> 16);
        *(short2*)(vthx + (size_t)cc * NPIX + off0) = hi;
        *(short2*)(vtlx + (size_t)cc * NPIX + off0) = lo;
      }
    }
  }
  gbar(ctr + 16);

  // ---------------- Stage 3: attn (1024 units, 2 per block) ----------------
  {
    int wave = tid >> 6, lane = tid & 63;
    int g = lane >> 4, c = lane & 15;
#pragma unroll 1
    for (int rep = 0; rep < 2; rep++) {
      int unit = bid * 2 + rep;
      int h = (unit >> 4) & 7, jp = unit >> 7;
      int i0 = (unit & 15) * 256 + wave * 64;
      int jbase = jp * 512;
      bf16x8 qB[4];
#pragma unroll
      for (int t = 0; t < 4; t++)
        qB[t] = *(const bf16x8*)(qhl +
                                 ((size_t)(h * NPIX + i0 + t * 16 + c) << 4) +
                                 ((g & 1) << 3));
      const unsigned short* kp =
          khl + ((size_t)(h * NPIX + jbase + c) << 4) + ((g >> 1) << 3);
      const unsigned short* vhp;
      const unsigned short* vlp;
      int vstep;
      if (c < 8) {
        vhp = vthx + (size_t)(h * 8 + c) * NPIX + jbase + (g << 3);
        vlp = vtlx + (size_t)(h * 8 + c) * NPIX + jbase + (g << 3);
        vstep = 32;
      } else {
        vhp = (c == 8) ? cbuf : (cbuf + 8);  // ones row / zero rows
        vlp = cbuf + 8;
        vstep = 0;
      }
      floatx4 zero4 = {0.f, 0.f, 0.f, 0.f};
      floatx4 aH[4], aM[4];
#pragma unroll
      for (int t = 0; t < 4; t++) {
        aH[t] = zero4;
        aM[t] = zero4;
      }
#pragma unroll 4
      for (int jt = 0; jt < 16; ++jt) {
        bf16x8 ka0 = *(const bf16x8*)kp;
        bf16x8 ka1 = *(const bf16x8*)(kp + 256);
        bf16x8 avh = *(const bf16x8*)vhp;
        bf16x8 avl = *(const bf16x8*)vlp;
        kp += 512;
        vhp += vstep;
        vlp += vstep;
#pragma unroll
        for (int t = 0; t < 4; t++) {
          floatx4 s0 = __builtin_amdgcn_mfma_f32_16x16x32_bf16(ka0, qB[t],
                                                               zero4, 0, 0, 0);
          floatx4 s1 = __builtin_amdgcn_mfma_f32_16x16x32_bf16(ka1, qB[t],
                                                               zero4, 0, 0, 0);
          float p0 = __builtin_amdgcn_exp2f(fminf(s0[0], 80.f));
          float p1 = __builtin_amdgcn_exp2f(fminf(s0[1], 80.f));
          float p2 = __builtin_amdgcn_exp2f(fminf(s0[2], 80.f));
          float p3 = __builtin_amdgcn_exp2f(fminf(s0[3], 80.f));
          float p4 = __builtin_amdgcn_exp2f(fminf(s1[0], 80.f));
          float p5 = __builtin_amdgcn_exp2f(fminf(s1[1], 80.f));
          float p6 = __builtin_amdgcn_exp2f(fminf(s1[2], 80.f));
          float p7 = __builtin_amdgcn_exp2f(fminf(s1[3], 80.f));
          uintx4 bh;
          bh.x = pack_hi2(p0, p1);
          bh.y = pack_hi2(p2, p3);
          bh.z = pack_hi2(p4, p5);
          bh.w = pack_hi2(p6, p7);
          bf16x8 pbh = __builtin_bit_cast(bf16x8, bh);
          aH[t] =
              __builtin_amdgcn_mfma_f32_16x16x32_bf16(avh, pbh, aH[t], 0, 0, 0);
          aM[t] =
              __builtin_amdgcn_mfma_f32_16x16x32_bf16(avl, pbh, aM[t], 0, 0, 0);
        }
      }
#pragma unroll
      for (int t = 0; t < 4; t++) {
        floatx4 o = aH[t] + aM[t];
        if (g < 2) {
          size_t b0 = (size_t)((jp * 8 + h) * NPIX + i0 + t * 16 + c);
          *(float4*)&pacc[b0 * 8 + g * 4] = make_float4(o[0], o[1], o[2], o[3]);
        } else if (g == 2) {
          pl[(size_t)((jp * 8 + h) * NPIX + i0 + t * 16 + c)] = o[0];
        }
      }
    }
  }
  gbar(ctr + 32);

  // ---------------- Stage 4: proj_ffn1 (512 units) ----------------
  {
    float(&at)[64][34] = u.s4.at;
    float(&wsh)[64][64] = u.s4.wsh;
    float(&xsl)[64][34] = u.s4.xsl;
    float(&ps)[16][32] = u.s4.ps;
    float(&pq)[16][32] = u.s4.pq;
    float(&mus)[32] = u.s4.mus;
    float(&rss)[32] = u.s4.rss;
    int n0 = (bid & 127) * 32;
    int ch = bid >> 7;
    int mm = tid >> 2, kg = (tid & 3) * 16;
    {
      const float4* wr = (const float4*)&projW[mm * 64 + kg];
      float4 w0 = wr[0], w1 = wr[1], w2 = wr[2], w3 = wr[3];
      float wv[16] = {w0.x, w0.y, w0.z, w0.w, w1.x, w1.y, w1.z, w1.w,
                      w2.x, w2.y, w2.z, w2.w, w3.x, w3.y, w3.z, w3.w};
#pragma unroll
      for (int j = 0; j < 16; j++) wsh[kg + j][mm] = wv[j];
    }
    {
      int hh = tid >> 5, nn = tid & 31;
      int i = n0 + nn;
      float L = 0.f, o[8] = {};
#pragma unroll
      for (int p = 0; p < 8; p++) {
        size_t base = (size_t)((p * 8 + hh) * NPIX + i);
        L += pl[base];
        const float4 a0 = *(const float4*)&pacc[base * 8];
        const float4 a1 = *(const float4*)&pacc[base * 8 + 4];
        o[0] += a0.x; o[1] += a0.y; o[2] += a0.z; o[3] += a0.w;
        o[4] += a1.x; o[5] += a1.y; o[6] += a1.z; o[7] += a1.w;
      }
      float inv = 1.f / L;
#pragma unroll
      for (int d = 0; d < 8; d++) at[hh * 8 + d][nn] = o[d] * inv;
    }
    __syncthreads();
    int mq = tid >> 4, pp = (tid & 15) * 2;
    float acc[4][2] = {};
#pragma unroll 8
    for (int k = 0; k < 64; k++) {
      float4 w4 = *(const float4*)&wsh[k][mq * 4];
      float2 b2 = *(const float2*)&at[k][pp];
      acc[0][0] = fmaf(w4.x, b2.x, acc[0][0]);
      acc[0][1] = fmaf(w4.x, b2.y, acc[0][1]);
      acc[1][0] = fmaf(w4.y, b2.x, acc[1][0]);
      acc[1][1] = fmaf(w4.y, b2.y, acc[1][1]);
      acc[2][0] = fmaf(w4.z, b2.x, acc[2][0]);
      acc[2][1] = fmaf(w4.z, b2.y, acc[2][1]);
      acc[3][0] = fmaf(w4.w, b2.x, acc[3][0]);
      acc[3][1] = fmaf(w4.w, b2.y, acc[3][1]);
    }
    float v[4][2], sn0 = 0.f, sn1 = 0.f, qn0 = 0.f, qn1 = 0.f;
#pragma unroll
    for (int im = 0; im < 4; im++) {
      int row = mq * 4 + im;
      float bpv = projB[row];
      const float2 xr = *(const float2*)&x[row * NPIX + n0 + pp];
      float v0 = acc[im][0] + bpv + xr.x;
      float v1 = acc[im][1] + bpv + xr.y;
      v[im][0] = v0;
      v[im][1] = v1;
      sn0 += v0;
      qn0 = fmaf(v0, v0, qn0);
      sn1 += v1;
      qn1 = fmaf(v1, v1, qn1);
    }
    if (ch == 0) {
#pragma unroll
      for (int im = 0; im < 4; im++)
        *(float2*)&x1[(mq * 4 + im) * NPIX + n0 + pp] =
            make_float2(v[im][0], v[im][1]);
    }
    ps[mq][pp] = sn0;
    ps[mq][pp + 1] = sn1;
    pq[mq][pp] = qn0;
    pq[mq][pp + 1] = qn1;
    __syncthreads();
    // Stage W1 slice into the (now free) weight buffer; tid<32 does LN stats.
    {
      const float4* w1r = (const float4*)&ffn1W[(ch * 64 + mm) * 64 + kg];
      float4 u0 = w1r[0], u1 = w1r[1], u2 = w1r[2], u3 = w1r[3];
      float uv[16] = {u0.x, u0.y, u0.z, u0.w, u1.x, u1.y, u1.z, u1.w,
                      u2.x, u2.y, u2.z, u2.w, u3.x, u3.y, u3.z, u3.w};
#pragma unroll
      for (int j = 0; j < 16; j++) wsh[kg + j][mm] = uv[j];
    }
    if (tid < 32) {
      float s = 0.f, q = 0.f;
#pragma unroll
      for (int t = 0; t < 16; t++) {
        s += ps[t][tid];
        q += pq[t][tid];
      }
      float mu = s * (1.f / 64.f);
      mus[tid] = mu;
      rss[tid] = rsqrtf(q * (1.f / 64.f) - mu * mu + 1e-5f);
    }
    __syncthreads();
    {
      float mu0 = mus[pp], mu1v = mus[pp + 1];
      float rs0 = rss[pp], rs1v = rss[pp + 1];
#pragma unroll
      for (int im = 0; im < 4; im++) {
        int row = mq * 4 + im;
        float w2v = ln2w[row], b2v = ln2b[row];
        *(float2*)&xsl[row][pp] =
            make_float2((v[im][0] - mu0) * rs0 * w2v + b2v,
                        (v[im][1] - mu1v) * rs1v * w2v + b2v);
      }
    }
    __syncthreads();
    float a2[4][2] = {};
#pragma unroll 8
    for (int k = 0; k < 64; k++) {
      float4 w4 = *(const float4*)&wsh[k][mq * 4];
      float2 b2 = *(const float2*)&xsl[k][pp];
      a2[0][0] = fmaf(w4.x, b2.x, a2[0][0]);
      a2[0][1] = fmaf(w4.x, b2.y, a2[0][1]);
      a2[1][0] = fmaf(w4.y, b2.x, a2[1][0]);
      a2[1][1] = fmaf(w4.y, b2.y, a2[1][1]);
      a2[2][0] = fmaf(w4.z, b2.x, a2[2][0]);
      a2[2][1] = fmaf(w4.z, b2.y, a2[2][1]);
      a2[3][0] = fmaf(w4.w, b2.x, a2[3][0]);
      a2[3][1] = fmaf(w4.w, b2.y, a2[3][1]);
    }
#pragma unroll
    for (int im = 0; im < 4; im++) {
      int row = ch * 64 + mq * 4 + im;
      float bb = ffn1B[row];
      *(float2*)&f1[row * NPIX + n0 + pp] =
          make_float2(a2[im][0] + bb, a2[im][1] + bb);
    }
  }
  gbar(ctr + 48);

  // ---------------- Stage 5: ffn2_dw (512 units) ----------------
  {
    float(&xs2)[16][260] = u.s5.xs2;
    float(&wshT)[32][260] = u.s5.wshT;
    int n0 = (bid & 255) * 16, m0 = (bid >> 8) * 32;
    int y = n0 >> 6, x0 = n0 & 63;
    {
      int mm = tid >> 3, kg = (tid & 7) * 32;
      const float4* src = (const float4*)&ffn2W[(m0 + mm) * 256 + kg];
      float4* dst = (float4*)&wshT[mm][kg];
#pragma unroll
      for (int i = 0; i < 8; i++) dst[i] = src[i];
    }
    {
      int px4 = (tid & 3) * 4;
      int xabs = x0 + px4;
#pragma unroll
      for (int k = 0; k < 4; k++) {
        int c = (tid >> 2) + 64 * k;
        const float* base = f1 + c * NPIX;
        float wv[9];
#pragma unroll
        for (int i = 0; i < 9; i++) wv[i] = dww[c * 9 + i];
        float bc = dwb[c];
        float a[4] = {bc, bc, bc, bc};
#pragma unroll
        for (int dy = 0; dy < 3; dy++) {
          int yy = y + dy - 1;
          if (yy < 0 || yy > 63) continue;
          const float* row = base + yy * IMG + xabs;
          float4 mid = *(const float4*)row;
          float left = (xabs > 0) ? row[-1] : 0.f;
          float right = (xabs + 4 < IMG) ? row[4] : 0.f;
          float win[6] = {left, mid.x, mid.y, mid.z, mid.w, right};
#pragma unroll
          for (int o = 0; o < 4; o++)
#pragma unroll
            for (int dx = 0; dx < 3; dx++)
              a[o] = fmaf(wv[dy * 3 + dx], win[o + dx], a[o]);
        }
#pragma unroll
        for (int o = 0; o < 4; o++)
          xs2[px4 + o][c] =
              0.5f * a[o] * (1.f + erff(a[o] * 0.70710678118654752f));
      }
    }
    __syncthreads();
    int m = tid >> 3, np = (tid & 7) * 2;
    float a0 = 0.f, a1 = 0.f;
#pragma unroll 4
    for (int k4 = 0; k4 < 64; k4++) {
      float4 w4 = *(const float4*)&wshT[m][k4 * 4];
      float4 xa = *(const float4*)&xs2[np][k4 * 4];
      float4 xb = *(const float4*)&xs2[np + 1][k4 * 4];
      a0 = fmaf(w4.x, xa.x, a0);
      a1 = fmaf(w4.x, xb.x, a1);
      a0 = fmaf(w4.y, xa.y, a0);
      a1 = fmaf(w4.y, xb.y, a1);
      a0 = fmaf(w4.z, xa.z, a0);
      a1 = fmaf(w4.z, xb.z, a1);
      a0 = fmaf(w4.w, xa.w, a0);
      a1 = fmaf(w4.w, xb.w, a1);
    }
    int row = m0 + m;
    float bv = ffn2B[row];
    const float2 rr = *(const float2*)&x1[row * NPIX + n0 + np];
    *(float2*)&out[row * NPIX + n0 + np] =
        make_float2(a0 + bv + rr.x, a1 + bv + rr.y);
  }
}

// ---------------------------------------------------------------------------
extern "C" void kernel_launch(void* const* d_in, const int* in_sizes, int n_in,
                              void* d_out, int out_size, void* d_ws,
                              size_t ws_size, hipStream_t stream) {
  const float* x      = (const float*)d_in[0];
  const float* luma   = (const float*)d_in[1];
  const float* ln1_w  = (const float*)d_in[2];
  const float* ln1_b  = (const float*)d_in[3];
  const float* qkv_w  = (const float*)d_in[4];
  const float* qkv_b  = (const float*)d_in[5];
  const float* proj_w = (const float*)d_in[6];
  const float* proj_b = (const float*)d_in[7];
  const float* lc1_w  = (const float*)d_in[8];
  const float* lc1_b  = (const float*)d_in[9];
  const float* lc2_w  = (const float*)d_in[10];
  const float* lc2_b  = (const float*)d_in[11];
  const float* gam_w  = (const float*)d_in[12];
  const float* gam_b  = (const float*)d_in[13];
  const float* bet_w  = (const float*)d_in[14];
  const float* bet_b  = (const float*)d_in[15];
  const float* alpha  = (const float*)d_in[16];
  const float* ln2_w  = (const float*)d_in[17];
  const float* ln2_b  = (const float*)d_in[18];
  const float* ffn1_w = (const float*)d_in[19];
  const float* ffn1_b = (const float*)d_in[20];
  const float* dw_w   = (const float*)d_in[21];
  const float* dw_b   = (const float*)d_in[22];
  const float* ffn2_w = (const float*)d_in[23];
  const float* ffn2_b = (const float*)d_in[24];
  float* out = (float*)d_out;

  float* w = (float*)d_ws;
  float* pooled = w + 0;        // 4096
  float* bsums  = w + 4096;     // 64 (16 used)
  unsigned short* cbuf = (unsigned short*)(w + 4160);     // 64 f (16 us used)
  float* mu1 = w + 4224;        // 4096
  float* rs1 = w + 8320;        // 4096
  unsigned short* qhl  = (unsigned short*)(w + 12416);    // 262144 f
  unsigned short* khl  = (unsigned short*)(w + 274560);   // 262144 f
  unsigned short* vthx = (unsigned short*)(w + 536704);   // 131072 f
  unsigned short* vtlx = (unsigned short*)(w + 667776);   // 131072 f
  float* pacc = w + 798848;    // 2097152 (JP=8)
  float* pl   = w + 2896000;   // 262144
  float* x1   = w + 3158144;   // 262144
  float* f1   = w + 3420288;   // 1048576
  float* h2   = w + 4468864;   // 131072
  unsigned int* ctr = (unsigned int*)(w + 4599936);  // 64 uints

  init_kernel<<<1, 128, 0, stream>>>(ctr, cbuf);
  fused_kernel<<<dim3(NBLK), 256, 0, stream>>>(
      x, luma, lc1_w, lc1_b, lc2_w, lc2_b, ln1_w, ln1_b, qkv_w, qkv_b, gam_w,
      gam_b, bet_w, bet_b, alpha, proj_w, proj_b, ln2_w, ln2_b, ffn1_w, ffn1_b,
      dw_w, dw_b, ffn2_w, ffn2_b, out, pooled, bsums, cbuf, mu1, rs1, qhl, khl,
      vthx, vtlx, pacc, pl, x1, f1, h2, ctr);
}

// Round 5
// 267.377 us; speedup vs baseline: 2.3031x; 1.0834x over previous
//
#include <hip/hip_runtime.h>
#include <math.h>

// B=1, C=64, H=W=64, N=4096, heads=8, dh=8, inner=64, hid_lc=32, hid_f=256.
// Single persistent fused kernel, 5 stages, device-scope grid barriers.
// Grid 512 blocks x 256 threads, co-resident (LDS union 49.9 KB, occupancy
// ~24% confirmed r2-r4).
//
// r5 coherence redesign: r4's elected per-XCD buffer_wbl2+buffer_inv still
// cost ~25 us/barrier (full 4MB L2 tag walks). Now NO cache maintenance at
// all: every inter-stage STORE is a relaxed agent-scope atomic store
// (write-through to the device-coherent LLC -- same path that makes
// cross-XCD atomicAdd work), so producer XCD L2s never hold dirty
// inter-stage lines. Consumer loads stay normal/cached: L2 was invalidated
// by the dispatch-start acquire (the same property the 5-kernel pipeline
// relies on), and inter-stage buffers are never normal-stored in-kernel, so
// no stale line can exist; first touch misses to LLC (fresh), then caches
// (K/V 16x reuse keeps its L2 hits). Barrier = arrival-only spin (~2 us).
#define NPIX 4096
#define IMG 64
#define NBLK 512

typedef __attribute__((ext_vector_type(8))) short bf16x8;
typedef __attribute__((ext_vector_type(4))) float floatx4;
typedef __attribute__((ext_vector_type(4))) unsigned int uintx4;

// fp32 -> (hi bf16 in low16) | (lo bf16 in high16), lo = x - f32(hi)
__device__ __forceinline__ unsigned int split_pack(float x) {
  unsigned int u = __float_as_uint(x);
  unsigned int hif = u & 0xffff0000u;
  float lof = x - __uint_as_float(hif);
  return (u >> 16) | (__float_as_uint(lof) & 0xffff0000u);
}

// pack hi16 of two floats in ONE v_perm_b32: low16 = hi16(a), high16 = hi16(b)
__device__ __forceinline__ unsigned int pack_hi2(float a, float b) {
  return __builtin_amdgcn_perm(__float_as_uint(b), __float_as_uint(a),
                               0x07060302u);
}

// Agent-scope (device-coherent, LLC write-through) stores for inter-stage
// buffers. Relaxed: ordering vs the barrier comes from the vmcnt(0) drain
// inside __syncthreads before arrival.
__device__ __forceinline__ void stA_f32(float* p, float v) {
  __hip_atomic_store(p, v, __ATOMIC_RELAXED, __HIP_MEMORY_SCOPE_AGENT);
}
__device__ __forceinline__ void stA_u32(void* p, unsigned int v) {
  __hip_atomic_store((unsigned int*)p, v, __ATOMIC_RELAXED,
                     __HIP_MEMORY_SCOPE_AGENT);
}
__device__ __forceinline__ void stA_u64(void* p, unsigned long long v) {
  __hip_atomic_store((unsigned long long*)p, v, __ATOMIC_RELAXED,
                     __HIP_MEMORY_SCOPE_AGENT);
}

// Arrival-only grid barrier. __syncthreads drains vmcnt (stores reached the
// coherent point); relaxed agent atomics on an LLC-resident counter; the
// trailing compiler barrier stops load hoisting (hardware is in-order).
__device__ __forceinline__ void gbar(unsigned int* ctr) {
  __syncthreads();
  if (threadIdx.x == 0) {
    __hip_atomic_fetch_add(ctr, 1u, __ATOMIC_RELAXED,
                           __HIP_MEMORY_SCOPE_AGENT);
    while (__hip_atomic_load(ctr, __ATOMIC_RELAXED,
                             __HIP_MEMORY_SCOPE_AGENT) < (unsigned)NBLK)
      __builtin_amdgcn_s_sleep(2);
    asm volatile("" ::: "memory");
  }
  __syncthreads();
}

// LDS stage overlays (union keeps the fused kernel at 49.9 KB).
struct S1 {  // lc12
  float lum[400];
  float sw1[288];
  float tin[32][324];
  float swt[4][32][9];
  float red[256];
};
struct S2 {  // ln_qkv
  float xs[64][32];
  float wsh[64][64];
  float h2s[32][32];
  float wgs[32][64];
  float wbs[32][64];
  float mu[32];
  float rs[32];
};
struct S4 {  // proj_ffn1 (single reused weight buffer)
  float at[64][34];
  float wsh[64][64];
  float xsl[64][34];
  float ps[16][32];
  float pq[16][32];
  float mus[32];
  float rss[32];
};
struct S5 {  // ffn2_dw
  float xs2[16][260];
  float wshT[32][260];
};
union SU {
  S1 s1;
  S2 s2;
  S4 s4;
  S5 s5;
};

__global__ void init_kernel(unsigned int* __restrict__ ctr,
                            unsigned short* __restrict__ cbuf) {
  int t = threadIdx.x;
  if (t < 64) ctr[t] = 0u;
  if (t >= 64 && t < 80) cbuf[t - 64] = (t - 64 < 8) ? 0x3F80 : 0;
}

__global__ __launch_bounds__(256, 3) void fused_kernel(
    const float* __restrict__ x, const float* __restrict__ luma,
    const float* __restrict__ lc1w, const float* __restrict__ lc1b,
    const float* __restrict__ lc2w, const float* __restrict__ lc2b,
    const float* __restrict__ ln1w, const float* __restrict__ ln1b,
    const float* __restrict__ qkvW, const float* __restrict__ qkvB,
    const float* __restrict__ gamW, const float* __restrict__ gamB,
    const float* __restrict__ betW, const float* __restrict__ betB,
    const float* __restrict__ alpha, const float* __restrict__ projW,
    const float* __restrict__ projB, const float* __restrict__ ln2w,
    const float* __restrict__ ln2b, const float* __restrict__ ffn1W,
    const float* __restrict__ ffn1B, const float* __restrict__ dww,
    const float* __restrict__ dwb, const float* __restrict__ ffn2W,
    const float* __restrict__ ffn2B, float* __restrict__ out,
    float* __restrict__ pooled, float* __restrict__ bsums,
    unsigned short* __restrict__ cbuf, float* __restrict__ mu1,
    float* __restrict__ rs1, unsigned short* __restrict__ qhl,
    unsigned short* __restrict__ khl, unsigned short* __restrict__ vthx,
    unsigned short* __restrict__ vtlx, float* __restrict__ pacc,
    float* __restrict__ pl, float* __restrict__ x1, float* __restrict__ f1,
    float* __restrict__ h2, unsigned int* __restrict__ ctr) {
  __shared__ SU u;
  int bid = blockIdx.x;
  int tid = threadIdx.x;

  // ---------------- Stage 1: lc12 (128 units) ----------------
  if (bid < 128) {
    int tile = bid >> 3, ocg = bid & 7;
    int ty0 = (tile >> 2) * 16, tx0 = (tile & 3) * 16;
    float(&lum)[400] = u.s1.lum;
    float(&sw1)[288] = u.s1.sw1;
    float(&tin)[32][324] = u.s1.tin;
    float(&swt)[4][32][9] = u.s1.swt;
    float(&red)[256] = u.s1.red;
    for (int idx = tid; idx < 400; idx += 256) {
      int py = idx / 20, px = idx - py * 20;
      int gy = ty0 + py - 2, gx = tx0 + px - 2;
      lum[idx] = (gy >= 0 && gy < IMG && gx >= 0 && gx < IMG)
                     ? luma[gy * IMG + gx]
                     : 0.f;
    }
    for (int idx = tid; idx < 288; idx += 256) sw1[idx] = lc1w[idx];
    for (int idx = tid; idx < 1152; idx += 256) {
      int o = idx / 288, r = idx - o * 288;
      swt[o][r / 9][r % 9] = lc2w[(ocg * 4 + o) * 288 + r];
    }
    __syncthreads();
    for (int idx = tid; idx < 32 * 324; idx += 256) {
      int ic = idx / 324, pos = idx - ic * 324;
      int py = pos / 18, px = pos - py * 18;
      int gy = ty0 + py - 1, gx = tx0 + px - 1;
      float v = 0.f;
      if (gy >= 0 && gy < IMG && gx >= 0 && gx < IMG) {
        float s = lc1b[ic];
        const float* wp = &sw1[ic * 9];
#pragma unroll
        for (int dy = 0; dy < 3; dy++)
#pragma unroll
          for (int dx = 0; dx < 3; dx++)
            s = fmaf(wp[dy * 3 + dx], lum[(py + dy) * 20 + px + dx], s);
        v = fmaxf(s, 0.f);
      }
      tin[ic][pos] = v;
    }
    __syncthreads();
    int ly = tid >> 4, lx = tid & 15;
    int p = (ty0 + ly) * IMG + tx0 + lx;
    float acc[4];
#pragma unroll
    for (int o = 0; o < 4; o++) acc[o] = lc2b[ocg * 4 + o];
    for (int ic = 0; ic < 32; ic++) {
      float v[9];
#pragma unroll
      for (int dy = 0; dy < 3; dy++)
#pragma unroll
        for (int dx = 0; dx < 3; dx++)
          v[dy * 3 + dx] = tin[ic][(ly + dy) * 18 + lx + dx];
#pragma unroll
      for (int o = 0; o < 4; o++)
#pragma unroll
        for (int t = 0; t < 9; t++) acc[o] = fmaf(swt[o][ic][t], v[t], acc[o]);
    }
#pragma unroll
    for (int o = 0; o < 4; o++)
      stA_f32(&h2[(ocg * 4 + o) * NPIX + p], fmaxf(acc[o], 0.f));
    if (ocg == 0) {
      int gy = ty0 + ly, gx = tx0 + lx;
      float sv = 0.f;
#pragma unroll
      for (int dy = 0; dy < 3; dy++)
#pragma unroll
        for (int dx = 0; dx < 3; dx++)
          sv += lum[(ly + dy + 1) * 20 + lx + dx + 1];
      float cy = 3.f - (gy == 0 ? 1.f : 0.f) - (gy == 63 ? 1.f : 0.f);
      float cx = 3.f - (gx == 0 ? 1.f : 0.f) - (gx == 63 ? 1.f : 0.f);
      float pv = (cy * cx - sv) * (1.f / 9.f);
      stA_f32(&pooled[p], pv);
      red[tid] = pv;
      __syncthreads();
      for (int st = 128; st > 0; st >>= 1) {
        if (tid < st) red[tid] += red[tid + st];
        __syncthreads();
      }
      if (tid == 0) stA_f32(&bsums[tile], red[0]);
      float s = 0.f, q = 0.f;
#pragma unroll 8
      for (int cc = 0; cc < 64; cc++) {
        float xv = x[cc * NPIX + p];
        s += xv;
        q = fmaf(xv, xv, q);
      }
      float mu = s * (1.f / 64.f);
      stA_f32(&mu1[p], mu);
      stA_f32(&rs1[p], rsqrtf(q * (1.f / 64.f) - mu * mu + 1e-5f));
    }
  }
  gbar(ctr + 0);

  // ---------------- Stage 2: ln_qkv (384 units) ----------------
  if (bid < 384) {
    const float QSCALE = 0.35355339059327376f * 1.4426950408889634f;
    float(&xs)[64][32] = u.s2.xs;
    float(&wsh)[64][64] = u.s2.wsh;
    float(&h2s)[32][32] = u.s2.h2s;
    float(&wgs)[32][64] = u.s2.wgs;
    float(&wbs)[32][64] = u.s2.wbs;
    float(&mu)[32] = u.s2.mu;
    float(&rs)[32] = u.s2.rs;
    int n0 = (bid & 127) * 32, part = bid >> 7, m0 = part * 64;
    if (tid < 32) {
      mu[tid] = mu1[n0 + tid];
      rs[tid] = rs1[n0 + tid];
    }
    {
      int e = tid * 2;
      int c = e >> 3, off = (e & 7) * 4;
      *(float4*)&xs[c][off] = *(const float4*)&x[c * NPIX + n0 + off];
      int e1 = e + 1;
      int c1 = e1 >> 3, off1 = (e1 & 7) * 4;
      *(float4*)&xs[c1][off1] = *(const float4*)&x[c1 * NPIX + n0 + off1];
    }
    {
      int m = tid >> 2, kg = (tid & 3) * 16;
      const float4* wr = (const float4*)&qkvW[(m0 + m) * 64 + kg];
      float4 w0 = wr[0], w1 = wr[1], w2 = wr[2], w3 = wr[3];
      float wv[16] = {w0.x, w0.y, w0.z, w0.w, w1.x, w1.y, w1.z, w1.w,
                      w2.x, w2.y, w2.z, w2.w, w3.x, w3.y, w3.z, w3.w};
#pragma unroll
      for (int j = 0; j < 16; j++) wsh[kg + j][m] = wv[j];
    }
    {
      int k = tid >> 3, nf = (tid & 7) * 4;
      *(float4*)&h2s[k][nf] = *(const float4*)&h2[k * NPIX + n0 + nf];
    }
    {
      int m = tid >> 2, kg = (tid & 3) * 8;
      const float4* g0 = (const float4*)&gamW[m * 32 + kg];
      float4 a = g0[0], b4 = g0[1];
      float gv[8] = {a.x, a.y, a.z, a.w, b4.x, b4.y, b4.z, b4.w};
#pragma unroll
      for (int j = 0; j < 8; j++) wgs[kg + j][m] = gv[j];
      const float4* bb0 = (const float4*)&betW[m * 32 + kg];
      float4 c4 = bb0[0], d4 = bb0[1];
      float bv[8] = {c4.x, c4.y, c4.z, c4.w, d4.x, d4.y, d4.z, d4.w};
#pragma unroll
      for (int j = 0; j < 8; j++) wbs[kg + j][m] = bv[j];
    }
    __syncthreads();
    {
      int c = tid >> 2, pg = (tid & 3) * 8;
      float wc = ln1w[c], bc = ln1b[c];
#pragma unroll
      for (int j = 0; j < 8; j++) {
        int p = pg + j;
        xs[c][p] = (xs[c][p] - mu[p]) * rs[p] * wc + bc;
      }
    }
    __syncthreads();
    int tx = tid & 15, ty = tid >> 4;
    float ga[4][2] = {}, ba[4][2] = {};
#pragma unroll 8
    for (int kk = 0; kk < 32; kk++) {
      float4 wg4 = *(const float4*)&wgs[kk][ty * 4];
      float4 wb4 = *(const float4*)&wbs[kk][ty * 4];
      float2 h22 = *(const float2*)&h2s[kk][tx * 2];
      float gv[4] = {wg4.x, wg4.y, wg4.z, wg4.w};
      float bv[4] = {wb4.x, wb4.y, wb4.z, wb4.w};
      float hv[2] = {h22.x, h22.y};
#pragma unroll
      for (int im = 0; im < 4; im++)
#pragma unroll
        for (int in = 0; in < 2; in++) {
          ga[im][in] = fmaf(gv[im], hv[in], ga[im][in]);
          ba[im][in] = fmaf(bv[im], hv[in], ba[im][in]);
        }
    }
#pragma unroll
    for (int im = 0; im < 4; im++) {
      int cc = ty * 4 + im;
      float gb = gamB[cc], bb2 = betB[cc];
#pragma unroll
      for (int in = 0; in < 2; in++) {
        ga[im][in] += gb;
        ba[im][in] += bb2;
      }
    }
    float acc[4][2] = {};
#pragma unroll 8
    for (int kk = 0; kk < 64; kk++) {
      float4 a = *(const float4*)&wsh[kk][ty * 4];
      float2 b2 = *(const float2*)&xs[kk][tx * 2];
      float av[4] = {a.x, a.y, a.z, a.w};
      float bv[2] = {b2.x, b2.y};
#pragma unroll
      for (int im = 0; im < 4; im++)
#pragma unroll
        for (int in = 0; in < 2; in++)
          acc[im][in] = fmaf(av[im], bv[in], acc[im][in]);
    }
    float val[4][2];
#pragma unroll
    for (int im = 0; im < 4; im++) {
      int cc = ty * 4 + im;
      float bv = qkvB[m0 + cc];
#pragma unroll
      for (int in = 0; in < 2; in++)
        val[im][in] = fmaf(ga[im][in], acc[im][in] + bv, ba[im][in]);
    }
    if (part == 0) {
      float msum = 0.f;
#pragma unroll
      for (int t = 0; t < 16; t++) msum += bsums[t];
      float mean = msum * (1.f / 4096.f);
      float a0 = alpha[0];
      const float2 pv = *(const float2*)&pooled[n0 + tx * 2];
      float iv[2] = {a0 * (pv.x - mean), a0 * (pv.y - mean)};
#pragma unroll
      for (int im = 0; im < 4; im++)
#pragma unroll
        for (int in = 0; in < 2; in++)
          val[im][in] = (val[im][in] + iv[in]) * QSCALE;
    }
    if (part < 2) {
      unsigned short* dst = (part == 0) ? qhl : khl;
      int hh = ty >> 1, d0 = (ty & 1) * 4;
#pragma unroll
      for (int in = 0; in < 2; in++) {
        int n = n0 + tx * 2 + in;
        unsigned int pk[4];
#pragma unroll
        for (int im = 0; im < 4; im++) pk[im] = split_pack(val[im][in]);
        short4 hi, lo;
        hi.x = (short)(pk[0] & 0xffffu); hi.y = (short)(pk[1] & 0xffffu);
        hi.z = (short)(pk[2] & 0xffffu); hi.w = (short)(pk[3] & 0xffffu);
        lo.x = (short)(pk[0] >> 16); lo.y = (short)(pk[1] >> 16);
        lo.z = (short)(pk[2] >> 16); lo.w = (short)(pk[3] >> 16);
        unsigned short* base = dst + ((size_t)(hh * NPIX + n) << 4) + d0;
        stA_u64(base, __builtin_bit_cast(unsigned long long, hi));
        stA_u64(base + 8, __builtin_bit_cast(unsigned long long, lo));
      }
    } else {
      int nq = n0 + tx * 2;
      int off0 = (nq >> 5) * 32 + ((nq >> 4) & 1) * 4 + ((nq >> 2) & 3) * 8 +
                 (nq & 3);
#pragma unroll
      for (int im = 0; im < 4; im++) {
        int cc = ty * 4 + im;
        unsigned int pk0 = split_pack(val[im][0]);
        unsigned int pk1 = split_pack(val[im][1]);
        short2 hi, lo;
        hi.x = (short)(pk0 & 0xffffu);
        hi.y = (short)(pk1 & 0xffffu);
        lo.x = (short)(pk0 >> 16);
        lo.y = (short)(pk1 >> 16);
        stA_u32(vthx + (size_t)cc * NPIX + off0,
                __builtin_bit_cast(unsigned int, hi));
        stA_u32(vtlx + (size_t)cc * NPIX + off0,
                __builtin_bit_cast(unsigned int, lo));
      }
    }
  }
  gbar(ctr + 16);

  // ---------------- Stage 3: attn (1024 units, 2 per block) ----------------
  {
    int wave = tid >> 6, lane = tid & 63;
    int g = lane >> 4, c = lane & 15;
#pragma unroll 1
    for (int rep = 0; rep < 2; rep++) {
      int unit = bid * 2 + rep;
      int h = (unit >> 4) & 7, jp = unit >> 7;
      int i0 = (unit & 15) * 256 + wave * 64;
      int jbase = jp * 512;
      bf16x8 qB[4];
#pragma unroll
      for (int t = 0; t < 4; t++)
        qB[t] = *(const bf16x8*)(qhl +
                                 ((size_t)(h * NPIX + i0 + t * 16 + c) << 4) +
                                 ((g & 1) << 3));
      const unsigned short* kp =
          khl + ((size_t)(h * NPIX + jbase + c) << 4) + ((g >> 1) << 3);
      const unsigned short* vhp;
      const unsigned short* vlp;
      int vstep;
      if (c < 8) {
        vhp = vthx + (size_t)(h * 8 + c) * NPIX + jbase + (g << 3);
        vlp = vtlx + (size_t)(h * 8 + c) * NPIX + jbase + (g << 3);
        vstep = 32;
      } else {
        vhp = (c == 8) ? cbuf : (cbuf + 8);  // ones row / zero rows
        vlp = cbuf + 8;
        vstep = 0;
      }
      floatx4 zero4 = {0.f, 0.f, 0.f, 0.f};
      floatx4 aH[4], aM[4];
#pragma unroll
      for (int t = 0; t < 4; t++) {
        aH[t] = zero4;
        aM[t] = zero4;
      }
#pragma unroll 4
      for (int jt = 0; jt < 16; ++jt) {
        bf16x8 ka0 = *(const bf16x8*)kp;
        bf16x8 ka1 = *(const bf16x8*)(kp + 256);
        bf16x8 avh = *(const bf16x8*)vhp;
        bf16x8 avl = *(const bf16x8*)vlp;
        kp += 512;
        vhp += vstep;
        vlp += vstep;
#pragma unroll
        for (int t = 0; t < 4; t++) {
          floatx4 s0 = __builtin_amdgcn_mfma_f32_16x16x32_bf16(ka0, qB[t],
                                                               zero4, 0, 0, 0);
          floatx4 s1 = __builtin_amdgcn_mfma_f32_16x16x32_bf16(ka1, qB[t],
                                                               zero4, 0, 0, 0);
          float p0 = __builtin_amdgcn_exp2f(fminf(s0[0], 80.f));
          float p1 = __builtin_amdgcn_exp2f(fminf(s0[1], 80.f));
          float p2 = __builtin_amdgcn_exp2f(fminf(s0[2], 80.f));
          float p3 = __builtin_amdgcn_exp2f(fminf(s0[3], 80.f));
          float p4 = __builtin_amdgcn_exp2f(fminf(s1[0], 80.f));
          float p5 = __builtin_amdgcn_exp2f(fminf(s1[1], 80.f));
          float p6 = __builtin_amdgcn_exp2f(fminf(s1[2], 80.f));
          float p7 = __builtin_amdgcn_exp2f(fminf(s1[3], 80.f));
          uintx4 bh;
          bh.x = pack_hi2(p0, p1);
          bh.y = pack_hi2(p2, p3);
          bh.z = pack_hi2(p4, p5);
          bh.w = pack_hi2(p6, p7);
          bf16x8 pbh = __builtin_bit_cast(bf16x8, bh);
          aH[t] =
              __builtin_amdgcn_mfma_f32_16x16x32_bf16(avh, pbh, aH[t], 0, 0, 0);
          aM[t] =
              __builtin_amdgcn_mfma_f32_16x16x32_bf16(avl, pbh, aM[t], 0, 0, 0);
        }
      }
#pragma unroll
      for (int t = 0; t < 4; t++) {
        floatx4 o = aH[t] + aM[t];
        if (g < 2) {
          size_t b0 = (size_t)((jp * 8 + h) * NPIX + i0 + t * 16 + c);
          float2 lo2 = make_float2(o[0], o[1]);
          float2 hi2 = make_float2(o[2], o[3]);
          stA_u64(&pacc[b0 * 8 + g * 4],
                  __builtin_bit_cast(unsigned long long, lo2));
          stA_u64(&pacc[b0 * 8 + g * 4 + 2],
                  __builtin_bit_cast(unsigned long long, hi2));
        } else if (g == 2) {
          stA_f32(&pl[(size_t)((jp * 8 + h) * NPIX + i0 + t * 16 + c)], o[0]);
        }
      }
    }
  }
  gbar(ctr + 32);

  // ---------------- Stage 4: proj_ffn1 (512 units) ----------------
  {
    float(&at)[64][34] = u.s4.at;
    float(&wsh)[64][64] = u.s4.wsh;
    float(&xsl)[64][34] = u.s4.xsl;
    float(&ps)[16][32] = u.s4.ps;
    float(&pq)[16][32] = u.s4.pq;
    float(&mus)[32] = u.s4.mus;
    float(&rss)[32] = u.s4.rss;
    int n0 = (bid & 127) * 32;
    int ch = bid >> 7;
    int mm = tid >> 2, kg = (tid & 3) * 16;
    {
      const float4* wr = (const float4*)&projW[mm * 64 + kg];
      float4 w0 = wr[0], w1 = wr[1], w2 = wr[2], w3 = wr[3];
      float wv[16] = {w0.x, w0.y, w0.z, w0.w, w1.x, w1.y, w1.z, w1.w,
                      w2.x, w2.y, w2.z, w2.w, w3.x, w3.y, w3.z, w3.w};
#pragma unroll
      for (int j = 0; j < 16; j++) wsh[kg + j][mm] = wv[j];
    }
    {
      int hh = tid >> 5, nn = tid & 31;
      int i = n0 + nn;
      float L = 0.f, o[8] = {};
#pragma unroll
      for (int p = 0; p < 8; p++) {
        size_t base = (size_t)((p * 8 + hh) * NPIX + i);
        L += pl[base];
        const float4 a0 = *(const float4*)&pacc[base * 8];
        const float4 a1 = *(const float4*)&pacc[base * 8 + 4];
        o[0] += a0.x; o[1] += a0.y; o[2] += a0.z; o[3] += a0.w;
        o[4] += a1.x; o[5] += a1.y; o[6] += a1.z; o[7] += a1.w;
      }
      float inv = 1.f / L;
#pragma unroll
      for (int d = 0; d < 8; d++) at[hh * 8 + d][nn] = o[d] * inv;
    }
    __syncthreads();
    int mq = tid >> 4, pp = (tid & 15) * 2;
    float acc[4][2] = {};
#pragma unroll 8
    for (int k = 0; k < 64; k++) {
      float4 w4 = *(const float4*)&wsh[k][mq * 4];
      float2 b2 = *(const float2*)&at[k][pp];
      acc[0][0] = fmaf(w4.x, b2.x, acc[0][0]);
      acc[0][1] = fmaf(w4.x, b2.y, acc[0][1]);
      acc[1][0] = fmaf(w4.y, b2.x, acc[1][0]);
      acc[1][1] = fmaf(w4.y, b2.y, acc[1][1]);
      acc[2][0] = fmaf(w4.z, b2.x, acc[2][0]);
      acc[2][1] = fmaf(w4.z, b2.y, acc[2][1]);
      acc[3][0] = fmaf(w4.w, b2.x, acc[3][0]);
      acc[3][1] = fmaf(w4.w, b2.y, acc[3][1]);
    }
    float v[4][2], sn0 = 0.f, sn1 = 0.f, qn0 = 0.f, qn1 = 0.f;
#pragma unroll
    for (int im = 0; im < 4; im++) {
      int row = mq * 4 + im;
      float bpv = projB[row];
      const float2 xr = *(const float2*)&x[row * NPIX + n0 + pp];
      float v0 = acc[im][0] + bpv + xr.x;
      float v1 = acc[im][1] + bpv + xr.y;
      v[im][0] = v0;
      v[im][1] = v1;
      sn0 += v0;
      qn0 = fmaf(v0, v0, qn0);
      sn1 += v1;
      qn1 = fmaf(v1, v1, qn1);
    }
    if (ch == 0) {
#pragma unroll
      for (int im = 0; im < 4; im++)
        stA_u64(&x1[(mq * 4 + im) * NPIX + n0 + pp],
                __builtin_bit_cast(unsigned long long,
                                   make_float2(v[im][0], v[im][1])));
    }
    ps[mq][pp] = sn0;
    ps[mq][pp + 1] = sn1;
    pq[mq][pp] = qn0;
    pq[mq][pp + 1] = qn1;
    __syncthreads();
    // Stage W1 slice into the (now free) weight buffer; tid<32 does LN stats.
    {
      const float4* w1r = (const float4*)&ffn1W[(ch * 64 + mm) * 64 + kg];
      float4 u0 = w1r[0], u1 = w1r[1], u2 = w1r[2], u3 = w1r[3];
      float uv[16] = {u0.x, u0.y, u0.z, u0.w, u1.x, u1.y, u1.z, u1.w,
                      u2.x, u2.y, u2.z, u2.w, u3.x, u3.y, u3.z, u3.w};
#pragma unroll
      for (int j = 0; j < 16; j++) wsh[kg + j][mm] = uv[j];
    }
    if (tid < 32) {
      float s = 0.f, q = 0.f;
#pragma unroll
      for (int t = 0; t < 16; t++) {
        s += ps[t][tid];
        q += pq[t][tid];
      }
      float mu = s * (1.f / 64.f);
      mus[tid] = mu;
      rss[tid] = rsqrtf(q * (1.f / 64.f) - mu * mu + 1e-5f);
    }
    __syncthreads();
    {
      float mu0 = mus[pp], mu1v = mus[pp + 1];
      float rs0 = rss[pp], rs1v = rss[pp + 1];
#pragma unroll
      for (int im = 0; im < 4; im++) {
        int row = mq * 4 + im;
        float w2v = ln2w[row], b2v = ln2b[row];
        *(float2*)&xsl[row][pp] =
            make_float2((v[im][0] - mu0) * rs0 * w2v + b2v,
                        (v[im][1] - mu1v) * rs1v * w2v + b2v);
      }
    }
    __syncthreads();
    float a2[4][2] = {};
#pragma unroll 8
    for (int k = 0; k < 64; k++) {
      float4 w4 = *(const float4*)&wsh[k][mq * 4];
      float2 b2 = *(const float2*)&xsl[k][pp];
      a2[0][0] = fmaf(w4.x, b2.x, a2[0][0]);
      a2[0][1] = fmaf(w4.x, b2.y, a2[0][1]);
      a2[1][0] = fmaf(w4.y, b2.x, a2[1][0]);
      a2[1][1] = fmaf(w4.y, b2.y, a2[1][1]);
      a2[2][0] = fmaf(w4.z, b2.x, a2[2][0]);
      a2[2][1] = fmaf(w4.z, b2.y, a2[2][1]);
      a2[3][0] = fmaf(w4.w, b2.x, a2[3][0]);
      a2[3][1] = fmaf(w4.w, b2.y, a2[3][1]);
    }
#pragma unroll
    for (int im = 0; im < 4; im++) {
      int row = ch * 64 + mq * 4 + im;
      float bb = ffn1B[row];
      stA_u64(&f1[row * NPIX + n0 + pp],
              __builtin_bit_cast(unsigned long long,
                                 make_float2(a2[im][0] + bb, a2[im][1] + bb)));
    }
  }
  gbar(ctr + 48);

  // ---------------- Stage 5: ffn2_dw (512 units) ----------------
  {
    float(&xs2)[16][260] = u.s5.xs2;
    float(&wshT)[32][260] = u.s5.wshT;
    int n0 = (bid & 255) * 16, m0 = (bid >> 8) * 32;
    int y = n0 >> 6, x0 = n0 & 63;
    {
      int mm = tid >> 3, kg = (tid & 7) * 32;
      const float4* src = (const float4*)&ffn2W[(m0 + mm) * 256 + kg];
      float4* dst = (float4*)&wshT[mm][kg];
#pragma unroll
      for (int i = 0; i < 8; i++) dst[i] = src[i];
    }
    {
      int px4 = (tid & 3) * 4;
      int xabs = x0 + px4;
#pragma unroll
      for (int k = 0; k < 4; k++) {
        int c = (tid >> 2) + 64 * k;
        const float* base = f1 + c * NPIX;
        float wv[9];
#pragma unroll
        for (int i = 0; i < 9; i++) wv[i] = dww[c * 9 + i];
        float bc = dwb[c];
        float a[4] = {bc, bc, bc, bc};
#pragma unroll
        for (int dy = 0; dy < 3; dy++) {
          int yy = y + dy - 1;
          if (yy < 0 || yy > 63) continue;
          const float* row = base + yy * IMG + xabs;
          float4 mid = *(const float4*)row;
          float left = (xabs > 0) ? row[-1] : 0.f;
          float right = (xabs + 4 < IMG) ? row[4] : 0.f;
          float win[6] = {left, mid.x, mid.y, mid.z, mid.w, right};
#pragma unroll
          for (int o = 0; o < 4; o++)
#pragma unroll
            for (int dx = 0; dx < 3; dx++)
              a[o] = fmaf(wv[dy * 3 + dx], win[o + dx], a[o]);
        }
#pragma unroll
        for (int o = 0; o < 4; o++)
          xs2[px4 + o][c] =
              0.5f * a[o] * (1.f + erff(a[o] * 0.70710678118654752f));
      }
    }
    __syncthreads();
    int m = tid >> 3, np = (tid & 7) * 2;
    float a0 = 0.f, a1 = 0.f;
#pragma unroll 4
    for (int k4 = 0; k4 < 64; k4++) {
      float4 w4 = *(const float4*)&wshT[m][k4 * 4];
      float4 xa = *(const float4*)&xs2[np][k4 * 4];
      float4 xb = *(const float4*)&xs2[np + 1][k4 * 4];
      a0 = fmaf(w4.x, xa.x, a0);
      a1 = fmaf(w4.x, xb.x, a1);
      a0 = fmaf(w4.y, xa.y, a0);
      a1 = fmaf(w4.y, xb.y, a1);
      a0 = fmaf(w4.z, xa.z, a0);
      a1 = fmaf(w4.z, xb.z, a1);
      a0 = fmaf(w4.w, xa.w, a0);
      a1 = fmaf(w4.w, xb.w, a1);
    }
    int row = m0 + m;
    float bv = ffn2B[row];
    const float2 rr = *(const float2*)&x1[row * NPIX + n0 + np];
    *(float2*)&out[row * NPIX + n0 + np] =
        make_float2(a0 + bv + rr.x, a1 + bv + rr.y);
  }
}

// ---------------------------------------------------------------------------
extern "C" void kernel_launch(void* const* d_in, const int* in_sizes, int n_in,
                              void* d_out, int out_size, void* d_ws,
                              size_t ws_size, hipStream_t stream) {
  const float* x      = (const float*)d_in[0];
  const float* luma   = (const float*)d_in[1];
  const float* ln1_w  = (const float*)d_in[2];
  const float* ln1_b  = (const float*)d_in[3];
  const float* qkv_w  = (const float*)d_in[4];
  const float* qkv_b  = (const float*)d_in[5];
  const float* proj_w = (const float*)d_in[6];
  const float* proj_b = (const float*)d_in[7];
  const float* lc1_w  = (const float*)d_in[8];
  const float* lc1_b  = (const float*)d_in[9];
  const float* lc2_w  = (const float*)d_in[10];
  const float* lc2_b  = (const float*)d_in[11];
  const float* gam_w  = (const float*)d_in[12];
  const float* gam_b  = (const float*)d_in[13];
  const float* bet_w  = (const float*)d_in[14];
  const float* bet_b  = (const float*)d_in[15];
  const float* alpha  = (const float*)d_in[16];
  const float* ln2_w  = (const float*)d_in[17];
  const float* ln2_b  = (const float*)d_in[18];
  const float* ffn1_w = (const float*)d_in[19];
  const float* ffn1_b = (const float*)d_in[20];
  const float* dw_w   = (const float*)d_in[21];
  const float* dw_b   = (const float*)d_in[22];
  const float* ffn2_w = (const float*)d_in[23];
  const float* ffn2_b = (const float*)d_in[24];
  float* out = (float*)d_out;

  float* w = (float*)d_ws;
  float* pooled = w + 0;        // 4096
  float* bsums  = w + 4096;     // 64 (16 used)
  unsigned short* cbuf = (unsigned short*)(w + 4160);     // 64 f (16 us used)
  float* mu1 = w + 4224;        // 4096
  float* rs1 = w + 8320;        // 4096
  unsigned short* qhl  = (unsigned short*)(w + 12416);    // 262144 f
  unsigned short* khl  = (unsigned short*)(w + 274560);   // 262144 f
  unsigned short* vthx = (unsigned short*)(w + 536704);   // 131072 f
  unsigned short* vtlx = (unsigned short*)(w + 667776);   // 131072 f
  float* pacc = w + 798848;    // 2097152 (JP=8)
  float* pl   = w + 2896000;   // 262144
  float* x1   = w + 3158144;   // 262144
  float* f1   = w + 3420288;   // 1048576
  float* h2   = w + 4468864;   // 131072
  unsigned int* ctr = (unsigned int*)(w + 4599936);  // 64 uints

  init_kernel<<<1, 128, 0, stream>>>(ctr, cbuf);
  fused_kernel<<<dim3(NBLK), 256, 0, stream>>>(
      x, luma, lc1_w, lc1_b, lc2_w, lc2_b, ln1_w, ln1_b, qkv_w, qkv_b, gam_w,
      gam_b, bet_w, bet_b, alpha, proj_w, proj_b, ln2_w, ln2_b, ffn1_w, ffn1_b,
      dw_w, dw_b, ffn2_w, ffn2_b, out, pooled, bsums, cbuf, mu1, rs1, qhl, khl,
      vthx, vtlx, pacc, pl, x1, f1, h2, ctr);
}

// Round 6
// 208.885 us; speedup vs baseline: 2.9480x; 1.2800x over previous
//
#include <hip/hip_runtime.h>
#include <math.h>

// B=1, C=64, H=W=64, N=4096, heads=8, dh=8, inner=64, hid_lc=32, hid_f=256.
// Persistent fused kernel, 5 stages, hierarchical grid barriers.
// Grid 512 x 256. r6: (a) 2-level barrier (8 groups of 64; per-group arrive +
// release lines, 8-entry global line) kills the 512-poller single-LLC-line
// contention of r5; (b) stage 1 spread over all 512 blocks (8x8 tiles);
// (c) stage 2 spread over all 512 blocks (v-part duplicated into hi/lo
// writer halves). Inter-stage stores remain agent-scope write-through
// (no L2 maintenance anywhere).
#define NPIX 4096
#define IMG 64
#define NBLK 512

typedef __attribute__((ext_vector_type(8))) short bf16x8;
typedef __attribute__((ext_vector_type(4))) float floatx4;
typedef __attribute__((ext_vector_type(4))) unsigned int uintx4;

__device__ __forceinline__ unsigned int split_pack(float x) {
  unsigned int u = __float_as_uint(x);
  unsigned int hif = u & 0xffff0000u;
  float lof = x - __uint_as_float(hif);
  return (u >> 16) | (__float_as_uint(lof) & 0xffff0000u);
}

__device__ __forceinline__ unsigned int pack_hi2(float a, float b) {
  return __builtin_amdgcn_perm(__float_as_uint(b), __float_as_uint(a),
                               0x07060302u);
}

__device__ __forceinline__ void stA_f32(float* p, float v) {
  __hip_atomic_store(p, v, __ATOMIC_RELAXED, __HIP_MEMORY_SCOPE_AGENT);
}
__device__ __forceinline__ void stA_u32(void* p, unsigned int v) {
  __hip_atomic_store((unsigned int*)p, v, __ATOMIC_RELAXED,
                     __HIP_MEMORY_SCOPE_AGENT);
}
__device__ __forceinline__ void stA_u64(void* p, unsigned long long v) {
  __hip_atomic_store((unsigned long long*)p, v, __ATOMIC_RELAXED,
                     __HIP_MEMORY_SCOPE_AGENT);
}
__device__ __forceinline__ unsigned int ldA(const unsigned int* p) {
  return __hip_atomic_load(p, __ATOMIC_RELAXED, __HIP_MEMORY_SCOPE_AGENT);
}
__device__ __forceinline__ unsigned int addA(unsigned int* p) {
  return __hip_atomic_fetch_add(p, 1u, __ATOMIC_RELAXED,
                                __HIP_MEMORY_SCOPE_AGENT);
}

// Hierarchical grid barrier. base = 512-uint region for this barrier:
//   group g (g=0..7, 64 blocks each): arrive @ base[g*32], release @
//   base[g*32+16] (separate 128B lines); global done @ base[256].
// The 64th arriver of a group is leader: bumps global, polls global==8,
// then sets the group release flag. Members poll only their group line
// (<=63 pollers/line). vmcnt(0) drain inside __syncthreads orders the
// write-through stores before arrival.
__device__ __forceinline__ void gbar(unsigned int* base, int bid) {
  __syncthreads();
  if (threadIdx.x == 0) {
    int g = bid >> 6;
    unsigned int* ga = base + g * 32;
    unsigned int old = addA(ga);
    if (old == 63u) {
      addA(base + 256);
      while (ldA(base + 256) < 8u) __builtin_amdgcn_s_sleep(1);
      stA_u32(ga + 16, 1u);
    } else {
      while (ldA(ga + 16) == 0u) __builtin_amdgcn_s_sleep(2);
    }
    asm volatile("" ::: "memory");
  }
  __syncthreads();
}

// LDS stage overlays.
struct S1 {  // lc12, 8x8 tiles
  float lum[144];       // 12x12
  float sw1[288];
  float tin[32][100];   // h1 on 10x10 halo per ic
  float swt[4][32][9];
  float red[64];
};
struct S2 {  // ln_qkv
  float xs[64][32];
  float wsh[64][64];
  float h2s[32][32];
  float wgs[32][64];
  float wbs[32][64];
  float mu[32];
  float rs[32];
};
struct S4 {  // proj_ffn1
  float at[64][34];
  float wsh[64][64];
  float xsl[64][34];
  float ps[16][32];
  float pq[16][32];
  float mus[32];
  float rss[32];
};
struct S5 {  // ffn2_dw
  float xs2[16][260];
  float wshT[32][260];
};
union SU {
  S1 s1;
  S2 s2;
  S4 s4;
  S5 s5;
};

__global__ void init_kernel(unsigned int* __restrict__ ctr,
                            unsigned short* __restrict__ cbuf) {
  int t = threadIdx.x;
#pragma unroll
  for (int i = 0; i < 8; i++) ctr[t + i * 256] = 0u;
  if (t < 16) cbuf[t] = (t < 8) ? 0x3F80 : 0;
}

__global__ __launch_bounds__(256, 3) void fused_kernel(
    const float* __restrict__ x, const float* __restrict__ luma,
    const float* __restrict__ lc1w, const float* __restrict__ lc1b,
    const float* __restrict__ lc2w, const float* __restrict__ lc2b,
    const float* __restrict__ ln1w, const float* __restrict__ ln1b,
    const float* __restrict__ qkvW, const float* __restrict__ qkvB,
    const float* __restrict__ gamW, const float* __restrict__ gamB,
    const float* __restrict__ betW, const float* __restrict__ betB,
    const float* __restrict__ alpha, const float* __restrict__ projW,
    const float* __restrict__ projB, const float* __restrict__ ln2w,
    const float* __restrict__ ln2b, const float* __restrict__ ffn1W,
    const float* __restrict__ ffn1B, const float* __restrict__ dww,
    const float* __restrict__ dwb, const float* __restrict__ ffn2W,
    const float* __restrict__ ffn2B, float* __restrict__ out,
    float* __restrict__ pooled, float* __restrict__ bsums,
    unsigned short* __restrict__ cbuf, float* __restrict__ mu1,
    float* __restrict__ rs1, unsigned short* __restrict__ qhl,
    unsigned short* __restrict__ khl, unsigned short* __restrict__ vthx,
    unsigned short* __restrict__ vtlx, float* __restrict__ pacc,
    float* __restrict__ pl, float* __restrict__ x1, float* __restrict__ f1,
    float* __restrict__ h2, unsigned int* __restrict__ ctr) {
  __shared__ SU u;
  int bid = blockIdx.x;
  int tid = threadIdx.x;

  // ------- Stage 1: lc12 on 8x8 tiles (64 tiles x 8 ocg = 512 units) -------
  {
    int tile = bid >> 3, ocg = bid & 7;
    int ty0 = (tile >> 3) * 8, tx0 = (tile & 7) * 8;
    float(&lum)[144] = u.s1.lum;
    float(&sw1)[288] = u.s1.sw1;
    float(&tin)[32][100] = u.s1.tin;
    float(&swt)[4][32][9] = u.s1.swt;
    float(&red)[64] = u.s1.red;
    if (tid < 144) {
      int py = tid / 12, px = tid - py * 12;
      int gy = ty0 + py - 2, gx = tx0 + px - 2;
      lum[tid] = (gy >= 0 && gy < IMG && gx >= 0 && gx < IMG)
                     ? luma[gy * IMG + gx]
                     : 0.f;
    }
    for (int idx = tid; idx < 288; idx += 256) sw1[idx] = lc1w[idx];
    for (int idx = tid; idx < 1152; idx += 256) {
      int o = idx / 288, r = idx - o * 288;
      swt[o][r / 9][r % 9] = lc2w[(ocg * 4 + o) * 288 + r];
    }
    __syncthreads();
    for (int idx = tid; idx < 3200; idx += 256) {
      int ic = idx / 100, pos = idx - ic * 100;
      int py = pos / 10, px = pos - py * 10;
      int gy = ty0 + py - 1, gx = tx0 + px - 1;
      float v = 0.f;
      if (gy >= 0 && gy < IMG && gx >= 0 && gx < IMG) {
        float s = lc1b[ic];
        const float* wp = &sw1[ic * 9];
#pragma unroll
        for (int dy = 0; dy < 3; dy++)
#pragma unroll
          for (int dx = 0; dx < 3; dx++)
            s = fmaf(wp[dy * 3 + dx], lum[(py + dy) * 12 + px + dx], s);
        v = fmaxf(s, 0.f);
      }
      tin[ic][pos] = v;
    }
    __syncthreads();
    int o = tid >> 6, pix = tid & 63;
    int ly = pix >> 3, lx = pix & 7;
    int p = (ty0 + ly) * IMG + tx0 + lx;
    float acc = lc2b[ocg * 4 + o];
    for (int ic = 0; ic < 32; ic++) {
      float v[9];
#pragma unroll
      for (int dy = 0; dy < 3; dy++)
#pragma unroll
        for (int dx = 0; dx < 3; dx++)
          v[dy * 3 + dx] = tin[ic][(ly + dy) * 10 + lx + dx];
#pragma unroll
      for (int t = 0; t < 9; t++) acc = fmaf(swt[o][ic][t], v[t], acc);
    }
    stA_f32(&h2[(ocg * 4 + o) * NPIX + p], fmaxf(acc, 0.f));
    if (ocg == 0) {
      if (tid < 64) {
        int gy = ty0 + ly, gx = tx0 + lx;
        float sv = 0.f;
#pragma unroll
        for (int dy = 0; dy < 3; dy++)
#pragma unroll
          for (int dx = 0; dx < 3; dx++)
            sv += lum[(ly + dy + 1) * 12 + lx + dx + 1];
        float cy = 3.f - (gy == 0 ? 1.f : 0.f) - (gy == 63 ? 1.f : 0.f);
        float cx = 3.f - (gx == 0 ? 1.f : 0.f) - (gx == 63 ? 1.f : 0.f);
        float pv = (cy * cx - sv) * (1.f / 9.f);
        stA_f32(&pooled[p], pv);
        red[tid] = pv;
      }
      __syncthreads();
      for (int st = 32; st > 0; st >>= 1) {
        if (tid < st) red[tid] += red[tid + st];
        __syncthreads();
      }
      if (tid == 0) stA_f32(&bsums[tile], red[0]);
      if (tid < 64) {
        float s = 0.f, q = 0.f;
#pragma unroll 8
        for (int cc = 0; cc < 64; cc++) {
          float xv = x[cc * NPIX + p];
          s += xv;
          q = fmaf(xv, xv, q);
        }
        float mu = s * (1.f / 64.f);
        stA_f32(&mu1[p], mu);
        stA_f32(&rs1[p], rsqrtf(q * (1.f / 64.f) - mu * mu + 1e-5f));
      }
    }
  }
  gbar(ctr + 0, bid);

  // ------- Stage 2: ln_qkv (4 parts x 128 n-tiles = 512 units) -------
  {
    const float QSCALE = 0.35355339059327376f * 1.4426950408889634f;
    float(&xs)[64][32] = u.s2.xs;
    float(&wsh)[64][64] = u.s2.wsh;
    float(&h2s)[32][32] = u.s2.h2s;
    float(&wgs)[32][64] = u.s2.wgs;
    float(&wbs)[32][64] = u.s2.wbs;
    float(&mu)[32] = u.s2.mu;
    float(&rs)[32] = u.s2.rs;
    int n0 = (bid & 127) * 32, part = bid >> 7;
    int m0 = (part < 2 ? part : 2) * 64;
    if (tid < 32) {
      mu[tid] = mu1[n0 + tid];
      rs[tid] = rs1[n0 + tid];
    }
    {
      int e = tid * 2;
      int c = e >> 3, off = (e & 7) * 4;
      *(float4*)&xs[c][off] = *(const float4*)&x[c * NPIX + n0 + off];
      int e1 = e + 1;
      int c1 = e1 >> 3, off1 = (e1 & 7) * 4;
      *(float4*)&xs[c1][off1] = *(const float4*)&x[c1 * NPIX + n0 + off1];
    }
    {
      int m = tid >> 2, kg = (tid & 3) * 16;
      const float4* wr = (const float4*)&qkvW[(m0 + m) * 64 + kg];
      float4 w0 = wr[0], w1 = wr[1], w2 = wr[2], w3 = wr[3];
      float wv[16] = {w0.x, w0.y, w0.z, w0.w, w1.x, w1.y, w1.z, w1.w,
                      w2.x, w2.y, w2.z, w2.w, w3.x, w3.y, w3.z, w3.w};
#pragma unroll
      for (int j = 0; j < 16; j++) wsh[kg + j][m] = wv[j];
    }
    {
      int k = tid >> 3, nf = (tid & 7) * 4;
      *(float4*)&h2s[k][nf] = *(const float4*)&h2[k * NPIX + n0 + nf];
    }
    {
      int m = tid >> 2, kg = (tid & 3) * 8;
      const float4* g0 = (const float4*)&gamW[m * 32 + kg];
      float4 a = g0[0], b4 = g0[1];
      float gv[8] = {a.x, a.y, a.z, a.w, b4.x, b4.y, b4.z, b4.w};
#pragma unroll
      for (int j = 0; j < 8; j++) wgs[kg + j][m] = gv[j];
      const float4* bb0 = (const float4*)&betW[m * 32 + kg];
      float4 c4 = bb0[0], d4 = bb0[1];
      float bv[8] = {c4.x, c4.y, c4.z, c4.w, d4.x, d4.y, d4.z, d4.w};
#pragma unroll
      for (int j = 0; j < 8; j++) wbs[kg + j][m] = bv[j];
    }
    __syncthreads();
    {
      int c = tid >> 2, pg = (tid & 3) * 8;
      float wc = ln1w[c], bc = ln1b[c];
#pragma unroll
      for (int j = 0; j < 8; j++) {
        int p = pg + j;
        xs[c][p] = (xs[c][p] - mu[p]) * rs[p] * wc + bc;
      }
    }
    __syncthreads();
    int tx = tid & 15, ty = tid >> 4;
    float ga[4][2] = {}, ba[4][2] = {};
#pragma unroll 8
    for (int kk = 0; kk < 32; kk++) {
      float4 wg4 = *(const float4*)&wgs[kk][ty * 4];
      float4 wb4 = *(const float4*)&wbs[kk][ty * 4];
      float2 h22 = *(const float2*)&h2s[kk][tx * 2];
      float gv[4] = {wg4.x, wg4.y, wg4.z, wg4.w};
      float bv[4] = {wb4.x, wb4.y, wb4.z, wb4.w};
      float hv[2] = {h22.x, h22.y};
#pragma unroll
      for (int im = 0; im < 4; im++)
#pragma unroll
        for (int in = 0; in < 2; in++) {
          ga[im][in] = fmaf(gv[im], hv[in], ga[im][in]);
          ba[im][in] = fmaf(bv[im], hv[in], ba[im][in]);
        }
    }
#pragma unroll
    for (int im = 0; im < 4; im++) {
      int cc = ty * 4 + im;
      float gb = gamB[cc], bb2 = betB[cc];
#pragma unroll
      for (int in = 0; in < 2; in++) {
        ga[im][in] += gb;
        ba[im][in] += bb2;
      }
    }
    float acc[4][2] = {};
#pragma unroll 8
    for (int kk = 0; kk < 64; kk++) {
      float4 a = *(const float4*)&wsh[kk][ty * 4];
      float2 b2 = *(const float2*)&xs[kk][tx * 2];
      float av[4] = {a.x, a.y, a.z, a.w};
      float bv[2] = {b2.x, b2.y};
#pragma unroll
      for (int im = 0; im < 4; im++)
#pragma unroll
        for (int in = 0; in < 2; in++)
          acc[im][in] = fmaf(av[im], bv[in], acc[im][in]);
    }
    float val[4][2];
#pragma unroll
    for (int im = 0; im < 4; im++) {
      int cc = ty * 4 + im;
      float bv = qkvB[m0 + cc];
#pragma unroll
      for (int in = 0; in < 2; in++)
        val[im][in] = fmaf(ga[im][in], acc[im][in] + bv, ba[im][in]);
    }
    if (part == 0) {
      float msum = 0.f;
      for (int t = 0; t < 64; t++) msum += bsums[t];
      float mean = msum * (1.f / 4096.f);
      float a0 = alpha[0];
      const float2 pv = *(const float2*)&pooled[n0 + tx * 2];
      float iv[2] = {a0 * (pv.x - mean), a0 * (pv.y - mean)};
#pragma unroll
      for (int im = 0; im < 4; im++)
#pragma unroll
        for (int in = 0; in < 2; in++)
          val[im][in] = (val[im][in] + iv[in]) * QSCALE;
    }
    if (part < 2) {
      unsigned short* dst = (part == 0) ? qhl : khl;
      int hh = ty >> 1, d0 = (ty & 1) * 4;
#pragma unroll
      for (int in = 0; in < 2; in++) {
        int n = n0 + tx * 2 + in;
        unsigned int pk[4];
#pragma unroll
        for (int im = 0; im < 4; im++) pk[im] = split_pack(val[im][in]);
        short4 hi, lo;
        hi.x = (short)(pk[0] & 0xffffu); hi.y = (short)(pk[1] & 0xffffu);
        hi.z = (short)(pk[2] & 0xffffu); hi.w = (short)(pk[3] & 0xffffu);
        lo.x = (short)(pk[0] >> 16); lo.y = (short)(pk[1] >> 16);
        lo.z = (short)(pk[2] >> 16); lo.w = (short)(pk[3] >> 16);
        unsigned short* base = dst + ((size_t)(hh * NPIX + n) << 4) + d0;
        stA_u64(base, __builtin_bit_cast(unsigned long long, hi));
        stA_u64(base + 8, __builtin_bit_cast(unsigned long long, lo));
      }
    } else {
      int nq = n0 + tx * 2;
      int off0 = (nq >> 5) * 32 + ((nq >> 4) & 1) * 4 + ((nq >> 2) & 3) * 8 +
                 (nq & 3);
#pragma unroll
      for (int im = 0; im < 4; im++) {
        int cc = ty * 4 + im;
        unsigned int pk0 = split_pack(val[im][0]);
        unsigned int pk1 = split_pack(val[im][1]);
        if (part == 2) {
          short2 hi;
          hi.x = (short)(pk0 & 0xffffu);
          hi.y = (short)(pk1 & 0xffffu);
          stA_u32(vthx + (size_t)cc * NPIX + off0,
                  __builtin_bit_cast(unsigned int, hi));
        } else {
          short2 lo;
          lo.x = (short)(pk0 >> 16);
          lo.y = (short)(pk1 >> 16);
          stA_u32(vtlx + (size_t)cc * NPIX + off0,
                  __builtin_bit_cast(unsigned int, lo));
        }
      }
    }
  }
  gbar(ctr + 512, bid);

  // ------- Stage 3: attn (1024 units, 2 per block) -------
  {
    int wave = tid >> 6, lane = tid & 63;
    int g = lane >> 4, c = lane & 15;
#pragma unroll 1
    for (int rep = 0; rep < 2; rep++) {
      int unit = bid * 2 + rep;
      int h = (unit >> 4) & 7, jp = unit >> 7;
      int i0 = (unit & 15) * 256 + wave * 64;
      int jbase = jp * 512;
      bf16x8 qB[4];
#pragma unroll
      for (int t = 0; t < 4; t++)
        qB[t] = *(const bf16x8*)(qhl +
                                 ((size_t)(h * NPIX + i0 + t * 16 + c) << 4) +
                                 ((g & 1) << 3));
      const unsigned short* kp =
          khl + ((size_t)(h * NPIX + jbase + c) << 4) + ((g >> 1) << 3);
      const unsigned short* vhp;
      const unsigned short* vlp;
      int vstep;
      if (c < 8) {
        vhp = vthx + (size_t)(h * 8 + c) * NPIX + jbase + (g << 3);
        vlp = vtlx + (size_t)(h * 8 + c) * NPIX + jbase + (g << 3);
        vstep = 32;
      } else {
        vhp = (c == 8) ? cbuf : (cbuf + 8);  // ones row / zero rows
        vlp = cbuf + 8;
        vstep = 0;
      }
      floatx4 zero4 = {0.f, 0.f, 0.f, 0.f};
      floatx4 aH[4], aM[4];
#pragma unroll
      for (int t = 0; t < 4; t++) {
        aH[t] = zero4;
        aM[t] = zero4;
      }
#pragma unroll 4
      for (int jt = 0; jt < 16; ++jt) {
        bf16x8 ka0 = *(const bf16x8*)kp;
        bf16x8 ka1 = *(const bf16x8*)(kp + 256);
        bf16x8 avh = *(const bf16x8*)vhp;
        bf16x8 avl = *(const bf16x8*)vlp;
        kp += 512;
        vhp += vstep;
        vlp += vstep;
#pragma unroll
        for (int t = 0; t < 4; t++) {
          floatx4 s0 = __builtin_amdgcn_mfma_f32_16x16x32_bf16(ka0, qB[t],
                                                               zero4, 0, 0, 0);
          floatx4 s1 = __builtin_amdgcn_mfma_f32_16x16x32_bf16(ka1, qB[t],
                                                               zero4, 0, 0, 0);
          float p0 = __builtin_amdgcn_exp2f(fminf(s0[0], 80.f));
          float p1 = __builtin_amdgcn_exp2f(fminf(s0[1], 80.f));
          float p2 = __builtin_amdgcn_exp2f(fminf(s0[2], 80.f));
          float p3 = __builtin_amdgcn_exp2f(fminf(s0[3], 80.f));
          float p4 = __builtin_amdgcn_exp2f(fminf(s1[0], 80.f));
          float p5 = __builtin_amdgcn_exp2f(fminf(s1[1], 80.f));
          float p6 = __builtin_amdgcn_exp2f(fminf(s1[2], 80.f));
          float p7 = __builtin_amdgcn_exp2f(fminf(s1[3], 80.f));
          uintx4 bh;
          bh.x = pack_hi2(p0, p1);
          bh.y = pack_hi2(p2, p3);
          bh.z = pack_hi2(p4, p5);
          bh.w = pack_hi2(p6, p7);
          bf16x8 pbh = __builtin_bit_cast(bf16x8, bh);
          aH[t] =
              __builtin_amdgcn_mfma_f32_16x16x32_bf16(avh, pbh, aH[t], 0, 0, 0);
          aM[t] =
              __builtin_amdgcn_mfma_f32_16x16x32_bf16(avl, pbh, aM[t], 0, 0, 0);
        }
      }
#pragma unroll
      for (int t = 0; t < 4; t++) {
        floatx4 o = aH[t] + aM[t];
        if (g < 2) {
          size_t b0 = (size_t)((jp * 8 + h) * NPIX + i0 + t * 16 + c);
          float2 lo2 = make_float2(o[0], o[1]);
          float2 hi2 = make_float2(o[2], o[3]);
          stA_u64(&pacc[b0 * 8 + g * 4],
                  __builtin_bit_cast(unsigned long long, lo2));
          stA_u64(&pacc[b0 * 8 + g * 4 + 2],
                  __builtin_bit_cast(unsigned long long, hi2));
        } else if (g == 2) {
          stA_f32(&pl[(size_t)((jp * 8 + h) * NPIX + i0 + t * 16 + c)], o[0]);
        }
      }
    }
  }
  gbar(ctr + 1024, bid);

  // ------- Stage 4: proj_ffn1 (512 units) -------
  {
    float(&at)[64][34] = u.s4.at;
    float(&wsh)[64][64] = u.s4.wsh;
    float(&xsl)[64][34] = u.s4.xsl;
    float(&ps)[16][32] = u.s4.ps;
    float(&pq)[16][32] = u.s4.pq;
    float(&mus)[32] = u.s4.mus;
    float(&rss)[32] = u.s4.rss;
    int n0 = (bid & 127) * 32;
    int ch = bid >> 7;
    int mm = tid >> 2, kg = (tid & 3) * 16;
    {
      const float4* wr = (const float4*)&projW[mm * 64 + kg];
      float4 w0 = wr[0], w1 = wr[1], w2 = wr[2], w3 = wr[3];
      float wv[16] = {w0.x, w0.y, w0.z, w0.w, w1.x, w1.y, w1.z, w1.w,
                      w2.x, w2.y, w2.z, w2.w, w3.x, w3.y, w3.z, w3.w};
#pragma unroll
      for (int j = 0; j < 16; j++) wsh[kg + j][mm] = wv[j];
    }
    {
      int hh = tid >> 5, nn = tid & 31;
      int i = n0 + nn;
      float L = 0.f, o[8] = {};
#pragma unroll
      for (int p = 0; p < 8; p++) {
        size_t base = (size_t)((p * 8 + hh) * NPIX + i);
        L += pl[base];
        const float4 a0 = *(const float4*)&pacc[base * 8];
        const float4 a1 = *(const float4*)&pacc[base * 8 + 4];
        o[0] += a0.x; o[1] += a0.y; o[2] += a0.z; o[3] += a0.w;
        o[4] += a1.x; o[5] += a1.y; o[6] += a1.z; o[7] += a1.w;
      }
      float inv = 1.f / L;
#pragma unroll
      for (int d = 0; d < 8; d++) at[hh * 8 + d][nn] = o[d] * inv;
    }
    __syncthreads();
    int mq = tid >> 4, pp = (tid & 15) * 2;
    float acc[4][2] = {};
#pragma unroll 8
    for (int k = 0; k < 64; k++) {
      float4 w4 = *(const float4*)&wsh[k][mq * 4];
      float2 b2 = *(const float2*)&at[k][pp];
      acc[0][0] = fmaf(w4.x, b2.x, acc[0][0]);
      acc[0][1] = fmaf(w4.x, b2.y, acc[0][1]);
      acc[1][0] = fmaf(w4.y, b2.x, acc[1][0]);
      acc[1][1] = fmaf(w4.y, b2.y, acc[1][1]);
      acc[2][0] = fmaf(w4.z, b2.x, acc[2][0]);
      acc[2][1] = fmaf(w4.z, b2.y, acc[2][1]);
      acc[3][0] = fmaf(w4.w, b2.x, acc[3][0]);
      acc[3][1] = fmaf(w4.w, b2.y, acc[3][1]);
    }
    float v[4][2], sn0 = 0.f, sn1 = 0.f, qn0 = 0.f, qn1 = 0.f;
#pragma unroll
    for (int im = 0; im < 4; im++) {
      int row = mq * 4 + im;
      float bpv = projB[row];
      const float2 xr = *(const float2*)&x[row * NPIX + n0 + pp];
      float v0 = acc[im][0] + bpv + xr.x;
      float v1 = acc[im][1] + bpv + xr.y;
      v[im][0] = v0;
      v[im][1] = v1;
      sn0 += v0;
      qn0 = fmaf(v0, v0, qn0);
      sn1 += v1;
      qn1 = fmaf(v1, v1, qn1);
    }
    if (ch == 0) {
#pragma unroll
      for (int im = 0; im < 4; im++)
        stA_u64(&x1[(mq * 4 + im) * NPIX + n0 + pp],
                __builtin_bit_cast(unsigned long long,
                                   make_float2(v[im][0], v[im][1])));
    }
    ps[mq][pp] = sn0;
    ps[mq][pp + 1] = sn1;
    pq[mq][pp] = qn0;
    pq[mq][pp + 1] = qn1;
    __syncthreads();
    {
      const float4* w1r = (const float4*)&ffn1W[(ch * 64 + mm) * 64 + kg];
      float4 u0 = w1r[0], u1 = w1r[1], u2 = w1r[2], u3 = w1r[3];
      float uv[16] = {u0.x, u0.y, u0.z, u0.w, u1.x, u1.y, u1.z, u1.w,
                      u2.x, u2.y, u2.z, u2.w, u3.x, u3.y, u3.z, u3.w};
#pragma unroll
      for (int j = 0; j < 16; j++) wsh[kg + j][mm] = uv[j];
    }
    if (tid < 32) {
      float s = 0.f, q = 0.f;
#pragma unroll
      for (int t = 0; t < 16; t++) {
        s += ps[t][tid];
        q += pq[t][tid];
      }
      float mu = s * (1.f / 64.f);
      mus[tid] = mu;
      rss[tid] = rsqrtf(q * (1.f / 64.f) - mu * mu + 1e-5f);
    }
    __syncthreads();
    {
      float mu0 = mus[pp], mu1v = mus[pp + 1];
      float rs0 = rss[pp], rs1v = rss[pp + 1];
#pragma unroll
      for (int im = 0; im < 4; im++) {
        int row = mq * 4 + im;
        float w2v = ln2w[row], b2v = ln2b[row];
        *(float2*)&xsl[row][pp] =
            make_float2((v[im][0] - mu0) * rs0 * w2v + b2v,
                        (v[im][1] - mu1v) * rs1v * w2v + b2v);
      }
    }
    __syncthreads();
    float a2[4][2] = {};
#pragma unroll 8
    for (int k = 0; k < 64; k++) {
      float4 w4 = *(const float4*)&wsh[k][mq * 4];
      float2 b2 = *(const float2*)&xsl[k][pp];
      a2[0][0] = fmaf(w4.x, b2.x, a2[0][0]);
      a2[0][1] = fmaf(w4.x, b2.y, a2[0][1]);
      a2[1][0] = fmaf(w4.y, b2.x, a2[1][0]);
      a2[1][1] = fmaf(w4.y, b2.y, a2[1][1]);
      a2[2][0] = fmaf(w4.z, b2.x, a2[2][0]);
      a2[2][1] = fmaf(w4.z, b2.y, a2[2][1]);
      a2[3][0] = fmaf(w4.w, b2.x, a2[3][0]);
      a2[3][1] = fmaf(w4.w, b2.y, a2[3][1]);
    }
#pragma unroll
    for (int im = 0; im < 4; im++) {
      int row = ch * 64 + mq * 4 + im;
      float bb = ffn1B[row];
      stA_u64(&f1[row * NPIX + n0 + pp],
              __builtin_bit_cast(unsigned long long,
                                 make_float2(a2[im][0] + bb, a2[im][1] + bb)));
    }
  }
  gbar(ctr + 1536, bid);

  // ------- Stage 5: ffn2_dw (512 units) -------
  {
    float(&xs2)[16][260] = u.s5.xs2;
    float(&wshT)[32][260] = u.s5.wshT;
    int n0 = (bid & 255) * 16, m0 = (bid >> 8) * 32;
    int y = n0 >> 6, x0 = n0 & 63;
    {
      int mm = tid >> 3, kg = (tid & 7) * 32;
      const float4* src = (const float4*)&ffn2W[(m0 + mm) * 256 + kg];
      float4* dst = (float4*)&wshT[mm][kg];
#pragma unroll
      for (int i = 0; i < 8; i++) dst[i] = src[i];
    }
    {
      int px4 = (tid & 3) * 4;
      int xabs = x0 + px4;
#pragma unroll
      for (int k = 0; k < 4; k++) {
        int c = (tid >> 2) + 64 * k;
        const float* base = f1 + c * NPIX;
        float wv[9];
#pragma unroll
        for (int i = 0; i < 9; i++) wv[i] = dww[c * 9 + i];
        float bc = dwb[c];
        float a[4] = {bc, bc, bc, bc};
#pragma unroll
        for (int dy = 0; dy < 3; dy++) {
          int yy = y + dy - 1;
          if (yy < 0 || yy > 63) continue;
          const float* row = base + yy * IMG + xabs;
          float4 mid = *(const float4*)row;
          float left = (xabs > 0) ? row[-1] : 0.f;
          float right = (xabs + 4 < IMG) ? row[4] : 0.f;
          float win[6] = {left, mid.x, mid.y, mid.z, mid.w, right};
#pragma unroll
          for (int o = 0; o < 4; o++)
#pragma unroll
            for (int dx = 0; dx < 3; dx++)
              a[o] = fmaf(wv[dy * 3 + dx], win[o + dx], a[o]);
        }
#pragma unroll
        for (int o = 0; o < 4; o++)
          xs2[px4 + o][c] =
              0.5f * a[o] * (1.f + erff(a[o] * 0.70710678118654752f));
      }
    }
    __syncthreads();
    int m = tid >> 3, np = (tid & 7) * 2;
    float a0 = 0.f, a1 = 0.f;
#pragma unroll 4
    for (int k4 = 0; k4 < 64; k4++) {
      float4 w4 = *(const float4*)&wshT[m][k4 * 4];
      float4 xa = *(const float4*)&xs2[np][k4 * 4];
      float4 xb = *(const float4*)&xs2[np + 1][k4 * 4];
      a0 = fmaf(w4.x, xa.x, a0);
      a1 = fmaf(w4.x, xb.x, a1);
      a0 = fmaf(w4.y, xa.y, a0);
      a1 = fmaf(w4.y, xb.y, a1);
      a0 = fmaf(w4.z, xa.z, a0);
      a1 = fmaf(w4.z, xb.z, a1);
      a0 = fmaf(w4.w, xa.w, a0);
      a1 = fmaf(w4.w, xb.w, a1);
    }
    int row = m0 + m;
    float bv = ffn2B[row];
    const float2 rr = *(const float2*)&x1[row * NPIX + n0 + np];
    *(float2*)&out[row * NPIX + n0 + np] =
        make_float2(a0 + bv + rr.x, a1 + bv + rr.y);
  }
}

// ---------------------------------------------------------------------------
extern "C" void kernel_launch(void* const* d_in, const int* in_sizes, int n_in,
                              void* d_out, int out_size, void* d_ws,
                              size_t ws_size, hipStream_t stream) {
  const float* x      = (const float*)d_in[0];
  const float* luma   = (const float*)d_in[1];
  const float* ln1_w  = (const float*)d_in[2];
  const float* ln1_b  = (const float*)d_in[3];
  const float* qkv_w  = (const float*)d_in[4];
  const float* qkv_b  = (const float*)d_in[5];
  const float* proj_w = (const float*)d_in[6];
  const float* proj_b = (const float*)d_in[7];
  const float* lc1_w  = (const float*)d_in[8];
  const float* lc1_b  = (const float*)d_in[9];
  const float* lc2_w  = (const float*)d_in[10];
  const float* lc2_b  = (const float*)d_in[11];
  const float* gam_w  = (const float*)d_in[12];
  const float* gam_b  = (const float*)d_in[13];
  const float* bet_w  = (const float*)d_in[14];
  const float* bet_b  = (const float*)d_in[15];
  const float* alpha  = (const float*)d_in[16];
  const float* ln2_w  = (const float*)d_in[17];
  const float* ln2_b  = (const float*)d_in[18];
  const float* ffn1_w = (const float*)d_in[19];
  const float* ffn1_b = (const float*)d_in[20];
  const float* dw_w   = (const float*)d_in[21];
  const float* dw_b   = (const float*)d_in[22];
  const float* ffn2_w = (const float*)d_in[23];
  const float* ffn2_b = (const float*)d_in[24];
  float* out = (float*)d_out;

  float* w = (float*)d_ws;
  float* pooled = w + 0;        // 4096
  float* bsums  = w + 4096;     // 64 (64 used)
  unsigned short* cbuf = (unsigned short*)(w + 4160);     // 64 f (16 us used)
  float* mu1 = w + 4224;        // 4096
  float* rs1 = w + 8320;        // 4096
  unsigned short* qhl  = (unsigned short*)(w + 12416);    // 262144 f
  unsigned short* khl  = (unsigned short*)(w + 274560);   // 262144 f
  unsigned short* vthx = (unsigned short*)(w + 536704);   // 131072 f
  unsigned short* vtlx = (unsigned short*)(w + 667776);   // 131072 f
  float* pacc = w + 798848;    // 2097152 (JP=8)
  float* pl   = w + 2896000;   // 262144
  float* x1   = w + 3158144;   // 262144
  float* f1   = w + 3420288;   // 1048576
  float* h2   = w + 4468864;   // 131072
  unsigned int* ctr = (unsigned int*)(w + 4599936);  // 2048 uints

  init_kernel<<<1, 256, 0, stream>>>(ctr, cbuf);
  fused_kernel<<<dim3(NBLK), 256, 0, stream>>>(
      x, luma, lc1_w, lc1_b, lc2_w, lc2_b, ln1_w, ln1_b, qkv_w, qkv_b, gam_w,
      gam_b, bet_w, bet_b, alpha, proj_w, proj_b, ln2_w, ln2_b, ffn1_w, ffn1_b,
      dw_w, dw_b, ffn2_w, ffn2_b, out, pooled, bsums, cbuf, mu1, rs1, qhl, khl,
      vthx, vtlx, pacc, pl, x1, f1, h2, ctr);
}

// Round 7
// 201.950 us; speedup vs baseline: 3.0493x; 1.0343x over previous
//
#include <hip/hip_runtime.h>
#include <math.h>

// B=1, C=64, H=W=64, N=4096, heads=8, dh=8, inner=64, hid_lc=32, hid_f=256.
// Persistent fused kernel, 5 stages, hierarchical grid barriers (r6).
// r7: (a) LN1 stats moved from stage 1 (scattered stride-16KB x reads,
// 262K cache lines grid-wide) into stage 2 where the x-tile is already in
// LDS; mu1/rs1 buffers deleted. (b) JP=8 -> 4: attn = 16 i-tiles x 8 heads
// x 4 jp = 512 units (1/block, 32 jt), pacc LLC round-trip halves to
// 4+4 MB, stage-4 combine reads 4 partials. Sum reassociations ~1e-6,
// far under bf16 quantization (absmax unchanged).
#define NPIX 4096
#define IMG 64
#define NBLK 512

typedef __attribute__((ext_vector_type(8))) short bf16x8;
typedef __attribute__((ext_vector_type(4))) float floatx4;
typedef __attribute__((ext_vector_type(4))) unsigned int uintx4;

__device__ __forceinline__ unsigned int split_pack(float x) {
  unsigned int u = __float_as_uint(x);
  unsigned int hif = u & 0xffff0000u;
  float lof = x - __uint_as_float(hif);
  return (u >> 16) | (__float_as_uint(lof) & 0xffff0000u);
}

__device__ __forceinline__ unsigned int pack_hi2(float a, float b) {
  return __builtin_amdgcn_perm(__float_as_uint(b), __float_as_uint(a),
                               0x07060302u);
}

__device__ __forceinline__ void stA_f32(float* p, float v) {
  __hip_atomic_store(p, v, __ATOMIC_RELAXED, __HIP_MEMORY_SCOPE_AGENT);
}
__device__ __forceinline__ void stA_u32(void* p, unsigned int v) {
  __hip_atomic_store((unsigned int*)p, v, __ATOMIC_RELAXED,
                     __HIP_MEMORY_SCOPE_AGENT);
}
__device__ __forceinline__ void stA_u64(void* p, unsigned long long v) {
  __hip_atomic_store((unsigned long long*)p, v, __ATOMIC_RELAXED,
                     __HIP_MEMORY_SCOPE_AGENT);
}
__device__ __forceinline__ unsigned int ldA(const unsigned int* p) {
  return __hip_atomic_load(p, __ATOMIC_RELAXED, __HIP_MEMORY_SCOPE_AGENT);
}
__device__ __forceinline__ unsigned int addA(unsigned int* p) {
  return __hip_atomic_fetch_add(p, 1u, __ATOMIC_RELAXED,
                                __HIP_MEMORY_SCOPE_AGENT);
}

// Hierarchical grid barrier (r6): 8 groups of 64 blocks; per-group arrive +
// release lines (128B apart), global done counter. <=63 pollers per line.
__device__ __forceinline__ void gbar(unsigned int* base, int bid) {
  __syncthreads();
  if (threadIdx.x == 0) {
    int g = bid >> 6;
    unsigned int* ga = base + g * 32;
    unsigned int old = addA(ga);
    if (old == 63u) {
      addA(base + 256);
      while (ldA(base + 256) < 8u) __builtin_amdgcn_s_sleep(1);
      stA_u32(ga + 16, 1u);
    } else {
      while (ldA(ga + 16) == 0u) __builtin_amdgcn_s_sleep(2);
    }
    asm volatile("" ::: "memory");
  }
  __syncthreads();
}

// LDS stage overlays.
struct S1 {  // lc12, 8x8 tiles
  float lum[144];       // 12x12
  float sw1[288];
  float tin[32][100];   // h1 on 10x10 halo per ic
  float swt[4][32][9];
  float red[64];
};
struct S2 {  // ln_qkv (+ in-block LN1 stats)
  float xs[64][32];
  float wsh[64][64];
  float h2s[32][32];
  float wgs[32][64];
  float wbs[32][64];
  float pss[8][32];
  float pqq[8][32];
  float mu[32];
  float rs[32];
};
struct S4 {  // proj_ffn1
  float at[64][34];
  float wsh[64][64];
  float xsl[64][34];
  float ps[16][32];
  float pq[16][32];
  float mus[32];
  float rss[32];
};
struct S5 {  // ffn2_dw
  float xs2[16][260];
  float wshT[32][260];
};
union SU {
  S1 s1;
  S2 s2;
  S4 s4;
  S5 s5;
};

__global__ void init_kernel(unsigned int* __restrict__ ctr,
                            unsigned short* __restrict__ cbuf) {
  int t = threadIdx.x;
#pragma unroll
  for (int i = 0; i < 8; i++) ctr[t + i * 256] = 0u;
  if (t < 16) cbuf[t] = (t < 8) ? 0x3F80 : 0;
}

__global__ __launch_bounds__(256, 3) void fused_kernel(
    const float* __restrict__ x, const float* __restrict__ luma,
    const float* __restrict__ lc1w, const float* __restrict__ lc1b,
    const float* __restrict__ lc2w, const float* __restrict__ lc2b,
    const float* __restrict__ ln1w, const float* __restrict__ ln1b,
    const float* __restrict__ qkvW, const float* __restrict__ qkvB,
    const float* __restrict__ gamW, const float* __restrict__ gamB,
    const float* __restrict__ betW, const float* __restrict__ betB,
    const float* __restrict__ alpha, const float* __restrict__ projW,
    const float* __restrict__ projB, const float* __restrict__ ln2w,
    const float* __restrict__ ln2b, const float* __restrict__ ffn1W,
    const float* __restrict__ ffn1B, const float* __restrict__ dww,
    const float* __restrict__ dwb, const float* __restrict__ ffn2W,
    const float* __restrict__ ffn2B, float* __restrict__ out,
    float* __restrict__ pooled, float* __restrict__ bsums,
    unsigned short* __restrict__ cbuf, unsigned short* __restrict__ qhl,
    unsigned short* __restrict__ khl, unsigned short* __restrict__ vthx,
    unsigned short* __restrict__ vtlx, float* __restrict__ pacc,
    float* __restrict__ pl, float* __restrict__ x1, float* __restrict__ f1,
    float* __restrict__ h2, unsigned int* __restrict__ ctr) {
  __shared__ SU u;
  int bid = blockIdx.x;
  int tid = threadIdx.x;

  // ------- Stage 1: lc12 on 8x8 tiles (64 tiles x 8 ocg = 512 units) -------
  {
    int tile = bid >> 3, ocg = bid & 7;
    int ty0 = (tile >> 3) * 8, tx0 = (tile & 7) * 8;
    float(&lum)[144] = u.s1.lum;
    float(&sw1)[288] = u.s1.sw1;
    float(&tin)[32][100] = u.s1.tin;
    float(&swt)[4][32][9] = u.s1.swt;
    float(&red)[64] = u.s1.red;
    if (tid < 144) {
      int py = tid / 12, px = tid - py * 12;
      int gy = ty0 + py - 2, gx = tx0 + px - 2;
      lum[tid] = (gy >= 0 && gy < IMG && gx >= 0 && gx < IMG)
                     ? luma[gy * IMG + gx]
                     : 0.f;
    }
    for (int idx = tid; idx < 288; idx += 256) sw1[idx] = lc1w[idx];
    for (int idx = tid; idx < 1152; idx += 256) {
      int o = idx / 288, r = idx - o * 288;
      swt[o][r / 9][r % 9] = lc2w[(ocg * 4 + o) * 288 + r];
    }
    __syncthreads();
    for (int idx = tid; idx < 3200; idx += 256) {
      int ic = idx / 100, pos = idx - ic * 100;
      int py = pos / 10, px = pos - py * 10;
      int gy = ty0 + py - 1, gx = tx0 + px - 1;
      float v = 0.f;
      if (gy >= 0 && gy < IMG && gx >= 0 && gx < IMG) {
        float s = lc1b[ic];
        const float* wp = &sw1[ic * 9];
#pragma unroll
        for (int dy = 0; dy < 3; dy++)
#pragma unroll
          for (int dx = 0; dx < 3; dx++)
            s = fmaf(wp[dy * 3 + dx], lum[(py + dy) * 12 + px + dx], s);
        v = fmaxf(s, 0.f);
      }
      tin[ic][pos] = v;
    }
    __syncthreads();
    int o = tid >> 6, pix = tid & 63;
    int ly = pix >> 3, lx = pix & 7;
    int p = (ty0 + ly) * IMG + tx0 + lx;
    float acc = lc2b[ocg * 4 + o];
    for (int ic = 0; ic < 32; ic++) {
      float v[9];
#pragma unroll
      for (int dy = 0; dy < 3; dy++)
#pragma unroll
        for (int dx = 0; dx < 3; dx++)
          v[dy * 3 + dx] = tin[ic][(ly + dy) * 10 + lx + dx];
#pragma unroll
      for (int t = 0; t < 9; t++) acc = fmaf(swt[o][ic][t], v[t], acc);
    }
    stA_f32(&h2[(ocg * 4 + o) * NPIX + p], fmaxf(acc, 0.f));
    if (ocg == 0) {
      if (tid < 64) {
        int gy = ty0 + ly, gx = tx0 + lx;
        float sv = 0.f;
#pragma unroll
        for (int dy = 0; dy < 3; dy++)
#pragma unroll
          for (int dx = 0; dx < 3; dx++)
            sv += lum[(ly + dy + 1) * 12 + lx + dx + 1];
        float cy = 3.f - (gy == 0 ? 1.f : 0.f) - (gy == 63 ? 1.f : 0.f);
        float cx = 3.f - (gx == 0 ? 1.f : 0.f) - (gx == 63 ? 1.f : 0.f);
        float pv = (cy * cx - sv) * (1.f / 9.f);
        stA_f32(&pooled[p], pv);
        red[tid] = pv;
      }
      __syncthreads();
      for (int st = 32; st > 0; st >>= 1) {
        if (tid < st) red[tid] += red[tid + st];
        __syncthreads();
      }
      if (tid == 0) stA_f32(&bsums[tile], red[0]);
    }
  }
  gbar(ctr + 0, bid);

  // ------- Stage 2: ln_qkv (4 parts x 128 n-tiles = 512 units) -------
  {
    const float QSCALE = 0.35355339059327376f * 1.4426950408889634f;
    float(&xs)[64][32] = u.s2.xs;
    float(&wsh)[64][64] = u.s2.wsh;
    float(&h2s)[32][32] = u.s2.h2s;
    float(&wgs)[32][64] = u.s2.wgs;
    float(&wbs)[32][64] = u.s2.wbs;
    float(&pss)[8][32] = u.s2.pss;
    float(&pqq)[8][32] = u.s2.pqq;
    float(&mu)[32] = u.s2.mu;
    float(&rs)[32] = u.s2.rs;
    int n0 = (bid & 127) * 32, part = bid >> 7;
    int m0 = (part < 2 ? part : 2) * 64;
    {
      int e = tid * 2;
      int c = e >> 3, off = (e & 7) * 4;
      *(float4*)&xs[c][off] = *(const float4*)&x[c * NPIX + n0 + off];
      int e1 = e + 1;
      int c1 = e1 >> 3, off1 = (e1 & 7) * 4;
      *(float4*)&xs[c1][off1] = *(const float4*)&x[c1 * NPIX + n0 + off1];
    }
    {
      int m = tid >> 2, kg = (tid & 3) * 16;
      const float4* wr = (const float4*)&qkvW[(m0 + m) * 64 + kg];
      float4 w0 = wr[0], w1 = wr[1], w2 = wr[2], w3 = wr[3];
      float wv[16] = {w0.x, w0.y, w0.z, w0.w, w1.x, w1.y, w1.z, w1.w,
                      w2.x, w2.y, w2.z, w2.w, w3.x, w3.y, w3.z, w3.w};
#pragma unroll
      for (int j = 0; j < 16; j++) wsh[kg + j][m] = wv[j];
    }
    {
      int k = tid >> 3, nf = (tid & 7) * 4;
      *(float4*)&h2s[k][nf] = *(const float4*)&h2[k * NPIX + n0 + nf];
    }
    {
      int m = tid >> 2, kg = (tid & 3) * 8;
      const float4* g0 = (const float4*)&gamW[m * 32 + kg];
      float4 a = g0[0], b4 = g0[1];
      float gv[8] = {a.x, a.y, a.z, a.w, b4.x, b4.y, b4.z, b4.w};
#pragma unroll
      for (int j = 0; j < 8; j++) wgs[kg + j][m] = gv[j];
      const float4* bb0 = (const float4*)&betW[m * 32 + kg];
      float4 c4 = bb0[0], d4 = bb0[1];
      float bv[8] = {c4.x, c4.y, c4.z, c4.w, d4.x, d4.y, d4.z, d4.w};
#pragma unroll
      for (int j = 0; j < 8; j++) wbs[kg + j][m] = bv[j];
    }
    __syncthreads();
    // In-block LN1 stats from the LDS-resident x-tile (replaces stage-1's
    // scattered stride-16KB global reads).
    {
      int p = tid & 31, i = tid >> 5;
      float s = 0.f, q = 0.f;
#pragma unroll
      for (int j = 0; j < 8; j++) {
        float xv = xs[i * 8 + j][p];
        s += xv;
        q = fmaf(xv, xv, q);
      }
      pss[i][p] = s;
      pqq[i][p] = q;
    }
    __syncthreads();
    if (tid < 32) {
      float s = 0.f, q = 0.f;
#pragma unroll
      for (int i = 0; i < 8; i++) {
        s += pss[i][tid];
        q += pqq[i][tid];
      }
      float m = s * (1.f / 64.f);
      mu[tid] = m;
      rs[tid] = rsqrtf(q * (1.f / 64.f) - m * m + 1e-5f);
    }
    __syncthreads();
    {
      int c = tid >> 2, pg = (tid & 3) * 8;
      float wc = ln1w[c], bc = ln1b[c];
#pragma unroll
      for (int j = 0; j < 8; j++) {
        int p = pg + j;
        xs[c][p] = (xs[c][p] - mu[p]) * rs[p] * wc + bc;
      }
    }
    __syncthreads();
    int tx = tid & 15, ty = tid >> 4;
    float ga[4][2] = {}, ba[4][2] = {};
#pragma unroll 8
    for (int kk = 0; kk < 32; kk++) {
      float4 wg4 = *(const float4*)&wgs[kk][ty * 4];
      float4 wb4 = *(const float4*)&wbs[kk][ty * 4];
      float2 h22 = *(const float2*)&h2s[kk][tx * 2];
      float gv[4] = {wg4.x, wg4.y, wg4.z, wg4.w};
      float bv[4] = {wb4.x, wb4.y, wb4.z, wb4.w};
      float hv[2] = {h22.x, h22.y};
#pragma unroll
      for (int im = 0; im < 4; im++)
#pragma unroll
        for (int in = 0; in < 2; in++) {
          ga[im][in] = fmaf(gv[im], hv[in], ga[im][in]);
          ba[im][in] = fmaf(bv[im], hv[in], ba[im][in]);
        }
    }
#pragma unroll
    for (int im = 0; im < 4; im++) {
      int cc = ty * 4 + im;
      float gb = gamB[cc], bb2 = betB[cc];
#pragma unroll
      for (int in = 0; in < 2; in++) {
        ga[im][in] += gb;
        ba[im][in] += bb2;
      }
    }
    float acc[4][2] = {};
#pragma unroll 8
    for (int kk = 0; kk < 64; kk++) {
      float4 a = *(const float4*)&wsh[kk][ty * 4];
      float2 b2 = *(const float2*)&xs[kk][tx * 2];
      float av[4] = {a.x, a.y, a.z, a.w};
      float bv[2] = {b2.x, b2.y};
#pragma unroll
      for (int im = 0; im < 4; im++)
#pragma unroll
        for (int in = 0; in < 2; in++)
          acc[im][in] = fmaf(av[im], bv[in], acc[im][in]);
    }
    float val[4][2];
#pragma unroll
    for (int im = 0; im < 4; im++) {
      int cc = ty * 4 + im;
      float bv = qkvB[m0 + cc];
#pragma unroll
      for (int in = 0; in < 2; in++)
        val[im][in] = fmaf(ga[im][in], acc[im][in] + bv, ba[im][in]);
    }
    if (part == 0) {
      float msum = 0.f;
      for (int t = 0; t < 64; t++) msum += bsums[t];
      float mean = msum * (1.f / 4096.f);
      float a0 = alpha[0];
      const float2 pv = *(const float2*)&pooled[n0 + tx * 2];
      float iv[2] = {a0 * (pv.x - mean), a0 * (pv.y - mean)};
#pragma unroll
      for (int im = 0; im < 4; im++)
#pragma unroll
        for (int in = 0; in < 2; in++)
          val[im][in] = (val[im][in] + iv[in]) * QSCALE;
    }
    if (part < 2) {
      unsigned short* dst = (part == 0) ? qhl : khl;
      int hh = ty >> 1, d0 = (ty & 1) * 4;
#pragma unroll
      for (int in = 0; in < 2; in++) {
        int n = n0 + tx * 2 + in;
        unsigned int pk[4];
#pragma unroll
        for (int im = 0; im < 4; im++) pk[im] = split_pack(val[im][in]);
        short4 hi, lo;
        hi.x = (short)(pk[0] & 0xffffu); hi.y = (short)(pk[1] & 0xffffu);
        hi.z = (short)(pk[2] & 0xffffu); hi.w = (short)(pk[3] & 0xffffu);
        lo.x = (short)(pk[0] >> 16); lo.y = (short)(pk[1] >> 16);
        lo.z = (short)(pk[2] >> 16); lo.w = (short)(pk[3] >> 16);
        unsigned short* base = dst + ((size_t)(hh * NPIX + n) << 4) + d0;
        stA_u64(base, __builtin_bit_cast(unsigned long long, hi));
        stA_u64(base + 8, __builtin_bit_cast(unsigned long long, lo));
      }
    } else {
      int nq = n0 + tx * 2;
      int off0 = (nq >> 5) * 32 + ((nq >> 4) & 1) * 4 + ((nq >> 2) & 3) * 8 +
                 (nq & 3);
#pragma unroll
      for (int im = 0; im < 4; im++) {
        int cc = ty * 4 + im;
        unsigned int pk0 = split_pack(val[im][0]);
        unsigned int pk1 = split_pack(val[im][1]);
        if (part == 2) {
          short2 hi;
          hi.x = (short)(pk0 & 0xffffu);
          hi.y = (short)(pk1 & 0xffffu);
          stA_u32(vthx + (size_t)cc * NPIX + off0,
                  __builtin_bit_cast(unsigned int, hi));
        } else {
          short2 lo;
          lo.x = (short)(pk0 >> 16);
          lo.y = (short)(pk1 >> 16);
          stA_u32(vtlx + (size_t)cc * NPIX + off0,
                  __builtin_bit_cast(unsigned int, lo));
        }
      }
    }
  }
  gbar(ctr + 512, bid);

  // ------- Stage 3: attn, JP=4 (16 i-tiles x 8 heads x 4 jp = 512) -------
  {
    int wave = tid >> 6, lane = tid & 63;
    int g = lane >> 4, c = lane & 15;
    int h = (bid >> 4) & 7, jp = bid >> 7;
    int i0 = (bid & 15) * 256 + wave * 64;
    int jbase = jp * 1024;
    bf16x8 qB[4];
#pragma unroll
    for (int t = 0; t < 4; t++)
      qB[t] = *(const bf16x8*)(qhl +
                               ((size_t)(h * NPIX + i0 + t * 16 + c) << 4) +
                               ((g & 1) << 3));
    const unsigned short* kp =
        khl + ((size_t)(h * NPIX + jbase + c) << 4) + ((g >> 1) << 3);
    const unsigned short* vhp;
    const unsigned short* vlp;
    int vstep;
    if (c < 8) {
      vhp = vthx + (size_t)(h * 8 + c) * NPIX + jbase + (g << 3);
      vlp = vtlx + (size_t)(h * 8 + c) * NPIX + jbase + (g << 3);
      vstep = 32;
    } else {
      vhp = (c == 8) ? cbuf : (cbuf + 8);  // ones row / zero rows
      vlp = cbuf + 8;
      vstep = 0;
    }
    floatx4 zero4 = {0.f, 0.f, 0.f, 0.f};
    floatx4 aH[4], aM[4];
#pragma unroll
    for (int t = 0; t < 4; t++) {
      aH[t] = zero4;
      aM[t] = zero4;
    }
#pragma unroll 4
    for (int jt = 0; jt < 32; ++jt) {
      bf16x8 ka0 = *(const bf16x8*)kp;
      bf16x8 ka1 = *(const bf16x8*)(kp + 256);
      bf16x8 avh = *(const bf16x8*)vhp;
      bf16x8 avl = *(const bf16x8*)vlp;
      kp += 512;
      vhp += vstep;
      vlp += vstep;
#pragma unroll
      for (int t = 0; t < 4; t++) {
        floatx4 s0 = __builtin_amdgcn_mfma_f32_16x16x32_bf16(ka0, qB[t],
                                                             zero4, 0, 0, 0);
        floatx4 s1 = __builtin_amdgcn_mfma_f32_16x16x32_bf16(ka1, qB[t],
                                                             zero4, 0, 0, 0);
        float p0 = __builtin_amdgcn_exp2f(fminf(s0[0], 80.f));
        float p1 = __builtin_amdgcn_exp2f(fminf(s0[1], 80.f));
        float p2 = __builtin_amdgcn_exp2f(fminf(s0[2], 80.f));
        float p3 = __builtin_amdgcn_exp2f(fminf(s0[3], 80.f));
        float p4 = __builtin_amdgcn_exp2f(fminf(s1[0], 80.f));
        float p5 = __builtin_amdgcn_exp2f(fminf(s1[1], 80.f));
        float p6 = __builtin_amdgcn_exp2f(fminf(s1[2], 80.f));
        float p7 = __builtin_amdgcn_exp2f(fminf(s1[3], 80.f));
        uintx4 bh;
        bh.x = pack_hi2(p0, p1);
        bh.y = pack_hi2(p2, p3);
        bh.z = pack_hi2(p4, p5);
        bh.w = pack_hi2(p6, p7);
        bf16x8 pbh = __builtin_bit_cast(bf16x8, bh);
        aH[t] =
            __builtin_amdgcn_mfma_f32_16x16x32_bf16(avh, pbh, aH[t], 0, 0, 0);
        aM[t] =
            __builtin_amdgcn_mfma_f32_16x16x32_bf16(avl, pbh, aM[t], 0, 0, 0);
      }
    }
#pragma unroll
    for (int t = 0; t < 4; t++) {
      floatx4 o = aH[t] + aM[t];
      if (g < 2) {
        size_t b0 = (size_t)((jp * 8 + h) * NPIX + i0 + t * 16 + c);
        float2 lo2 = make_float2(o[0], o[1]);
        float2 hi2 = make_float2(o[2], o[3]);
        stA_u64(&pacc[b0 * 8 + g * 4],
                __builtin_bit_cast(unsigned long long, lo2));
        stA_u64(&pacc[b0 * 8 + g * 4 + 2],
                __builtin_bit_cast(unsigned long long, hi2));
      } else if (g == 2) {
        stA_f32(&pl[(size_t)((jp * 8 + h) * NPIX + i0 + t * 16 + c)], o[0]);
      }
    }
  }
  gbar(ctr + 1024, bid);

  // ------- Stage 4: proj_ffn1 (512 units; 4 partials) -------
  {
    float(&at)[64][34] = u.s4.at;
    float(&wsh)[64][64] = u.s4.wsh;
    float(&xsl)[64][34] = u.s4.xsl;
    float(&ps)[16][32] = u.s4.ps;
    float(&pq)[16][32] = u.s4.pq;
    float(&mus)[32] = u.s4.mus;
    float(&rss)[32] = u.s4.rss;
    int n0 = (bid & 127) * 32;
    int ch = bid >> 7;
    int mm = tid >> 2, kg = (tid & 3) * 16;
    {
      const float4* wr = (const float4*)&projW[mm * 64 + kg];
      float4 w0 = wr[0], w1 = wr[1], w2 = wr[2], w3 = wr[3];
      float wv[16] = {w0.x, w0.y, w0.z, w0.w, w1.x, w1.y, w1.z, w1.w,
                      w2.x, w2.y, w2.z, w2.w, w3.x, w3.y, w3.z, w3.w};
#pragma unroll
      for (int j = 0; j < 16; j++) wsh[kg + j][mm] = wv[j];
    }
    {
      int hh = tid >> 5, nn = tid & 31;
      int i = n0 + nn;
      float L = 0.f, o[8] = {};
#pragma unroll
      for (int p = 0; p < 4; p++) {
        size_t base = (size_t)((p * 8 + hh) * NPIX + i);
        L += pl[base];
        const float4 a0 = *(const float4*)&pacc[base * 8];
        const float4 a1 = *(const float4*)&pacc[base * 8 + 4];
        o[0] += a0.x; o[1] += a0.y; o[2] += a0.z; o[3] += a0.w;
        o[4] += a1.x; o[5] += a1.y; o[6] += a1.z; o[7] += a1.w;
      }
      float inv = 1.f / L;
#pragma unroll
      for (int d = 0; d < 8; d++) at[hh * 8 + d][nn] = o[d] * inv;
    }
    __syncthreads();
    int mq = tid >> 4, pp = (tid & 15) * 2;
    float acc[4][2] = {};
#pragma unroll 8
    for (int k = 0; k < 64; k++) {
      float4 w4 = *(const float4*)&wsh[k][mq * 4];
      float2 b2 = *(const float2*)&at[k][pp];
      acc[0][0] = fmaf(w4.x, b2.x, acc[0][0]);
      acc[0][1] = fmaf(w4.x, b2.y, acc[0][1]);
      acc[1][0] = fmaf(w4.y, b2.x, acc[1][0]);
      acc[1][1] = fmaf(w4.y, b2.y, acc[1][1]);
      acc[2][0] = fmaf(w4.z, b2.x, acc[2][0]);
      acc[2][1] = fmaf(w4.z, b2.y, acc[2][1]);
      acc[3][0] = fmaf(w4.w, b2.x, acc[3][0]);
      acc[3][1] = fmaf(w4.w, b2.y, acc[3][1]);
    }
    float v[4][2], sn0 = 0.f, sn1 = 0.f, qn0 = 0.f, qn1 = 0.f;
#pragma unroll
    for (int im = 0; im < 4; im++) {
      int row = mq * 4 + im;
      float bpv = projB[row];
      const float2 xr = *(const float2*)&x[row * NPIX + n0 + pp];
      float v0 = acc[im][0] + bpv + xr.x;
      float v1 = acc[im][1] + bpv + xr.y;
      v[im][0] = v0;
      v[im][1] = v1;
      sn0 += v0;
      qn0 = fmaf(v0, v0, qn0);
      sn1 += v1;
      qn1 = fmaf(v1, v1, qn1);
    }
    if (ch == 0) {
#pragma unroll
      for (int im = 0; im < 4; im++)
        stA_u64(&x1[(mq * 4 + im) * NPIX + n0 + pp],
                __builtin_bit_cast(unsigned long long,
                                   make_float2(v[im][0], v[im][1])));
    }
    ps[mq][pp] = sn0;
    ps[mq][pp + 1] = sn1;
    pq[mq][pp] = qn0;
    pq[mq][pp + 1] = qn1;
    __syncthreads();
    {
      const float4* w1r = (const float4*)&ffn1W[(ch * 64 + mm) * 64 + kg];
      float4 u0 = w1r[0], u1 = w1r[1], u2 = w1r[2], u3 = w1r[3];
      float uv[16] = {u0.x, u0.y, u0.z, u0.w, u1.x, u1.y, u1.z, u1.w,
                      u2.x, u2.y, u2.z, u2.w, u3.x, u3.y, u3.z, u3.w};
#pragma unroll
      for (int j = 0; j < 16; j++) wsh[kg + j][mm] = uv[j];
    }
    if (tid < 32) {
      float s = 0.f, q = 0.f;
#pragma unroll
      for (int t = 0; t < 16; t++) {
        s += ps[t][tid];
        q += pq[t][tid];
      }
      float mu = s * (1.f / 64.f);
      mus[tid] = mu;
      rss[tid] = rsqrtf(q * (1.f / 64.f) - mu * mu + 1e-5f);
    }
    __syncthreads();
    {
      float mu0 = mus[pp], mu1v = mus[pp + 1];
      float rs0 = rss[pp], rs1v = rss[pp + 1];
#pragma unroll
      for (int im = 0; im < 4; im++) {
        int row = mq * 4 + im;
        float w2v = ln2w[row], b2v = ln2b[row];
        *(float2*)&xsl[row][pp] =
            make_float2((v[im][0] - mu0) * rs0 * w2v + b2v,
                        (v[im][1] - mu1v) * rs1v * w2v + b2v);
      }
    }
    __syncthreads();
    float a2[4][2] = {};
#pragma unroll 8
    for (int k = 0; k < 64; k++) {
      float4 w4 = *(const float4*)&wsh[k][mq * 4];
      float2 b2 = *(const float2*)&xsl[k][pp];
      a2[0][0] = fmaf(w4.x, b2.x, a2[0][0]);
      a2[0][1] = fmaf(w4.x, b2.y, a2[0][1]);
      a2[1][0] = fmaf(w4.y, b2.x, a2[1][0]);
      a2[1][1] = fmaf(w4.y, b2.y, a2[1][1]);
      a2[2][0] = fmaf(w4.z, b2.x, a2[2][0]);
      a2[2][1] = fmaf(w4.z, b2.y, a2[2][1]);
      a2[3][0] = fmaf(w4.w, b2.x, a2[3][0]);
      a2[3][1] = fmaf(w4.w, b2.y, a2[3][1]);
    }
#pragma unroll
    for (int im = 0; im < 4; im++) {
      int row = ch * 64 + mq * 4 + im;
      float bb = ffn1B[row];
      stA_u64(&f1[row * NPIX + n0 + pp],
              __builtin_bit_cast(unsigned long long,
                                 make_float2(a2[im][0] + bb, a2[im][1] + bb)));
    }
  }
  gbar(ctr + 1536, bid);

  // ------- Stage 5: ffn2_dw (512 units) -------
  {
    float(&xs2)[16][260] = u.s5.xs2;
    float(&wshT)[32][260] = u.s5.wshT;
    int n0 = (bid & 255) * 16, m0 = (bid >> 8) * 32;
    int y = n0 >> 6, x0 = n0 & 63;
    {
      int mm = tid >> 3, kg = (tid & 7) * 32;
      const float4* src = (const float4*)&ffn2W[(m0 + mm) * 256 + kg];
      float4* dst = (float4*)&wshT[mm][kg];
#pragma unroll
      for (int i = 0; i < 8; i++) dst[i] = src[i];
    }
    {
      int px4 = (tid & 3) * 4;
      int xabs = x0 + px4;
#pragma unroll
      for (int k = 0; k < 4; k++) {
        int c = (tid >> 2) + 64 * k;
        const float* base = f1 + c * NPIX;
        float wv[9];
#pragma unroll
        for (int i = 0; i < 9; i++) wv[i] = dww[c * 9 + i];
        float bc = dwb[c];
        float a[4] = {bc, bc, bc, bc};
#pragma unroll
        for (int dy = 0; dy < 3; dy++) {
          int yy = y + dy - 1;
          if (yy < 0 || yy > 63) continue;
          const float* row = base + yy * IMG + xabs;
          float4 mid = *(const float4*)row;
          float left = (xabs > 0) ? row[-1] : 0.f;
          float right = (xabs + 4 < IMG) ? row[4] : 0.f;
          float win[6] = {left, mid.x, mid.y, mid.z, mid.w, right};
#pragma unroll
          for (int o = 0; o < 4; o++)
#pragma unroll
            for (int dx = 0; dx < 3; dx++)
              a[o] = fmaf(wv[dy * 3 + dx], win[o + dx], a[o]);
        }
#pragma unroll
        for (int o = 0; o < 4; o++)
          xs2[px4 + o][c] =
              0.5f * a[o] * (1.f + erff(a[o] * 0.70710678118654752f));
      }
    }
    __syncthreads();
    int m = tid >> 3, np = (tid & 7) * 2;
    float a0 = 0.f, a1 = 0.f;
#pragma unroll 4
    for (int k4 = 0; k4 < 64; k4++) {
      float4 w4 = *(const float4*)&wshT[m][k4 * 4];
      float4 xa = *(const float4*)&xs2[np][k4 * 4];
      float4 xb = *(const float4*)&xs2[np + 1][k4 * 4];
      a0 = fmaf(w4.x, xa.x, a0);
      a1 = fmaf(w4.x, xb.x, a1);
      a0 = fmaf(w4.y, xa.y, a0);
      a1 = fmaf(w4.y, xb.y, a1);
      a0 = fmaf(w4.z, xa.z, a0);
      a1 = fmaf(w4.z, xb.z, a1);
      a0 = fmaf(w4.w, xa.w, a0);
      a1 = fmaf(w4.w, xb.w, a1);
    }
    int row = m0 + m;
    float bv = ffn2B[row];
    const float2 rr = *(const float2*)&x1[row * NPIX + n0 + np];
    *(float2*)&out[row * NPIX + n0 + np] =
        make_float2(a0 + bv + rr.x, a1 + bv + rr.y);
  }
}

// ---------------------------------------------------------------------------
extern "C" void kernel_launch(void* const* d_in, const int* in_sizes, int n_in,
                              void* d_out, int out_size, void* d_ws,
                              size_t ws_size, hipStream_t stream) {
  const float* x      = (const float*)d_in[0];
  const float* luma   = (const float*)d_in[1];
  const float* ln1_w  = (const float*)d_in[2];
  const float* ln1_b  = (const float*)d_in[3];
  const float* qkv_w  = (const float*)d_in[4];
  const float* qkv_b  = (const float*)d_in[5];
  const float* proj_w = (const float*)d_in[6];
  const float* proj_b = (const float*)d_in[7];
  const float* lc1_w  = (const float*)d_in[8];
  const float* lc1_b  = (const float*)d_in[9];
  const float* lc2_w  = (const float*)d_in[10];
  const float* lc2_b  = (const float*)d_in[11];
  const float* gam_w  = (const float*)d_in[12];
  const float* gam_b  = (const float*)d_in[13];
  const float* bet_w  = (const float*)d_in[14];
  const float* bet_b  = (const float*)d_in[15];
  const float* alpha  = (const float*)d_in[16];
  const float* ln2_w  = (const float*)d_in[17];
  const float* ln2_b  = (const float*)d_in[18];
  const float* ffn1_w = (const float*)d_in[19];
  const float* ffn1_b = (const float*)d_in[20];
  const float* dw_w   = (const float*)d_in[21];
  const float* dw_b   = (const float*)d_in[22];
  const float* ffn2_w = (const float*)d_in[23];
  const float* ffn2_b = (const float*)d_in[24];
  float* out = (float*)d_out;

  float* w = (float*)d_ws;
  float* pooled = w + 0;        // 4096
  float* bsums  = w + 4096;     // 64 (64 used)
  unsigned short* cbuf = (unsigned short*)(w + 4160);     // 64 f (16 us used)
  unsigned short* qhl  = (unsigned short*)(w + 12416);    // 262144 f
  unsigned short* khl  = (unsigned short*)(w + 274560);   // 262144 f
  unsigned short* vthx = (unsigned short*)(w + 536704);   // 131072 f
  unsigned short* vtlx = (unsigned short*)(w + 667776);   // 131072 f
  float* pacc = w + 798848;    // 1048576 (JP=4)
  float* pl   = w + 2896000;   // 131072
  float* x1   = w + 3158144;   // 262144
  float* f1   = w + 3420288;   // 1048576
  float* h2   = w + 4468864;   // 131072
  unsigned int* ctr = (unsigned int*)(w + 4599936);  // 2048 uints

  init_kernel<<<1, 256, 0, stream>>>(ctr, cbuf);
  fused_kernel<<<dim3(NBLK), 256, 0, stream>>>(
      x, luma, lc1_w, lc1_b, lc2_w, lc2_b, ln1_w, ln1_b, qkv_w, qkv_b, gam_w,
      gam_b, bet_w, bet_b, alpha, proj_w, proj_b, ln2_w, ln2_b, ffn1_w, ffn1_b,
      dw_w, dw_b, ffn2_w, ffn2_b, out, pooled, bsums, cbuf, qhl, khl,
      vthx, vtlx, pacc, pl, x1, f1, h2, ctr);
}